// Round 1
// baseline (352.722 us; speedup 1.0000x reference)
//
#include <hip/hip_runtime.h>

// Sizes (fixed by the problem)
#define NB 4
#define NS 2048
#define ND 1024
#define NH 16
#define NDH 64
#define NR 12
#define NRH 192   // NH*NR

// ---------------------------------------------------------------------------
// Kernel 1: Wq_eff[b,h,r,e] = sum_d U[b,h,r,d] * W_Q[h*64+d, e]
// grid: 768 blocks = (b*16+h)*12+r ; 256 threads, 4 outputs each
// ---------------------------------------------------------------------------
__global__ __launch_bounds__(256) void build_wqeff(const float* __restrict__ U,
                                                   const float* __restrict__ WQ,
                                                   float* __restrict__ wq) {
  int idx = blockIdx.x;               // (b*16 + h)*12 + r
  int hr  = idx % (NH * NR);
  int h   = hr / NR;
  __shared__ float u[NDH];
  int t = threadIdx.x;
  if (t < NDH) u[t] = U[(size_t)idx * NDH + t];
  __syncthreads();
  int e0 = t * 4;
  float a0 = 0.f, a1 = 0.f, a2 = 0.f, a3 = 0.f;
  const float* wbase = WQ + (size_t)h * NDH * ND + e0;
#pragma unroll 4
  for (int d = 0; d < NDH; ++d) {
    float uv = u[d];
    const float* wr = wbase + (size_t)d * ND;
    a0 += uv * wr[0]; a1 += uv * wr[1]; a2 += uv * wr[2]; a3 += uv * wr[3];
  }
  float* o = wq + (size_t)idx * ND + e0;
  o[0] = a0; o[1] = a1; o[2] = a2; o[3] = a3;
}

// ---------------------------------------------------------------------------
// Tiled fp32 GEMM, 64x64 tile, BK=32, 256 threads, 4x4 microtile.
// BT=true : C[m,n] = sum_k A[m,k] * B[n,k]   (A[M,K], B[N,K] both row-major)
// BT=false: C[m,n] = sum_k A[m,k] * B[k,n]
// EPI 0: C row-major [M,N]
// EPI 1: ctx layout: m = h*12+r -> row (r*16+h), ldc = 2048 (per-batch flat)
// EPI 2: += bias[n]
// blockIdx.z = batch (strides sAb/sBb/sCb)
// ---------------------------------------------------------------------------
template <bool BT, int EPI>
__global__ __launch_bounds__(256) void gemm_tile(const float* __restrict__ A,
                                                 const float* __restrict__ Bm,
                                                 float* __restrict__ C,
                                                 const float* __restrict__ bias,
                                                 int M, int N, int Kd,
                                                 long sAb, long sBb, long sCb) {
  __shared__ float As[32][68];
  __shared__ float Bs[32][68];
  const int t  = threadIdx.x;
  const int tx = t & 15, ty = t >> 4;
  const int m0 = blockIdx.y * 64, n0 = blockIdx.x * 64;
  const float* Ab = A + (size_t)blockIdx.z * sAb;
  const float* Bb = Bm + (size_t)blockIdx.z * sBb;
  float* Cb = C + (size_t)blockIdx.z * sCb;

  float acc[4][4];
#pragma unroll
  for (int i = 0; i < 4; ++i)
#pragma unroll
    for (int j = 0; j < 4; ++j) acc[i][j] = 0.f;

  for (int k0 = 0; k0 < Kd; k0 += 32) {
    __syncthreads();
    // A tile -> As[k][m] (transposed store)
#pragma unroll
    for (int it = 0; it < 2; ++it) {
      int li = t + it * 256;
      int m = li >> 3, k4 = li & 7;
      float4 v = *(const float4*)&Ab[(size_t)(m0 + m) * Kd + k0 + k4 * 4];
      As[k4 * 4 + 0][m] = v.x; As[k4 * 4 + 1][m] = v.y;
      As[k4 * 4 + 2][m] = v.z; As[k4 * 4 + 3][m] = v.w;
    }
    if (BT) {
#pragma unroll
      for (int it = 0; it < 2; ++it) {
        int li = t + it * 256;
        int n = li >> 3, k4 = li & 7;
        float4 v = *(const float4*)&Bb[(size_t)(n0 + n) * Kd + k0 + k4 * 4];
        Bs[k4 * 4 + 0][n] = v.x; Bs[k4 * 4 + 1][n] = v.y;
        Bs[k4 * 4 + 2][n] = v.z; Bs[k4 * 4 + 3][n] = v.w;
      }
    } else {
#pragma unroll
      for (int it = 0; it < 2; ++it) {
        int li = t + it * 256;
        int k = li >> 4, n4 = li & 15;
        float4 v = *(const float4*)&Bb[(size_t)(k0 + k) * N + n0 + n4 * 4];
        *(float4*)&Bs[k][n4 * 4] = v;
      }
    }
    __syncthreads();
#pragma unroll
    for (int kk = 0; kk < 32; ++kk) {
      float4 a = *(const float4*)&As[kk][ty * 4];
      float4 b = *(const float4*)&Bs[kk][tx * 4];
      float av[4] = {a.x, a.y, a.z, a.w};
      float bv[4] = {b.x, b.y, b.z, b.w};
#pragma unroll
      for (int i = 0; i < 4; ++i)
#pragma unroll
        for (int j = 0; j < 4; ++j) acc[i][j] += av[i] * bv[j];
    }
  }

#pragma unroll
  for (int i = 0; i < 4; ++i) {
    int m = m0 + ty * 4 + i;
    float4 o;
    o.x = acc[i][0]; o.y = acc[i][1]; o.z = acc[i][2]; o.w = acc[i][3];
    if (EPI == 2) {
      float4 bv = *(const float4*)&bias[n0 + tx * 4];
      o.x += bv.x; o.y += bv.y; o.z += bv.z; o.w += bv.w;
    }
    if (EPI == 1) {
      int r = m % NR, hh = m / NR;
      *(float4*)&Cb[(size_t)(r * NH + hh) * NS + n0 + tx * 4] = o;
    } else {
      *(float4*)&Cb[(size_t)m * N + n0 + tx * 4] = o;
    }
  }
}

// ---------------------------------------------------------------------------
// Kernel: fused  s2 = T1 @ W_K_head^T -> softmax over dh -> A2 = attn @ W_V_head
// one block per (b,h): 64 blocks, 256 threads
// ---------------------------------------------------------------------------
__global__ __launch_bounds__(256) void fused_sm(const float* __restrict__ T1,
                                                const float* __restrict__ WK,
                                                const float* __restrict__ WV,
                                                float* __restrict__ A2) {
  int h = blockIdx.x & 15;
  int b = blockIdx.x >> 4;
  const int t = threadIdx.x;
  __shared__ float T1s[NR][ND];
  __shared__ float s2s[NR][NDH];
  __shared__ float attns[NR][NDH];

  const float* t1b = T1 + ((size_t)b * NRH + h * NR) * ND;
  for (int i = t; i < NR * ND / 4; i += 256) {
    int r = i >> 8;            // 256 float4 per row
    int c = (i & 255) * 4;
    *(float4*)&T1s[r][c] = *(const float4*)&t1b[(size_t)r * ND + c];
  }
  __syncthreads();

  // s2[r][d]: thread owns d = t&63, r in {t>>6, +4, +8}
  {
    int d  = t & 63;
    int rb = t >> 6;
    const float* wk = WK + (size_t)(h * NDH + d) * ND;
    float acc0 = 0.f, acc1 = 0.f, acc2 = 0.f;
    for (int e = 0; e < ND; e += 4) {
      float4 w  = *(const float4*)&wk[e];
      float4 x0 = *(const float4*)&T1s[rb][e];
      float4 x1 = *(const float4*)&T1s[rb + 4][e];
      float4 x2 = *(const float4*)&T1s[rb + 8][e];
      acc0 += w.x * x0.x + w.y * x0.y + w.z * x0.z + w.w * x0.w;
      acc1 += w.x * x1.x + w.y * x1.y + w.z * x1.z + w.w * x1.w;
      acc2 += w.x * x2.x + w.y * x2.y + w.z * x2.z + w.w * x2.w;
    }
    s2s[rb][d] = acc0; s2s[rb + 4][d] = acc1; s2s[rb + 8][d] = acc2;
  }
  __syncthreads();

  // softmax over dh=64, one wave handles 3 rows
  {
    int wave = t >> 6, lane = t & 63;
    for (int j = 0; j < 3; ++j) {
      int r = wave * 3 + j;
      float v = s2s[r][lane];
      float m = v;
#pragma unroll
      for (int off = 32; off > 0; off >>= 1) m = fmaxf(m, __shfl_xor(m, off));
      float e = __expf(v - m);
      float ssum = e;
#pragma unroll
      for (int off = 32; off > 0; off >>= 1) ssum += __shfl_xor(ssum, off);
      attns[r][lane] = e / ssum;
    }
  }
  __syncthreads();

  // A2[r][e] = sum_d attn[r][d] * WV[h*64+d][e]; thread owns 4 e's x 12 r's
  {
    int e0 = t * 4;
    float acc[NR][4];
#pragma unroll
    for (int r = 0; r < NR; ++r) {
      acc[r][0] = 0.f; acc[r][1] = 0.f; acc[r][2] = 0.f; acc[r][3] = 0.f;
    }
    const float* wv = WV + (size_t)h * NDH * ND + e0;
    for (int dd = 0; dd < NDH; ++dd) {
      float4 w = *(const float4*)&wv[(size_t)dd * ND];
#pragma unroll
      for (int r = 0; r < NR; ++r) {
        float a = attns[r][dd];
        acc[r][0] += a * w.x; acc[r][1] += a * w.y;
        acc[r][2] += a * w.z; acc[r][3] += a * w.w;
      }
    }
    float* a2b = A2 + ((size_t)b * NRH + h * NR) * ND + e0;
#pragma unroll
    for (int r = 0; r < NR; ++r) {
      float4 o;
      o.x = acc[r][0]; o.y = acc[r][1]; o.z = acc[r][2]; o.w = acc[r][3];
      *(float4*)&a2b[(size_t)r * ND] = o;
    }
  }
}

// ---------------------------------------------------------------------------
// LayerNorm over last dim (1024); one block per row
// ---------------------------------------------------------------------------
__global__ __launch_bounds__(256) void ln_k(const float* __restrict__ X,
                                            const float* __restrict__ gamma,
                                            const float* __restrict__ beta,
                                            float* __restrict__ out) {
  int row = blockIdx.x;
  int t = threadIdx.x;
  const float* x = X + (size_t)row * ND;
  float4 v = *(const float4*)&x[t * 4];
  float s  = v.x + v.y + v.z + v.w;
  float ss = v.x * v.x + v.y * v.y + v.z * v.z + v.w * v.w;
#pragma unroll
  for (int off = 32; off > 0; off >>= 1) {
    s  += __shfl_xor(s, off);
    ss += __shfl_xor(ss, off);
  }
  __shared__ float red[8];
  int wave = t >> 6, lane = t & 63;
  if (lane == 0) { red[wave] = s; red[4 + wave] = ss; }
  __syncthreads();
  s  = red[0] + red[1] + red[2] + red[3];
  ss = red[4] + red[5] + red[6] + red[7];
  float mu  = s * (1.0f / ND);
  float var = ss * (1.0f / ND) - mu * mu;
  float inv = rsqrtf(var + 1e-6f);
  float4 g  = *(const float4*)&gamma[t * 4];
  float4 be = *(const float4*)&beta[t * 4];
  float4 o;
  o.x = (v.x - mu) * inv * g.x + be.x;
  o.y = (v.y - mu) * inv * g.y + be.y;
  o.z = (v.z - mu) * inv * g.z + be.z;
  o.w = (v.w - mu) * inv * g.w + be.w;
  *(float4*)&out[(size_t)row * ND + t * 4] = o;
}

// ---------------------------------------------------------------------------
extern "C" void kernel_launch(void* const* d_in, const int* in_sizes, int n_in,
                              void* d_out, int out_size, void* d_ws, size_t ws_size,
                              hipStream_t stream) {
  const float* Q  = (const float*)d_in[0];
  const float* K  = (const float*)d_in[1];
  const float* V  = (const float*)d_in[2];
  const float* U  = (const float*)d_in[3];
  const float* WQ = (const float*)d_in[4];
  const float* WK = (const float*)d_in[5];
  const float* WV = (const float*)d_in[6];
  const float* WL = (const float*)d_in[7];
  const float* bl = (const float*)d_in[8];
  const float* ga = (const float*)d_in[9];
  const float* be = (const float*)d_in[10];
  float* out = (float*)d_out;
  float* ws  = (float*)d_ws;

  // workspace layout (floats)
  float* wq_eff = ws;                  // [4][192][1024]  786432
  float* s1t    = ws + 786432;         // [4][192][2048] 1572864
  float* t1     = ws + 2359296;        // [4][192][1024]  786432
  float* a2     = ws + 3145728;        // [4][192][1024]  786432
  float* ctx    = ws + 3932160;        // [4][384][1024] 1572864
  float* lin    = ws + 5505024;        // [4][384][1024] 1572864
  // total 7077888 floats = 28.3 MB

  // 1) fold U into W_Q
  build_wqeff<<<dim3(NB * NH * NR), 256, 0, stream>>>(U, WQ, wq_eff);

  // 2) s1^T[b][rh][s] = Wq_eff[b][rh] . Q[b][s]   (A@B^T)  M=192 N=2048 K=1024
  gemm_tile<true, 0><<<dim3(32, 3, NB), 256, 0, stream>>>(
      wq_eff, Q, s1t, nullptr, 192, 2048, 1024,
      192L * 1024, 2048L * 1024, 192L * 2048);

  // 3) T1[b][rh][e] = sum_s s1t[rh][s] K[b][s][e]  (A@B)  M=192 N=1024 K=2048
  gemm_tile<false, 0><<<dim3(16, 3, NB), 256, 0, stream>>>(
      s1t, K, t1, nullptr, 192, 1024, 2048,
      192L * 2048, 2048L * 1024, 192L * 1024);

  // 4) s2 = T1 @ WK_head^T ; softmax(dh) ; A2 = attn @ WV_head
  fused_sm<<<dim3(NB * NH), 256, 0, stream>>>(t1, WK, WV, a2);

  // 5) ctx[b][rh][s] = A2[b][rh] . V[b][s]  (A@B^T) -> [B,R,H,S] flat layout
  gemm_tile<true, 1><<<dim3(32, 3, NB), 256, 0, stream>>>(
      a2, V, ctx, nullptr, 192, 2048, 1024,
      192L * 1024, 2048L * 1024, 384L * 1024);

  // 6) lin = ctx_flat @ W_lin^T + b_lin   M=1536 N=1024 K=1024
  gemm_tile<true, 2><<<dim3(16, 24, 1), 256, 0, stream>>>(
      ctx, WL, lin, bl, 1536, 1024, 1024, 0, 0, 0);

  // 7) LayerNorm -> d_out
  ln_k<<<dim3(NB * 384), 256, 0, stream>>>(lin, ga, be, out);
}

// Round 2
// 201.841 us; speedup vs baseline: 1.7475x; 1.7475x over previous
//
#include <hip/hip_runtime.h>

#define NB 4
#define NS 2048
#define ND 1024
#define NH 16
#define NDH 64
#define NR 12
#define NRH 192

typedef __attribute__((ext_vector_type(8))) short bf16x8;
typedef __attribute__((ext_vector_type(4))) float f32x4;

__device__ __forceinline__ unsigned short rnbf(float f) {
  unsigned u = __float_as_uint(f);
  u += 0x7fffu + ((u >> 16) & 1u);
  return (unsigned short)(u >> 16);
}
__device__ __forceinline__ float bf2f(unsigned short h) {
  return __uint_as_float(((unsigned)h) << 16);
}

__device__ __forceinline__ void gload16(const void* g, void* l) {
  __builtin_amdgcn_global_load_lds(
      (const __attribute__((address_space(1))) unsigned int*)g,
      (__attribute__((address_space(3))) unsigned int*)l, 16, 0, 0);
}

#define MFMA(a, b, c) __builtin_amdgcn_mfma_f32_16x16x32_bf16(a, b, c, 0, 0, 0)

// ---------------------------------------------------------------------------
// fp32 -> bf16 hi/lo elementwise
// ---------------------------------------------------------------------------
__global__ __launch_bounds__(256) void cvt_hilo_k(const float* __restrict__ in,
                                                  unsigned short* __restrict__ hi,
                                                  unsigned short* __restrict__ lo,
                                                  int n4) {
  int i = blockIdx.x * 256 + threadIdx.x;
  int stride = gridDim.x * 256;
  for (; i < n4; i += stride) {
    float4 v = ((const float4*)in)[i];
    ushort4 h, l;
    h.x = rnbf(v.x); l.x = rnbf(v.x - bf2f(h.x));
    h.y = rnbf(v.y); l.y = rnbf(v.y - bf2f(h.y));
    h.z = rnbf(v.z); l.z = rnbf(v.z - bf2f(h.z));
    h.w = rnbf(v.w); l.w = rnbf(v.w - bf2f(h.w));
    ((ushort4*)hi)[i] = h;
    ((ushort4*)lo)[i] = l;
  }
}

// fp32 -> bf16 plain
__global__ __launch_bounds__(256) void cvt_bf_k(const float* __restrict__ in,
                                                unsigned short* __restrict__ o,
                                                int n4) {
  int i = blockIdx.x * 256 + threadIdx.x;
  int stride = gridDim.x * 256;
  for (; i < n4; i += stride) {
    float4 v = ((const float4*)in)[i];
    ushort4 h;
    h.x = rnbf(v.x); h.y = rnbf(v.y); h.z = rnbf(v.z); h.w = rnbf(v.w);
    ((ushort4*)o)[i] = h;
  }
}

// ---------------------------------------------------------------------------
// K [b][2048][1024] f32 -> KT hi/lo [b][1024][2048] bf16 (transpose + split)
// ---------------------------------------------------------------------------
__global__ __launch_bounds__(256) void cvt_t_hilo(const float* __restrict__ in,
                                                  unsigned short* __restrict__ ohi,
                                                  unsigned short* __restrict__ olo) {
  __shared__ float tbuf[64][65];
  int s0 = blockIdx.x * 64, e0 = blockIdx.y * 64, b = blockIdx.z;
  const float* src = in + ((size_t)b * NS + s0) * ND + e0;
  int tx = threadIdx.x & 15, ty = threadIdx.x >> 4;
#pragma unroll
  for (int rr = 0; rr < 4; ++rr) {
    int row = ty + rr * 16;
    float4 v = *(const float4*)&src[(size_t)row * ND + tx * 4];
    tbuf[row][tx * 4 + 0] = v.x; tbuf[row][tx * 4 + 1] = v.y;
    tbuf[row][tx * 4 + 2] = v.z; tbuf[row][tx * 4 + 3] = v.w;
  }
  __syncthreads();
  size_t obase = ((size_t)b * ND + e0) * NS + s0;
#pragma unroll
  for (int rr = 0; rr < 4; ++rr) {
    int el = ty + rr * 16;
    ushort4 h, l;
    float f0 = tbuf[tx * 4 + 0][el];
    float f1 = tbuf[tx * 4 + 1][el];
    float f2 = tbuf[tx * 4 + 2][el];
    float f3 = tbuf[tx * 4 + 3][el];
    h.x = rnbf(f0); l.x = rnbf(f0 - bf2f(h.x));
    h.y = rnbf(f1); l.y = rnbf(f1 - bf2f(h.y));
    h.z = rnbf(f2); l.z = rnbf(f2 - bf2f(h.z));
    h.w = rnbf(f3); l.w = rnbf(f3 - bf2f(h.w));
    *(ushort4*)&ohi[obase + (size_t)el * NS + tx * 4] = h;
    *(ushort4*)&olo[obase + (size_t)el * NS + tx * 4] = l;
  }
}

// ---------------------------------------------------------------------------
// Wq_eff[b,h,r,e] = sum_d U[b,h,r,d] * W_Q[h*64+d, e]  -> hi/lo bf16
// ---------------------------------------------------------------------------
__global__ __launch_bounds__(256) void build_wqeff(const float* __restrict__ U,
                                                   const float* __restrict__ WQ,
                                                   unsigned short* __restrict__ wqhi,
                                                   unsigned short* __restrict__ wqlo) {
  int idx = blockIdx.x;
  int hr = idx % (NH * NR);
  int h = hr / NR;
  __shared__ float u[NDH];
  int t = threadIdx.x;
  if (t < NDH) u[t] = U[(size_t)idx * NDH + t];
  __syncthreads();
  int e0 = t * 4;
  float a0 = 0.f, a1 = 0.f, a2 = 0.f, a3 = 0.f;
  const float* wbase = WQ + (size_t)h * NDH * ND + e0;
#pragma unroll 4
  for (int d = 0; d < NDH; ++d) {
    float uv = u[d];
    const float* wr = wbase + (size_t)d * ND;
    a0 += uv * wr[0]; a1 += uv * wr[1]; a2 += uv * wr[2]; a3 += uv * wr[3];
  }
  ushort4 h4, l4;
  h4.x = rnbf(a0); l4.x = rnbf(a0 - bf2f(h4.x));
  h4.y = rnbf(a1); l4.y = rnbf(a1 - bf2f(h4.y));
  h4.z = rnbf(a2); l4.z = rnbf(a2 - bf2f(h4.z));
  h4.w = rnbf(a3); l4.w = rnbf(a3 - bf2f(h4.w));
  *(ushort4*)&wqhi[(size_t)idx * ND + e0] = h4;
  *(ushort4*)&wqlo[(size_t)idx * ND + e0] = l4;
}

// ---------------------------------------------------------------------------
// MFMA GEMM: C[m][n] = sum_k A[m][k]*B[n][k]  (both row-major, K contiguous)
// SPLIT: A,B given as (hi,lo) pairs; acc = Ahi*Bhi + Ahi*Blo + Alo*Bhi
// BM=64, BN=128, BK=64; 256 threads = 4 waves (2x2); wave-tile 32x64.
// LDS linear tiles, XOR-swizzled via pre-swizzled global source (16B slots).
// EPI 0: C0 f32 [m][ldc]        (batched via sCb)
// EPI 1: C0/C1 bf16 hi/lo       (batched)
// EPI 2: C0 bf16, row remap m=(h*12+r) -> r*16+h  (batched)
// EPI 3: C0 f32 += bias[n]      (no batch)
// ---------------------------------------------------------------------------
template <bool SPLIT, int EPI>
__global__ __launch_bounds__(256) void mgemm(
    const unsigned short* __restrict__ Ahi, const unsigned short* __restrict__ Alo,
    const unsigned short* __restrict__ Bhi, const unsigned short* __restrict__ Blo,
    void* __restrict__ C0, void* __restrict__ C1, const float* __restrict__ bias,
    int K, int lda, int ldb, int ldc,
    long sAb, long sBb, long sCb) {
  constexpr int NBUF = SPLIT ? 2 : 1;
  __shared__ unsigned short As[NBUF][64 * 64];
  __shared__ unsigned short Bs[NBUF][128 * 64];
  const int tid = threadIdx.x;
  const int lane = tid & 63;
  const int wid = tid >> 6;
  const int wm = wid >> 1, wn = wid & 1;
  const int m0 = blockIdx.y * 64, n0 = blockIdx.x * 128;
  const int bz = blockIdx.z;
  const unsigned short* pAhi = Ahi + (size_t)bz * sAb;
  const unsigned short* pAlo = SPLIT ? (Alo + (size_t)bz * sAb) : nullptr;
  const unsigned short* pBhi = Bhi + (size_t)bz * sBb;
  const unsigned short* pBlo = SPLIT ? (Blo + (size_t)bz * sBb) : nullptr;

  const int rsub = lane >> 3;          // row within 8-row chunk
  const int slot = (lane & 7) ^ rsub;  // pre-swizzled source 16B slot

  f32x4 acc[2][4];
#pragma unroll
  for (int i = 0; i < 2; ++i)
#pragma unroll
    for (int j = 0; j < 4; ++j) acc[i][j] = (f32x4){0.f, 0.f, 0.f, 0.f};

  for (int k0 = 0; k0 < K; k0 += 64) {
    // ---- stage via global_load_lds (linear LDS dest, swizzled global src)
#pragma unroll
    for (int cc = 0; cc < 2; ++cc) {
      int c = wid * 2 + cc;
      int grow = m0 + c * 8 + rsub;
      gload16(&pAhi[(size_t)grow * lda + k0 + slot * 8], &As[0][c * 512]);
      if (SPLIT)
        gload16(&pAlo[(size_t)grow * lda + k0 + slot * 8], &As[NBUF - 1][c * 512]);
    }
#pragma unroll
    for (int cc = 0; cc < 4; ++cc) {
      int c = wid * 4 + cc;
      int grow = n0 + c * 8 + rsub;
      gload16(&pBhi[(size_t)grow * ldb + k0 + slot * 8], &Bs[0][c * 512]);
      if (SPLIT)
        gload16(&pBlo[(size_t)grow * ldb + k0 + slot * 8], &Bs[NBUF - 1][c * 512]);
    }
    __syncthreads();  // compiler drains vmcnt before s_barrier

    // ---- compute
#pragma unroll
    for (int kk = 0; kk < 64; kk += 32) {
      int sig = (kk >> 3) + (lane >> 4);
      bf16x8 ah[2], al[2], bh[4], bl[4];
#pragma unroll
      for (int fm = 0; fm < 2; ++fm) {
        int r = wm * 32 + fm * 16 + (lane & 15);
        int off = r * 128 + ((sig ^ (r & 7)) << 4);
        ah[fm] = *(const bf16x8*)((const char*)&As[0][0] + off);
        if (SPLIT) al[fm] = *(const bf16x8*)((const char*)&As[0][0] + 8192 + off);
      }
#pragma unroll
      for (int fn = 0; fn < 4; ++fn) {
        int r = wn * 64 + fn * 16 + (lane & 15);
        int off = r * 128 + ((sig ^ (r & 7)) << 4);
        bh[fn] = *(const bf16x8*)((const char*)&Bs[0][0] + off);
        if (SPLIT) bl[fn] = *(const bf16x8*)((const char*)&Bs[0][0] + 16384 + off);
      }
#pragma unroll
      for (int fm = 0; fm < 2; ++fm)
#pragma unroll
        for (int fn = 0; fn < 4; ++fn) {
          acc[fm][fn] = MFMA(ah[fm], bh[fn], acc[fm][fn]);
          if (SPLIT) {
            acc[fm][fn] = MFMA(ah[fm], bl[fn], acc[fm][fn]);
            acc[fm][fn] = MFMA(al[fm], bh[fn], acc[fm][fn]);
          }
        }
    }
    __syncthreads();  // all reads done before next stage overwrites
  }

  // ---- epilogue; C/D frag: col = lane&15, row = (lane>>4)*4 + j
  const int jr = lane >> 4, cl = lane & 15;
#pragma unroll
  for (int fm = 0; fm < 2; ++fm)
#pragma unroll
    for (int fn = 0; fn < 4; ++fn) {
      f32x4 v = acc[fm][fn];
      int gcol = n0 + wn * 64 + fn * 16 + cl;
#pragma unroll
      for (int j = 0; j < 4; ++j) {
        int m = m0 + wm * 32 + fm * 16 + jr * 4 + j;
        float x = v[j];
        if (EPI == 0) {
          ((float*)C0)[(size_t)bz * sCb + (size_t)m * ldc + gcol] = x;
        } else if (EPI == 1) {
          unsigned short h = rnbf(x);
          unsigned short l = rnbf(x - bf2f(h));
          ((unsigned short*)C0)[(size_t)bz * sCb + (size_t)m * ldc + gcol] = h;
          ((unsigned short*)C1)[(size_t)bz * sCb + (size_t)m * ldc + gcol] = l;
        } else if (EPI == 2) {
          int r = m % NR, hh = m / NR;
          ((unsigned short*)C0)[(size_t)bz * sCb + (size_t)(r * NH + hh) * ldc + gcol] =
              rnbf(x);
        } else {
          ((float*)C0)[(size_t)m * ldc + gcol] = x + bias[gcol];
        }
      }
    }
}

// ---------------------------------------------------------------------------
// fused: s2 = T1 @ WK_head^T -> softmax(dh) -> A2 = attn @ WV_head (bf16 out)
// ---------------------------------------------------------------------------
__global__ __launch_bounds__(256) void fused_sm(const float* __restrict__ T1,
                                                const float* __restrict__ WK,
                                                const float* __restrict__ WV,
                                                unsigned short* __restrict__ A2) {
  int h = blockIdx.x & 15;
  int b = blockIdx.x >> 4;
  const int t = threadIdx.x;
  __shared__ float T1s[NR][ND];
  __shared__ float s2s[NR][NDH];
  __shared__ float attns[NR][NDH];

  const float* t1b = T1 + ((size_t)b * NRH + h * NR) * ND;
  for (int i = t; i < NR * ND / 4; i += 256) {
    int r = i >> 8;
    int c = (i & 255) * 4;
    *(float4*)&T1s[r][c] = *(const float4*)&t1b[(size_t)r * ND + c];
  }
  __syncthreads();

  {
    int d = t & 63;
    int rb = t >> 6;
    const float* wk = WK + (size_t)(h * NDH + d) * ND;
    float acc0 = 0.f, acc1 = 0.f, acc2 = 0.f;
    for (int e = 0; e < ND; e += 4) {
      float4 w = *(const float4*)&wk[e];
      float4 x0 = *(const float4*)&T1s[rb][e];
      float4 x1 = *(const float4*)&T1s[rb + 4][e];
      float4 x2 = *(const float4*)&T1s[rb + 8][e];
      acc0 += w.x * x0.x + w.y * x0.y + w.z * x0.z + w.w * x0.w;
      acc1 += w.x * x1.x + w.y * x1.y + w.z * x1.z + w.w * x1.w;
      acc2 += w.x * x2.x + w.y * x2.y + w.z * x2.z + w.w * x2.w;
    }
    s2s[rb][d] = acc0; s2s[rb + 4][d] = acc1; s2s[rb + 8][d] = acc2;
  }
  __syncthreads();

  {
    int wave = t >> 6, lane = t & 63;
    for (int j = 0; j < 3; ++j) {
      int r = wave * 3 + j;
      float v = s2s[r][lane];
      float m = v;
#pragma unroll
      for (int off = 32; off > 0; off >>= 1) m = fmaxf(m, __shfl_xor(m, off));
      float e = __expf(v - m);
      float ssum = e;
#pragma unroll
      for (int off = 32; off > 0; off >>= 1) ssum += __shfl_xor(ssum, off);
      attns[r][lane] = e / ssum;
    }
  }
  __syncthreads();

  {
    int e0 = t * 4;
    float acc[NR][4];
#pragma unroll
    for (int r = 0; r < NR; ++r) {
      acc[r][0] = 0.f; acc[r][1] = 0.f; acc[r][2] = 0.f; acc[r][3] = 0.f;
    }
    const float* wv = WV + (size_t)h * NDH * ND + e0;
    for (int dd = 0; dd < NDH; ++dd) {
      float4 w = *(const float4*)&wv[(size_t)dd * ND];
#pragma unroll
      for (int r = 0; r < NR; ++r) {
        float a = attns[r][dd];
        acc[r][0] += a * w.x; acc[r][1] += a * w.y;
        acc[r][2] += a * w.z; acc[r][3] += a * w.w;
      }
    }
    unsigned short* a2b = A2 + ((size_t)b * NRH + h * NR) * ND + e0;
#pragma unroll
    for (int r = 0; r < NR; ++r) {
      ushort4 o;
      o.x = rnbf(acc[r][0]); o.y = rnbf(acc[r][1]);
      o.z = rnbf(acc[r][2]); o.w = rnbf(acc[r][3]);
      *(ushort4*)&a2b[(size_t)r * ND] = o;
    }
  }
}

// ---------------------------------------------------------------------------
// LayerNorm over last dim (1024)
// ---------------------------------------------------------------------------
__global__ __launch_bounds__(256) void ln_k(const float* __restrict__ X,
                                            const float* __restrict__ gamma,
                                            const float* __restrict__ beta,
                                            float* __restrict__ out) {
  int row = blockIdx.x;
  int t = threadIdx.x;
  const float* x = X + (size_t)row * ND;
  float4 v = *(const float4*)&x[t * 4];
  float s = v.x + v.y + v.z + v.w;
  float ss = v.x * v.x + v.y * v.y + v.z * v.z + v.w * v.w;
#pragma unroll
  for (int off = 32; off > 0; off >>= 1) {
    s += __shfl_xor(s, off);
    ss += __shfl_xor(ss, off);
  }
  __shared__ float red[8];
  int wave = t >> 6, lane = t & 63;
  if (lane == 0) { red[wave] = s; red[4 + wave] = ss; }
  __syncthreads();
  s = red[0] + red[1] + red[2] + red[3];
  ss = red[4] + red[5] + red[6] + red[7];
  float mu = s * (1.0f / ND);
  float var = ss * (1.0f / ND) - mu * mu;
  float inv = rsqrtf(var + 1e-6f);
  float4 g = *(const float4*)&gamma[t * 4];
  float4 be = *(const float4*)&beta[t * 4];
  float4 o;
  o.x = (v.x - mu) * inv * g.x + be.x;
  o.y = (v.y - mu) * inv * g.y + be.y;
  o.z = (v.z - mu) * inv * g.z + be.z;
  o.w = (v.w - mu) * inv * g.w + be.w;
  *(float4*)&out[(size_t)row * ND + t * 4] = o;
}

// ---------------------------------------------------------------------------
extern "C" void kernel_launch(void* const* d_in, const int* in_sizes, int n_in,
                              void* d_out, int out_size, void* d_ws, size_t ws_size,
                              hipStream_t stream) {
  const float* Q = (const float*)d_in[0];
  const float* K = (const float*)d_in[1];
  const float* V = (const float*)d_in[2];
  const float* U = (const float*)d_in[3];
  const float* WQ = (const float*)d_in[4];
  const float* WK = (const float*)d_in[5];
  const float* WV = (const float*)d_in[6];
  const float* WL = (const float*)d_in[7];
  const float* bl = (const float*)d_in[8];
  const float* ga = (const float*)d_in[9];
  const float* be = (const float*)d_in[10];
  float* out = (float*)d_out;
  char* w = (char*)d_ws;

  // big shared region (33.5 MB), reused sequentially:
  //   phase 1: Qhi/Qlo  ->  phase 2: KThi/KTlo  ->  phase 3: Vb
  unsigned short* Qhi = (unsigned short*)w;
  unsigned short* Qlo = (unsigned short*)(w + 16777216);
  unsigned short* KThi = (unsigned short*)w;
  unsigned short* KTlo = (unsigned short*)(w + 16777216);
  unsigned short* Vb = (unsigned short*)w;
  size_t off = 33554432;
  unsigned short* wqhi = (unsigned short*)(w + off); off += 1572864;
  unsigned short* wqlo = (unsigned short*)(w + off); off += 1572864;
  unsigned short* s1hi = (unsigned short*)(w + off); off += 3145728;
  unsigned short* s1lo = (unsigned short*)(w + off); off += 3145728;
  float* T1 = (float*)(w + off); off += 3145728;
  unsigned short* A2b = (unsigned short*)(w + off); off += 1572864;
  unsigned short* ctxb = (unsigned short*)(w + off); off += 3145728;
  unsigned short* WLb = (unsigned short*)(w + off); off += 2097152;
  float* lin = (float*)(w + off); off += 6291456;  // ~59.2 MB total

  // converts
  cvt_bf_k<<<1024, 256, 0, stream>>>(WL, WLb, ND * ND / 4);
  cvt_hilo_k<<<2048, 256, 0, stream>>>(Q, Qhi, Qlo, NB * NS * ND / 4);
  build_wqeff<<<NB * NH * NR, 256, 0, stream>>>(U, WQ, wqhi, wqlo);

  // G1: s1[rh][s] = wq_eff[rh] . Q[s]  (SPLIT, out hi/lo bf16)
  // M=192 N=2048 K=1024
  mgemm<true, 1><<<dim3(16, 3, NB), 256, 0, stream>>>(
      wqhi, wqlo, Qhi, Qlo, s1hi, s1lo, nullptr,
      1024, 1024, 1024, 2048, 192L * 1024, 2048L * 1024, 192L * 2048);

  // K -> KT hi/lo (reuses Q region; stream-ordered after G1)
  cvt_t_hilo<<<dim3(32, 16, NB), 256, 0, stream>>>(K, KThi, KTlo);

  // G2: T1[rh][e] = s1[rh] . KT[e]  (SPLIT, out f32)
  // M=192 N=1024 K=2048
  mgemm<true, 0><<<dim3(8, 3, NB), 256, 0, stream>>>(
      s1hi, s1lo, KThi, KTlo, T1, nullptr, nullptr,
      2048, 2048, 2048, 1024, 192L * 2048, 1024L * 2048, 192L * 1024);

  // s2 -> softmax -> A2 (bf16 out)
  fused_sm<<<NB * NH, 256, 0, stream>>>(T1, WK, WV, A2b);

  // V -> bf16 (reuses region)
  cvt_bf_k<<<2048, 256, 0, stream>>>(V, Vb, NB * NS * ND / 4);

  // G3: ctx[rh][s] = A2[rh] . V[s]  (plain bf16, remapped rows r*16+h)
  // M=192 N=2048 K=1024
  mgemm<false, 2><<<dim3(16, 3, NB), 256, 0, stream>>>(
      A2b, nullptr, Vb, nullptr, ctxb, nullptr, nullptr,
      1024, 1024, 1024, 2048, 192L * 1024, 2048L * 1024, 192L * 2048);

  // G4: lin = ctx_flat @ WL^T + bias   M=1536 N=1024 K=1024
  mgemm<false, 3><<<dim3(8, 24, 1), 256, 0, stream>>>(
      ctxb, nullptr, WLb, nullptr, lin, nullptr, bl,
      1024, 1024, 1024, 1024, 0, 0, 0);

  // LayerNorm
  ln_k<<<NB * 384, 256, 0, stream>>>(lin, ga, be, out);
}

// Round 3
// 180.886 us; speedup vs baseline: 1.9500x; 1.1158x over previous
//
#include <hip/hip_runtime.h>

#define NB 4
#define NS 2048
#define ND 1024
#define NH 16
#define NDH 64
#define NR 12
#define NRH 192

typedef __attribute__((ext_vector_type(8))) short bf16x8;
typedef __attribute__((ext_vector_type(4))) float f32x4;

__device__ __forceinline__ unsigned short rnbf(float f) {
  unsigned u = __float_as_uint(f);
  u += 0x7fffu + ((u >> 16) & 1u);
  return (unsigned short)(u >> 16);
}
__device__ __forceinline__ float bf2f(unsigned short h) {
  return __uint_as_float(((unsigned)h) << 16);
}

__device__ __forceinline__ void gload16(const void* g, void* l) {
  __builtin_amdgcn_global_load_lds(
      (const __attribute__((address_space(1))) unsigned int*)g,
      (__attribute__((address_space(3))) unsigned int*)l, 16, 0, 0);
}

#define MFMA(a, b, c) __builtin_amdgcn_mfma_f32_16x16x32_bf16(a, b, c, 0, 0, 0)

// ---------------------------------------------------------------------------
// fp32 -> bf16 hi/lo elementwise
// ---------------------------------------------------------------------------
__global__ __launch_bounds__(256) void cvt_hilo_k(const float* __restrict__ in,
                                                  unsigned short* __restrict__ hi,
                                                  unsigned short* __restrict__ lo,
                                                  int n4) {
  int i = blockIdx.x * 256 + threadIdx.x;
  int stride = gridDim.x * 256;
  for (; i < n4; i += stride) {
    float4 v = ((const float4*)in)[i];
    ushort4 h, l;
    h.x = rnbf(v.x); l.x = rnbf(v.x - bf2f(h.x));
    h.y = rnbf(v.y); l.y = rnbf(v.y - bf2f(h.y));
    h.z = rnbf(v.z); l.z = rnbf(v.z - bf2f(h.z));
    h.w = rnbf(v.w); l.w = rnbf(v.w - bf2f(h.w));
    ((ushort4*)hi)[i] = h;
    ((ushort4*)lo)[i] = l;
  }
}

// fp32 -> bf16 plain
__global__ __launch_bounds__(256) void cvt_bf_k(const float* __restrict__ in,
                                                unsigned short* __restrict__ o,
                                                int n4) {
  int i = blockIdx.x * 256 + threadIdx.x;
  int stride = gridDim.x * 256;
  for (; i < n4; i += stride) {
    float4 v = ((const float4*)in)[i];
    ushort4 h;
    h.x = rnbf(v.x); h.y = rnbf(v.y); h.z = rnbf(v.z); h.w = rnbf(v.w);
    ((ushort4*)o)[i] = h;
  }
}

// ---------------------------------------------------------------------------
// K [b][2048][1024] f32 -> KT hi/lo [b][1024][2048] bf16 (transpose + split)
// ---------------------------------------------------------------------------
__global__ __launch_bounds__(256) void cvt_t_hilo(const float* __restrict__ in,
                                                  unsigned short* __restrict__ ohi,
                                                  unsigned short* __restrict__ olo) {
  __shared__ float tbuf[64][65];
  int s0 = blockIdx.x * 64, e0 = blockIdx.y * 64, b = blockIdx.z;
  const float* src = in + ((size_t)b * NS + s0) * ND + e0;
  int tx = threadIdx.x & 15, ty = threadIdx.x >> 4;
#pragma unroll
  for (int rr = 0; rr < 4; ++rr) {
    int row = ty + rr * 16;
    float4 v = *(const float4*)&src[(size_t)row * ND + tx * 4];
    tbuf[row][tx * 4 + 0] = v.x; tbuf[row][tx * 4 + 1] = v.y;
    tbuf[row][tx * 4 + 2] = v.z; tbuf[row][tx * 4 + 3] = v.w;
  }
  __syncthreads();
  size_t obase = ((size_t)b * ND + e0) * NS + s0;
#pragma unroll
  for (int rr = 0; rr < 4; ++rr) {
    int el = ty + rr * 16;
    ushort4 h, l;
    float f0 = tbuf[tx * 4 + 0][el];
    float f1 = tbuf[tx * 4 + 1][el];
    float f2 = tbuf[tx * 4 + 2][el];
    float f3 = tbuf[tx * 4 + 3][el];
    h.x = rnbf(f0); l.x = rnbf(f0 - bf2f(h.x));
    h.y = rnbf(f1); l.y = rnbf(f1 - bf2f(h.y));
    h.z = rnbf(f2); l.z = rnbf(f2 - bf2f(h.z));
    h.w = rnbf(f3); l.w = rnbf(f3 - bf2f(h.w));
    *(ushort4*)&ohi[obase + (size_t)el * NS + tx * 4] = h;
    *(ushort4*)&olo[obase + (size_t)el * NS + tx * 4] = l;
  }
}

// ---------------------------------------------------------------------------
// f32 [rows][cols] -> transpose [cols][rows]
// ---------------------------------------------------------------------------
__global__ __launch_bounds__(256) void transpose_k(const float* __restrict__ in,
                                                   float* __restrict__ out,
                                                   int rows, int cols) {
  __shared__ float tb[64][65];
  int r0 = blockIdx.y * 64, c0 = blockIdx.x * 64;
  int tx = threadIdx.x & 15, ty = threadIdx.x >> 4;
#pragma unroll
  for (int rr = 0; rr < 4; ++rr) {
    int row = ty + rr * 16;
    float4 v = *(const float4*)&in[(size_t)(r0 + row) * cols + c0 + tx * 4];
    tb[row][tx * 4 + 0] = v.x; tb[row][tx * 4 + 1] = v.y;
    tb[row][tx * 4 + 2] = v.z; tb[row][tx * 4 + 3] = v.w;
  }
  __syncthreads();
#pragma unroll
  for (int rr = 0; rr < 4; ++rr) {
    int orow = ty + rr * 16;
    float4 o;
    o.x = tb[tx * 4 + 0][orow];
    o.y = tb[tx * 4 + 1][orow];
    o.z = tb[tx * 4 + 2][orow];
    o.w = tb[tx * 4 + 3][orow];
    *(float4*)&out[(size_t)(c0 + orow) * rows + r0 + tx * 4] = o;
  }
}

// ---------------------------------------------------------------------------
// Wq_eff[b,h,r,e] = sum_d U[b,h,r,d] * W_Q[h*64+d, e]  -> hi/lo bf16
// ---------------------------------------------------------------------------
__global__ __launch_bounds__(256) void build_wqeff(const float* __restrict__ U,
                                                   const float* __restrict__ WQ,
                                                   unsigned short* __restrict__ wqhi,
                                                   unsigned short* __restrict__ wqlo) {
  int idx = blockIdx.x;
  int hr = idx % (NH * NR);
  int h = hr / NR;
  __shared__ float u[NDH];
  int t = threadIdx.x;
  if (t < NDH) u[t] = U[(size_t)idx * NDH + t];
  __syncthreads();
  int e0 = t * 4;
  float a0 = 0.f, a1 = 0.f, a2 = 0.f, a3 = 0.f;
  const float* wbase = WQ + (size_t)h * NDH * ND + e0;
#pragma unroll 4
  for (int d = 0; d < NDH; ++d) {
    float uv = u[d];
    const float* wr = wbase + (size_t)d * ND;
    a0 += uv * wr[0]; a1 += uv * wr[1]; a2 += uv * wr[2]; a3 += uv * wr[3];
  }
  ushort4 h4, l4;
  h4.x = rnbf(a0); l4.x = rnbf(a0 - bf2f(h4.x));
  h4.y = rnbf(a1); l4.y = rnbf(a1 - bf2f(h4.y));
  h4.z = rnbf(a2); l4.z = rnbf(a2 - bf2f(h4.z));
  h4.w = rnbf(a3); l4.w = rnbf(a3 - bf2f(h4.w));
  *(ushort4*)&wqhi[(size_t)idx * ND + e0] = h4;
  *(ushort4*)&wqlo[(size_t)idx * ND + e0] = l4;
}

// ---------------------------------------------------------------------------
// MFMA GEMM: C[m][n] = sum_k A[m][k]*B[n][k]  (both row-major, K contiguous)
// (unchanged from round 1 — see comments there)
// ---------------------------------------------------------------------------
template <bool SPLIT, int EPI>
__global__ __launch_bounds__(256) void mgemm(
    const unsigned short* __restrict__ Ahi, const unsigned short* __restrict__ Alo,
    const unsigned short* __restrict__ Bhi, const unsigned short* __restrict__ Blo,
    void* __restrict__ C0, void* __restrict__ C1, const float* __restrict__ bias,
    int K, int lda, int ldb, int ldc,
    long sAb, long sBb, long sCb) {
  constexpr int NBUF = SPLIT ? 2 : 1;
  __shared__ unsigned short As[NBUF][64 * 64];
  __shared__ unsigned short Bs[NBUF][128 * 64];
  const int tid = threadIdx.x;
  const int lane = tid & 63;
  const int wid = tid >> 6;
  const int wm = wid >> 1, wn = wid & 1;
  const int m0 = blockIdx.y * 64, n0 = blockIdx.x * 128;
  const int bz = blockIdx.z;
  const unsigned short* pAhi = Ahi + (size_t)bz * sAb;
  const unsigned short* pAlo = SPLIT ? (Alo + (size_t)bz * sAb) : nullptr;
  const unsigned short* pBhi = Bhi + (size_t)bz * sBb;
  const unsigned short* pBlo = SPLIT ? (Blo + (size_t)bz * sBb) : nullptr;

  const int rsub = lane >> 3;
  const int slot = (lane & 7) ^ rsub;

  f32x4 acc[2][4];
#pragma unroll
  for (int i = 0; i < 2; ++i)
#pragma unroll
    for (int j = 0; j < 4; ++j) acc[i][j] = (f32x4){0.f, 0.f, 0.f, 0.f};

  for (int k0 = 0; k0 < K; k0 += 64) {
#pragma unroll
    for (int cc = 0; cc < 2; ++cc) {
      int c = wid * 2 + cc;
      int grow = m0 + c * 8 + rsub;
      gload16(&pAhi[(size_t)grow * lda + k0 + slot * 8], &As[0][c * 512]);
      if (SPLIT)
        gload16(&pAlo[(size_t)grow * lda + k0 + slot * 8], &As[NBUF - 1][c * 512]);
    }
#pragma unroll
    for (int cc = 0; cc < 4; ++cc) {
      int c = wid * 4 + cc;
      int grow = n0 + c * 8 + rsub;
      gload16(&pBhi[(size_t)grow * ldb + k0 + slot * 8], &Bs[0][c * 512]);
      if (SPLIT)
        gload16(&pBlo[(size_t)grow * ldb + k0 + slot * 8], &Bs[NBUF - 1][c * 512]);
    }
    __syncthreads();

#pragma unroll
    for (int kk = 0; kk < 64; kk += 32) {
      int sig = (kk >> 3) + (lane >> 4);
      bf16x8 ah[2], al[2], bh[4], bl[4];
#pragma unroll
      for (int fm = 0; fm < 2; ++fm) {
        int r = wm * 32 + fm * 16 + (lane & 15);
        int off = r * 128 + ((sig ^ (r & 7)) << 4);
        ah[fm] = *(const bf16x8*)((const char*)&As[0][0] + off);
        if (SPLIT) al[fm] = *(const bf16x8*)((const char*)&As[0][0] + 8192 + off);
      }
#pragma unroll
      for (int fn = 0; fn < 4; ++fn) {
        int r = wn * 64 + fn * 16 + (lane & 15);
        int off = r * 128 + ((sig ^ (r & 7)) << 4);
        bh[fn] = *(const bf16x8*)((const char*)&Bs[0][0] + off);
        if (SPLIT) bl[fn] = *(const bf16x8*)((const char*)&Bs[0][0] + 16384 + off);
      }
#pragma unroll
      for (int fm = 0; fm < 2; ++fm)
#pragma unroll
        for (int fn = 0; fn < 4; ++fn) {
          acc[fm][fn] = MFMA(ah[fm], bh[fn], acc[fm][fn]);
          if (SPLIT) {
            acc[fm][fn] = MFMA(ah[fm], bl[fn], acc[fm][fn]);
            acc[fm][fn] = MFMA(al[fm], bh[fn], acc[fm][fn]);
          }
        }
    }
    __syncthreads();
  }

  const int jr = lane >> 4, cl = lane & 15;
#pragma unroll
  for (int fm = 0; fm < 2; ++fm)
#pragma unroll
    for (int fn = 0; fn < 4; ++fn) {
      f32x4 v = acc[fm][fn];
      int gcol = n0 + wn * 64 + fn * 16 + cl;
#pragma unroll
      for (int j = 0; j < 4; ++j) {
        int m = m0 + wm * 32 + fm * 16 + jr * 4 + j;
        float x = v[j];
        if (EPI == 0) {
          ((float*)C0)[(size_t)bz * sCb + (size_t)m * ldc + gcol] = x;
        } else if (EPI == 1) {
          unsigned short h = rnbf(x);
          unsigned short l = rnbf(x - bf2f(h));
          ((unsigned short*)C0)[(size_t)bz * sCb + (size_t)m * ldc + gcol] = h;
          ((unsigned short*)C1)[(size_t)bz * sCb + (size_t)m * ldc + gcol] = l;
        } else if (EPI == 2) {
          int r = m % NR, hh = m / NR;
          ((unsigned short*)C0)[(size_t)bz * sCb + (size_t)(r * NH + hh) * ldc + gcol] =
              rnbf(x);
        } else {
          ((float*)C0)[(size_t)m * ldc + gcol] = x + bias[gcol];
        }
      }
    }
}

// ---------------------------------------------------------------------------
// sm_k: one block per (b,h,r).  s2[d] = sum_e T1[bhr][e]*WKT[e][h64+d] (f32),
// softmax over d=64, A2[bhr][e] = sum_d attn[d]*WV[h64+d][e] -> bf16.
// Block decode keeps h % 8 == blockIdx.x % 8 (XCD-pinned heads for L2).
// ---------------------------------------------------------------------------
__global__ __launch_bounds__(256) void sm_k(const float* __restrict__ T1,
                                            const float* __restrict__ WKT,
                                            const float* __restrict__ WV,
                                            unsigned short* __restrict__ A2) {
  int x = blockIdx.x;
  int xcd = x & 7, within = x >> 3;
  int h = xcd + 8 * (within & 1);
  int rb = within >> 1;           // 48 = r*4 + b
  int r = rb >> 2, b = rb & 3;
  int idx = (b * NH + h) * NR + r;

  const int t = threadIdx.x;
  __shared__ float t1s[ND];
  __shared__ float part[4][NDH];
  __shared__ float attns[NDH];

  ((float4*)t1s)[t] = ((const float4*)(T1 + (size_t)idx * ND))[t];
  __syncthreads();

  // s2 partials: lane d = t&63, quarter q = t>>6
  {
    int d = t & 63, q = t >> 6;
    const float* wcol = WKT + (size_t)(h * NDH + d);
    float acc = 0.f;
    int e0 = q * 256;
#pragma unroll 8
    for (int e = 0; e < 256; ++e)
      acc += t1s[e0 + e] * wcol[(size_t)(e0 + e) * ND];
    part[q][d] = acc;
  }
  __syncthreads();

  if (t < NDH) {
    float s2 = part[0][t] + part[1][t] + part[2][t] + part[3][t];
    float m = s2;
#pragma unroll
    for (int off = 32; off > 0; off >>= 1) m = fmaxf(m, __shfl_xor(m, off));
    float e = __expf(s2 - m);
    float sum = e;
#pragma unroll
    for (int off = 32; off > 0; off >>= 1) sum += __shfl_xor(sum, off);
    attns[t] = e / sum;
  }
  __syncthreads();

  // A2 row
  {
    int e0 = t * 4;
    const float* wv = WV + (size_t)h * NDH * ND + e0;
    float a0 = 0.f, a1 = 0.f, a2 = 0.f, a3 = 0.f;
#pragma unroll 4
    for (int dd = 0; dd < NDH; ++dd) {
      float4 wvv = *(const float4*)&wv[(size_t)dd * ND];
      float a = attns[dd];
      a0 += a * wvv.x; a1 += a * wvv.y; a2 += a * wvv.z; a3 += a * wvv.w;
    }
    ushort4 o;
    o.x = rnbf(a0); o.y = rnbf(a1); o.z = rnbf(a2); o.w = rnbf(a3);
    *(ushort4*)&A2[(size_t)idx * ND + e0] = o;
  }
}

// ---------------------------------------------------------------------------
// LayerNorm over last dim (1024)
// ---------------------------------------------------------------------------
__global__ __launch_bounds__(256) void ln_k(const float* __restrict__ X,
                                            const float* __restrict__ gamma,
                                            const float* __restrict__ beta,
                                            float* __restrict__ out) {
  int row = blockIdx.x;
  int t = threadIdx.x;
  const float* x = X + (size_t)row * ND;
  float4 v = *(const float4*)&x[t * 4];
  float s = v.x + v.y + v.z + v.w;
  float ss = v.x * v.x + v.y * v.y + v.z * v.z + v.w * v.w;
#pragma unroll
  for (int off = 32; off > 0; off >>= 1) {
    s += __shfl_xor(s, off);
    ss += __shfl_xor(ss, off);
  }
  __shared__ float red[8];
  int wave = t >> 6, lane = t & 63;
  if (lane == 0) { red[wave] = s; red[4 + wave] = ss; }
  __syncthreads();
  s = red[0] + red[1] + red[2] + red[3];
  ss = red[4] + red[5] + red[6] + red[7];
  float mu = s * (1.0f / ND);
  float var = ss * (1.0f / ND) - mu * mu;
  float inv = rsqrtf(var + 1e-6f);
  float4 g = *(const float4*)&gamma[t * 4];
  float4 be = *(const float4*)&beta[t * 4];
  float4 o;
  o.x = (v.x - mu) * inv * g.x + be.x;
  o.y = (v.y - mu) * inv * g.y + be.y;
  o.z = (v.z - mu) * inv * g.z + be.z;
  o.w = (v.w - mu) * inv * g.w + be.w;
  *(float4*)&out[(size_t)row * ND + t * 4] = o;
}

// ---------------------------------------------------------------------------
extern "C" void kernel_launch(void* const* d_in, const int* in_sizes, int n_in,
                              void* d_out, int out_size, void* d_ws, size_t ws_size,
                              hipStream_t stream) {
  const float* Q = (const float*)d_in[0];
  const float* K = (const float*)d_in[1];
  const float* V = (const float*)d_in[2];
  const float* U = (const float*)d_in[3];
  const float* WQ = (const float*)d_in[4];
  const float* WK = (const float*)d_in[5];
  const float* WV = (const float*)d_in[6];
  const float* WL = (const float*)d_in[7];
  const float* bl = (const float*)d_in[8];
  const float* ga = (const float*)d_in[9];
  const float* be = (const float*)d_in[10];
  float* out = (float*)d_out;
  char* w = (char*)d_ws;

  // region A (0..32MB), reused: Qhi/Qlo -> KThi/KTlo -> Vb
  unsigned short* Qhi = (unsigned short*)w;
  unsigned short* Qlo = (unsigned short*)(w + 16777216);
  unsigned short* KThi = (unsigned short*)w;
  unsigned short* KTlo = (unsigned short*)(w + 16777216);
  unsigned short* Vb = (unsigned short*)w;
  size_t off = 33554432;
  unsigned short* wqhi = (unsigned short*)(w + off); off += 1572864;
  unsigned short* wqlo = (unsigned short*)(w + off); off += 1572864;
  unsigned short* s1hi = (unsigned short*)(w + off); off += 3145728;
  unsigned short* s1lo = (unsigned short*)(w + off); off += 3145728;
  float* WKT = (float*)s1hi;  // 4MB, reuses s1hi+s1lo region after G2
  float* T1 = (float*)(w + off); off += 3145728;
  unsigned short* A2b = (unsigned short*)(w + off); off += 1572864;
  unsigned short* ctxb = (unsigned short*)(w + off); off += 3145728;
  unsigned short* WLb = (unsigned short*)(w + off); off += 2097152;
  float* lin = (float*)(w + off); off += 6291456;

  cvt_bf_k<<<1024, 256, 0, stream>>>(WL, WLb, ND * ND / 4);
  cvt_hilo_k<<<2048, 256, 0, stream>>>(Q, Qhi, Qlo, NB * NS * ND / 4);
  build_wqeff<<<NB * NH * NR, 256, 0, stream>>>(U, WQ, wqhi, wqlo);

  // G1: s1[rh][s] = wq_eff[rh] . Q[s]  (SPLIT, out hi/lo bf16)
  mgemm<true, 1><<<dim3(16, 3, NB), 256, 0, stream>>>(
      wqhi, wqlo, Qhi, Qlo, s1hi, s1lo, nullptr,
      1024, 1024, 1024, 2048, 192L * 1024, 2048L * 1024, 192L * 2048);

  cvt_t_hilo<<<dim3(32, 16, NB), 256, 0, stream>>>(K, KThi, KTlo);

  // G2: T1[rh][e] = s1[rh] . KT[e]  (SPLIT, out f32)
  mgemm<true, 0><<<dim3(8, 3, NB), 256, 0, stream>>>(
      s1hi, s1lo, KThi, KTlo, T1, nullptr, nullptr,
      2048, 2048, 2048, 1024, 192L * 2048, 1024L * 2048, 192L * 1024);

  // WK -> WKT (s1 region is dead after G2)
  transpose_k<<<dim3(16, 16), 256, 0, stream>>>(WK, WKT, ND, ND);

  // s2 -> softmax -> A2 (768 blocks, XCD-pinned heads)
  sm_k<<<NB * NH * NR, 256, 0, stream>>>(T1, WKT, WV, A2b);

  cvt_bf_k<<<2048, 256, 0, stream>>>(V, Vb, NB * NS * ND / 4);

  // G3: ctx[rh][s] = A2[rh] . V[s]  (bf16, remapped rows r*16+h)
  mgemm<false, 2><<<dim3(16, 3, NB), 256, 0, stream>>>(
      A2b, nullptr, Vb, nullptr, ctxb, nullptr, nullptr,
      1024, 1024, 1024, 2048, 192L * 1024, 2048L * 1024, 192L * 2048);

  // G4: lin = ctx_flat @ WL^T + bias
  mgemm<false, 3><<<dim3(8, 24, 1), 256, 0, stream>>>(
      ctxb, nullptr, WLb, nullptr, lin, nullptr, bl,
      1024, 1024, 1024, 1024, 0, 0, 0);

  ln_k<<<NB * 384, 256, 0, stream>>>(lin, ga, be, out);
}

// Round 4
// 167.030 us; speedup vs baseline: 2.1117x; 1.0830x over previous
//
#include <hip/hip_runtime.h>

#define NB 4
#define NS 2048
#define ND 1024
#define NH 16
#define NDH 64
#define NR 12
#define NRH 192

typedef __attribute__((ext_vector_type(8))) short bf16x8;
typedef __attribute__((ext_vector_type(4))) float f32x4;

__device__ __forceinline__ unsigned short rnbf(float f) {
  unsigned u = __float_as_uint(f);
  u += 0x7fffu + ((u >> 16) & 1u);
  return (unsigned short)(u >> 16);
}
__device__ __forceinline__ float bf2f(unsigned short h) {
  return __uint_as_float(((unsigned)h) << 16);
}

__device__ __forceinline__ void gload16(const void* g, void* l) {
  __builtin_amdgcn_global_load_lds(
      (const __attribute__((address_space(1))) unsigned int*)g,
      (__attribute__((address_space(3))) unsigned int*)l, 16, 0, 0);
}

#define MFMA(a, b, c) __builtin_amdgcn_mfma_f32_16x16x32_bf16(a, b, c, 0, 0, 0)

// ---------------------------------------------------------------------------
// fp32 -> bf16 hi/lo elementwise
// ---------------------------------------------------------------------------
__global__ __launch_bounds__(256) void cvt_hilo_k(const float* __restrict__ in,
                                                  unsigned short* __restrict__ hi,
                                                  unsigned short* __restrict__ lo,
                                                  int n4) {
  int i = blockIdx.x * 256 + threadIdx.x;
  int stride = gridDim.x * 256;
  for (; i < n4; i += stride) {
    float4 v = ((const float4*)in)[i];
    ushort4 h, l;
    h.x = rnbf(v.x); l.x = rnbf(v.x - bf2f(h.x));
    h.y = rnbf(v.y); l.y = rnbf(v.y - bf2f(h.y));
    h.z = rnbf(v.z); l.z = rnbf(v.z - bf2f(h.z));
    h.w = rnbf(v.w); l.w = rnbf(v.w - bf2f(h.w));
    ((ushort4*)hi)[i] = h;
    ((ushort4*)lo)[i] = l;
  }
}

__global__ __launch_bounds__(256) void cvt_bf_k(const float* __restrict__ in,
                                                unsigned short* __restrict__ o,
                                                int n4) {
  int i = blockIdx.x * 256 + threadIdx.x;
  int stride = gridDim.x * 256;
  for (; i < n4; i += stride) {
    float4 v = ((const float4*)in)[i];
    ushort4 h;
    h.x = rnbf(v.x); h.y = rnbf(v.y); h.z = rnbf(v.z); h.w = rnbf(v.w);
    ((ushort4*)o)[i] = h;
  }
}

// ---------------------------------------------------------------------------
// K [b][2048][1024] f32 -> KT hi/lo [b][1024][2048] bf16 (transpose + split)
// ---------------------------------------------------------------------------
__global__ __launch_bounds__(256) void cvt_t_hilo(const float* __restrict__ in,
                                                  unsigned short* __restrict__ ohi,
                                                  unsigned short* __restrict__ olo) {
  __shared__ float tbuf[64][65];
  int s0 = blockIdx.x * 64, e0 = blockIdx.y * 64, b = blockIdx.z;
  const float* src = in + ((size_t)b * NS + s0) * ND + e0;
  int tx = threadIdx.x & 15, ty = threadIdx.x >> 4;
#pragma unroll
  for (int rr = 0; rr < 4; ++rr) {
    int row = ty + rr * 16;
    float4 v = *(const float4*)&src[(size_t)row * ND + tx * 4];
    tbuf[row][tx * 4 + 0] = v.x; tbuf[row][tx * 4 + 1] = v.y;
    tbuf[row][tx * 4 + 2] = v.z; tbuf[row][tx * 4 + 3] = v.w;
  }
  __syncthreads();
  size_t obase = ((size_t)b * ND + e0) * NS + s0;
#pragma unroll
  for (int rr = 0; rr < 4; ++rr) {
    int el = ty + rr * 16;
    ushort4 h, l;
    float f0 = tbuf[tx * 4 + 0][el];
    float f1 = tbuf[tx * 4 + 1][el];
    float f2 = tbuf[tx * 4 + 2][el];
    float f3 = tbuf[tx * 4 + 3][el];
    h.x = rnbf(f0); l.x = rnbf(f0 - bf2f(h.x));
    h.y = rnbf(f1); l.y = rnbf(f1 - bf2f(h.y));
    h.z = rnbf(f2); l.z = rnbf(f2 - bf2f(h.z));
    h.w = rnbf(f3); l.w = rnbf(f3 - bf2f(h.w));
    *(ushort4*)&ohi[obase + (size_t)el * NS + tx * 4] = h;
    *(ushort4*)&olo[obase + (size_t)el * NS + tx * 4] = l;
  }
}

// ---------------------------------------------------------------------------
// f32 [rows][cols] -> transpose [cols][rows]
// ---------------------------------------------------------------------------
__global__ __launch_bounds__(256) void transpose_k(const float* __restrict__ in,
                                                   float* __restrict__ out,
                                                   int rows, int cols) {
  __shared__ float tb[64][65];
  int r0 = blockIdx.y * 64, c0 = blockIdx.x * 64;
  int tx = threadIdx.x & 15, ty = threadIdx.x >> 4;
#pragma unroll
  for (int rr = 0; rr < 4; ++rr) {
    int row = ty + rr * 16;
    float4 v = *(const float4*)&in[(size_t)(r0 + row) * cols + c0 + tx * 4];
    tb[row][tx * 4 + 0] = v.x; tb[row][tx * 4 + 1] = v.y;
    tb[row][tx * 4 + 2] = v.z; tb[row][tx * 4 + 3] = v.w;
  }
  __syncthreads();
#pragma unroll
  for (int rr = 0; rr < 4; ++rr) {
    int orow = ty + rr * 16;
    float4 o;
    o.x = tb[tx * 4 + 0][orow];
    o.y = tb[tx * 4 + 1][orow];
    o.z = tb[tx * 4 + 2][orow];
    o.w = tb[tx * 4 + 3][orow];
    *(float4*)&out[(size_t)(c0 + orow) * rows + r0 + tx * 4] = o;
  }
}

// ---------------------------------------------------------------------------
// Wq_eff[b,h,r,e] = sum_d U[b,h,r,d] * W_Q[h*64+d, e]  -> hi/lo bf16
// ---------------------------------------------------------------------------
__global__ __launch_bounds__(256) void build_wqeff(const float* __restrict__ U,
                                                   const float* __restrict__ WQ,
                                                   unsigned short* __restrict__ wqhi,
                                                   unsigned short* __restrict__ wqlo) {
  int idx = blockIdx.x;
  int hr = idx % (NH * NR);
  int h = hr / NR;
  __shared__ float u[NDH];
  int t = threadIdx.x;
  if (t < NDH) u[t] = U[(size_t)idx * NDH + t];
  __syncthreads();
  int e0 = t * 4;
  float a0 = 0.f, a1 = 0.f, a2 = 0.f, a3 = 0.f;
  const float* wbase = WQ + (size_t)h * NDH * ND + e0;
#pragma unroll 4
  for (int d = 0; d < NDH; ++d) {
    float uv = u[d];
    const float* wr = wbase + (size_t)d * ND;
    a0 += uv * wr[0]; a1 += uv * wr[1]; a2 += uv * wr[2]; a3 += uv * wr[3];
  }
  ushort4 h4, l4;
  h4.x = rnbf(a0); l4.x = rnbf(a0 - bf2f(h4.x));
  h4.y = rnbf(a1); l4.y = rnbf(a1 - bf2f(h4.y));
  h4.z = rnbf(a2); l4.z = rnbf(a2 - bf2f(h4.z));
  h4.w = rnbf(a3); l4.w = rnbf(a3 - bf2f(h4.w));
  *(ushort4*)&wqhi[(size_t)idx * ND + e0] = h4;
  *(ushort4*)&wqlo[(size_t)idx * ND + e0] = l4;
}

// ---------------------------------------------------------------------------
// Split-K MFMA GEMM: P[z][m][n] = sum_{k in chunk z} A[m][k]*B[n][k]
// z = split*nbatch + b; SPLIT adds hi/lo cross terms (3 MFMAs / frag).
// BM=64, BN=128, BK=64; 256 threads = 4 waves (2x2); fp32 partial out.
// ---------------------------------------------------------------------------
template <bool SPLIT>
__global__ __launch_bounds__(256) void mgemm(
    const unsigned short* __restrict__ Ahi, const unsigned short* __restrict__ Alo,
    const unsigned short* __restrict__ Bhi, const unsigned short* __restrict__ Blo,
    float* __restrict__ P, int kchunk, int lda, int ldb, int ldc,
    long sAb, long sBb, long sPz, int nbatch) {
  constexpr int NBUF = SPLIT ? 2 : 1;
  __shared__ unsigned short As[NBUF][64 * 64];
  __shared__ unsigned short Bs[NBUF][128 * 64];
  const int tid = threadIdx.x;
  const int lane = tid & 63;
  const int wid = tid >> 6;
  const int wm = wid >> 1, wn = wid & 1;
  const int m0 = blockIdx.y * 64, n0 = blockIdx.x * 128;
  const int bz = blockIdx.z;
  const int b = bz % nbatch;
  const int kbeg = (bz / nbatch) * kchunk;
  const unsigned short* pAhi = Ahi + (size_t)b * sAb;
  const unsigned short* pAlo = SPLIT ? (Alo + (size_t)b * sAb) : nullptr;
  const unsigned short* pBhi = Bhi + (size_t)b * sBb;
  const unsigned short* pBlo = SPLIT ? (Blo + (size_t)b * sBb) : nullptr;

  const int rsub = lane >> 3;
  const int slot = (lane & 7) ^ rsub;

  f32x4 acc[2][4];
#pragma unroll
  for (int i = 0; i < 2; ++i)
#pragma unroll
    for (int j = 0; j < 4; ++j) acc[i][j] = (f32x4){0.f, 0.f, 0.f, 0.f};

  for (int k0 = kbeg; k0 < kbeg + kchunk; k0 += 64) {
#pragma unroll
    for (int cc = 0; cc < 2; ++cc) {
      int c = wid * 2 + cc;
      int grow = m0 + c * 8 + rsub;
      gload16(&pAhi[(size_t)grow * lda + k0 + slot * 8], &As[0][c * 512]);
      if (SPLIT)
        gload16(&pAlo[(size_t)grow * lda + k0 + slot * 8], &As[NBUF - 1][c * 512]);
    }
#pragma unroll
    for (int cc = 0; cc < 4; ++cc) {
      int c = wid * 4 + cc;
      int grow = n0 + c * 8 + rsub;
      gload16(&pBhi[(size_t)grow * ldb + k0 + slot * 8], &Bs[0][c * 512]);
      if (SPLIT)
        gload16(&pBlo[(size_t)grow * ldb + k0 + slot * 8], &Bs[NBUF - 1][c * 512]);
    }
    __syncthreads();

#pragma unroll
    for (int kk = 0; kk < 64; kk += 32) {
      int sig = (kk >> 3) + (lane >> 4);
      bf16x8 ah[2], al[2], bh[4], bl[4];
#pragma unroll
      for (int fm = 0; fm < 2; ++fm) {
        int r = wm * 32 + fm * 16 + (lane & 15);
        int off = r * 128 + ((sig ^ (r & 7)) << 4);
        ah[fm] = *(const bf16x8*)((const char*)&As[0][0] + off);
        if (SPLIT) al[fm] = *(const bf16x8*)((const char*)&As[0][0] + 8192 + off);
      }
#pragma unroll
      for (int fn = 0; fn < 4; ++fn) {
        int r = wn * 64 + fn * 16 + (lane & 15);
        int off = r * 128 + ((sig ^ (r & 7)) << 4);
        bh[fn] = *(const bf16x8*)((const char*)&Bs[0][0] + off);
        if (SPLIT) bl[fn] = *(const bf16x8*)((const char*)&Bs[0][0] + 16384 + off);
      }
#pragma unroll
      for (int fm = 0; fm < 2; ++fm)
#pragma unroll
        for (int fn = 0; fn < 4; ++fn) {
          acc[fm][fn] = MFMA(ah[fm], bh[fn], acc[fm][fn]);
          if (SPLIT) {
            acc[fm][fn] = MFMA(ah[fm], bl[fn], acc[fm][fn]);
            acc[fm][fn] = MFMA(al[fm], bh[fn], acc[fm][fn]);
          }
        }
    }
    __syncthreads();
  }

  const int jr = lane >> 4, cl = lane & 15;
  float* pc = P + (size_t)bz * sPz;
#pragma unroll
  for (int fm = 0; fm < 2; ++fm)
#pragma unroll
    for (int fn = 0; fn < 4; ++fn) {
      f32x4 v = acc[fm][fn];
      int gcol = n0 + wn * 64 + fn * 16 + cl;
#pragma unroll
      for (int j = 0; j < 4; ++j) {
        int m = m0 + wm * 32 + fm * 16 + jr * 4 + j;
        pc[(size_t)m * ldc + gcol] = v[j];
      }
    }
}

// ---------------------------------------------------------------------------
// Reduce kernels over split partials P[(s*NB + b)][elems]
// ---------------------------------------------------------------------------
__global__ __launch_bounds__(256) void red_hilo(const float* __restrict__ P,
                                                unsigned short* __restrict__ hi,
                                                unsigned short* __restrict__ lo,
                                                int nsplit, int f4pb) {
  int j = blockIdx.x * 256 + threadIdx.x;  // float4 index within batch slice
  int b = blockIdx.y;
  const float4* p4 = (const float4*)P;
  float4 a = p4[(size_t)b * f4pb + j];
  for (int s = 1; s < nsplit; ++s) {
    float4 v = p4[((size_t)s * NB + b) * f4pb + j];
    a.x += v.x; a.y += v.y; a.z += v.z; a.w += v.w;
  }
  ushort4 h, l;
  h.x = rnbf(a.x); l.x = rnbf(a.x - bf2f(h.x));
  h.y = rnbf(a.y); l.y = rnbf(a.y - bf2f(h.y));
  h.z = rnbf(a.z); l.z = rnbf(a.z - bf2f(h.z));
  h.w = rnbf(a.w); l.w = rnbf(a.w - bf2f(h.w));
  ((ushort4*)hi)[(size_t)b * f4pb + j] = h;
  ((ushort4*)lo)[(size_t)b * f4pb + j] = l;
}

__global__ __launch_bounds__(256) void red_f32(const float* __restrict__ P,
                                               float* __restrict__ out,
                                               int nsplit, int f4pb) {
  int j = blockIdx.x * 256 + threadIdx.x;
  int b = blockIdx.y;
  const float4* p4 = (const float4*)P;
  float4 a = p4[(size_t)b * f4pb + j];
  for (int s = 1; s < nsplit; ++s) {
    float4 v = p4[((size_t)s * NB + b) * f4pb + j];
    a.x += v.x; a.y += v.y; a.z += v.z; a.w += v.w;
  }
  ((float4*)out)[(size_t)b * f4pb + j] = a;
}

// G3 reduce: sum + bf16 + row remap m=(h*12+r) -> r*16+h
__global__ __launch_bounds__(256) void red_remap(const float* __restrict__ P,
                                                 unsigned short* __restrict__ ctx,
                                                 int nsplit) {
  int m = blockIdx.x;  // 0..191
  int b = blockIdx.y;
  int t = threadIdx.x;
  const size_t slice = (size_t)NRH * NS;  // per (s,b)
  int orow = (m % NR) * NH + m / NR;
  unsigned short* dst = ctx + ((size_t)b * NRH + orow) * NS;
#pragma unroll
  for (int it = 0; it < 2; ++it) {
    int c4 = t + it * 256;  // float4 col index, 512 total
    float4 a = ((const float4*)(P + ((size_t)b) * slice + (size_t)m * NS))[c4];
    for (int s = 1; s < nsplit; ++s) {
      float4 v =
          ((const float4*)(P + ((size_t)s * NB + b) * slice + (size_t)m * NS))[c4];
      a.x += v.x; a.y += v.y; a.z += v.z; a.w += v.w;
    }
    ushort4 h;
    h.x = rnbf(a.x); h.y = rnbf(a.y); h.z = rnbf(a.z); h.w = rnbf(a.w);
    ((ushort4*)dst)[c4] = h;
  }
}

// G4 reduce: sum + bias + LayerNorm -> out
__global__ __launch_bounds__(256) void red_bias_ln(const float* __restrict__ P,
                                                   const float* __restrict__ bias,
                                                   const float* __restrict__ gamma,
                                                   const float* __restrict__ beta,
                                                   float* __restrict__ out,
                                                   int nsplit) {
  int row = blockIdx.x;  // 0..1535
  int t = threadIdx.x;
  const size_t slice = 1536 * (size_t)ND;
  float4 a = ((const float4*)(P + (size_t)row * ND))[t];
  for (int s = 1; s < nsplit; ++s) {
    float4 v = ((const float4*)(P + (size_t)s * slice + (size_t)row * ND))[t];
    a.x += v.x; a.y += v.y; a.z += v.z; a.w += v.w;
  }
  float4 bv = ((const float4*)bias)[t];
  a.x += bv.x; a.y += bv.y; a.z += bv.z; a.w += bv.w;

  float s = a.x + a.y + a.z + a.w;
  float ss = a.x * a.x + a.y * a.y + a.z * a.z + a.w * a.w;
#pragma unroll
  for (int off = 32; off > 0; off >>= 1) {
    s += __shfl_xor(s, off);
    ss += __shfl_xor(ss, off);
  }
  __shared__ float red[8];
  int wave = t >> 6, lane = t & 63;
  if (lane == 0) { red[wave] = s; red[4 + wave] = ss; }
  __syncthreads();
  s = red[0] + red[1] + red[2] + red[3];
  ss = red[4] + red[5] + red[6] + red[7];
  float mu = s * (1.0f / ND);
  float var = ss * (1.0f / ND) - mu * mu;
  float inv = rsqrtf(var + 1e-6f);
  float4 g = ((const float4*)gamma)[t];
  float4 be = ((const float4*)beta)[t];
  float4 o;
  o.x = (a.x - mu) * inv * g.x + be.x;
  o.y = (a.y - mu) * inv * g.y + be.y;
  o.z = (a.z - mu) * inv * g.z + be.z;
  o.w = (a.w - mu) * inv * g.w + be.w;
  ((float4*)(out + (size_t)row * ND))[t] = o;
}

// ---------------------------------------------------------------------------
// sm_k: one block per (b,h,r) — unchanged from round 3
// ---------------------------------------------------------------------------
__global__ __launch_bounds__(256) void sm_k(const float* __restrict__ T1,
                                            const float* __restrict__ WKT,
                                            const float* __restrict__ WV,
                                            unsigned short* __restrict__ A2) {
  int x = blockIdx.x;
  int xcd = x & 7, within = x >> 3;
  int h = xcd + 8 * (within & 1);
  int rb = within >> 1;
  int r = rb >> 2, b = rb & 3;
  int idx = (b * NH + h) * NR + r;

  const int t = threadIdx.x;
  __shared__ float t1s[ND];
  __shared__ float part[4][NDH];
  __shared__ float attns[NDH];

  ((float4*)t1s)[t] = ((const float4*)(T1 + (size_t)idx * ND))[t];
  __syncthreads();

  {
    int d = t & 63, q = t >> 6;
    const float* wcol = WKT + (size_t)(h * NDH + d);
    float acc = 0.f;
    int e0 = q * 256;
#pragma unroll 8
    for (int e = 0; e < 256; ++e)
      acc += t1s[e0 + e] * wcol[(size_t)(e0 + e) * ND];
    part[q][d] = acc;
  }
  __syncthreads();

  if (t < NDH) {
    float s2 = part[0][t] + part[1][t] + part[2][t] + part[3][t];
    float m = s2;
#pragma unroll
    for (int off = 32; off > 0; off >>= 1) m = fmaxf(m, __shfl_xor(m, off));
    float e = __expf(s2 - m);
    float sum = e;
#pragma unroll
    for (int off = 32; off > 0; off >>= 1) sum += __shfl_xor(sum, off);
    attns[t] = e / sum;
  }
  __syncthreads();

  {
    int e0 = t * 4;
    const float* wv = WV + (size_t)h * NDH * ND + e0;
    float a0 = 0.f, a1 = 0.f, a2 = 0.f, a3 = 0.f;
#pragma unroll 4
    for (int dd = 0; dd < NDH; ++dd) {
      float4 wvv = *(const float4*)&wv[(size_t)dd * ND];
      float a = attns[dd];
      a0 += a * wvv.x; a1 += a * wvv.y; a2 += a * wvv.z; a3 += a * wvv.w;
    }
    ushort4 o;
    o.x = rnbf(a0); o.y = rnbf(a1); o.z = rnbf(a2); o.w = rnbf(a3);
    *(ushort4*)&A2[(size_t)idx * ND + e0] = o;
  }
}

// ---------------------------------------------------------------------------
extern "C" void kernel_launch(void* const* d_in, const int* in_sizes, int n_in,
                              void* d_out, int out_size, void* d_ws, size_t ws_size,
                              hipStream_t stream) {
  const float* Q = (const float*)d_in[0];
  const float* K = (const float*)d_in[1];
  const float* V = (const float*)d_in[2];
  const float* U = (const float*)d_in[3];
  const float* WQ = (const float*)d_in[4];
  const float* WK = (const float*)d_in[5];
  const float* WV = (const float*)d_in[6];
  const float* WL = (const float*)d_in[7];
  const float* bl = (const float*)d_in[8];
  const float* ga = (const float*)d_in[9];
  const float* be = (const float*)d_in[10];
  float* out = (float*)d_out;
  char* w = (char*)d_ws;

  // layout (bytes):
  //  [0, 32M)        region A: Qhi/Qlo -> KThi/KTlo -> Vb
  //  [32M, +2M)      WLb
  //  [+3M)           wq hi/lo    -> A2b (after G1)
  //  [+6M)           s1 hi/lo    -> WKT (after G2)
  //  [+3M)           T1          -> ctxb (after sm_k)
  //  [48,234,496...] P (split partials, reused by all 4 GEMMs)
  unsigned short* Qhi = (unsigned short*)w;
  unsigned short* Qlo = (unsigned short*)(w + 16777216);
  unsigned short* KThi = Qhi;
  unsigned short* KTlo = Qlo;
  unsigned short* Vb = Qhi;
  unsigned short* WLb = (unsigned short*)(w + 33554432);
  unsigned short* wqhi = (unsigned short*)(w + 35651584);
  unsigned short* wqlo = (unsigned short*)(w + 35651584 + 1572864);
  unsigned short* A2b = wqhi;  // reuse after G1
  unsigned short* s1hi = (unsigned short*)(w + 38797312);
  unsigned short* s1lo = (unsigned short*)(w + 38797312 + 3145728);
  float* WKT = (float*)s1hi;   // reuse after G2 (4MB <= 6MB)
  float* T1 = (float*)(w + 45088768);
  unsigned short* ctxb = (unsigned short*)T1;  // reuse after sm_k
  float* P = (float*)(w + 48234496);

  size_t avail = ws_size > 48234496 ? ws_size - 48234496 : 0;
  auto pick = [&](size_t bytesPerSplit, int maxs) {
    int s = 1;
    while (s * 2 <= maxs && bytesPerSplit * (size_t)(s * 2) <= avail) s *= 2;
    return s;
  };
  int sG1 = pick(6291456, 4);   // P: [sG1*4][192][2048] f32
  int sG2 = pick(3145728, 8);   // P: [sG2*4][192][1024] f32
  int sG3 = pick(6291456, 4);
  int sG4 = pick(6291456, 4);   // P: [sG4][1536][1024] f32

  cvt_bf_k<<<1024, 256, 0, stream>>>(WL, WLb, ND * ND / 4);
  cvt_hilo_k<<<2048, 256, 0, stream>>>(Q, Qhi, Qlo, NB * NS * ND / 4);
  build_wqeff<<<NB * NH * NR, 256, 0, stream>>>(U, WQ, wqhi, wqlo);

  // G1: s1[rh][s] = wq_eff[rh] . Q[s]  M=192 N=2048 K=1024 (SPLIT)
  mgemm<true><<<dim3(16, 3, NB * sG1), 256, 0, stream>>>(
      wqhi, wqlo, Qhi, Qlo, P, 1024 / sG1,
      1024, 1024, 2048, 192L * 1024, 2048L * 1024, 192L * 2048, NB);
  red_hilo<<<dim3(384, NB), 256, 0, stream>>>(P, s1hi, s1lo, sG1, 98304);

  cvt_t_hilo<<<dim3(32, 16, NB), 256, 0, stream>>>(K, KThi, KTlo);

  // G2: T1[rh][e] = s1[rh] . KT[e]  M=192 N=1024 K=2048 (SPLIT)
  mgemm<true><<<dim3(8, 3, NB * sG2), 256, 0, stream>>>(
      s1hi, s1lo, KThi, KTlo, P, 2048 / sG2,
      2048, 2048, 1024, 192L * 2048, 1024L * 2048, 192L * 1024, NB);
  red_f32<<<dim3(192, NB), 256, 0, stream>>>(P, T1, sG2, 49152);

  transpose_k<<<dim3(16, 16), 256, 0, stream>>>(WK, WKT, ND, ND);
  sm_k<<<NB * NH * NR, 256, 0, stream>>>(T1, WKT, WV, A2b);

  cvt_bf_k<<<2048, 256, 0, stream>>>(V, Vb, NB * NS * ND / 4);

  // G3: ctx[rh][s] = A2[rh] . V[s]  M=192 N=2048 K=1024
  mgemm<false><<<dim3(16, 3, NB * sG3), 256, 0, stream>>>(
      A2b, nullptr, Vb, nullptr, P, 1024 / sG3,
      1024, 1024, 2048, 192L * 1024, 2048L * 1024, 192L * 2048, NB);
  red_remap<<<dim3(192, NB), 256, 0, stream>>>(P, ctxb, sG3);

  // G4: lin = ctx_flat @ WL^T  M=1536 N=1024 K=1024
  mgemm<false><<<dim3(8, 24, sG4), 256, 0, stream>>>(
      ctxb, nullptr, WLb, nullptr, P, 1024 / sG4,
      1024, 1024, 1024, 0, 0, 1536L * 1024, 1);
  red_bias_ln<<<1536, 256, 0, stream>>>(P, bl, ga, be, out, sG4);
}

// Round 5
// 149.508 us; speedup vs baseline: 2.3592x; 1.1172x over previous
//
#include <hip/hip_runtime.h>

#define NB 4
#define NS 2048
#define ND 1024
#define NH 16
#define NDH 64
#define NR 12
#define NRH 192

typedef __attribute__((ext_vector_type(8))) short bf16x8;
typedef __attribute__((ext_vector_type(4))) float f32x4;

__device__ __forceinline__ unsigned short rnbf(float f) {
  unsigned u = __float_as_uint(f);
  u += 0x7fffu + ((u >> 16) & 1u);
  return (unsigned short)(u >> 16);
}
__device__ __forceinline__ float bf2f(unsigned short h) {
  return __uint_as_float(((unsigned)h) << 16);
}

// v_cvt_pk_bf16_f32: dst[15:0]=bf16(a) RNE, dst[31:16]=bf16(b)
__device__ __forceinline__ unsigned cvtpk(float a, float b) {
  unsigned r;
  asm("v_cvt_pk_bf16_f32 %0, %1, %2" : "=v"(r) : "v"(a), "v"(b));
  return r;
}
__device__ __forceinline__ uint4 pk_hi(float4 u, float4 w) {
  uint4 h;
  h.x = cvtpk(u.x, u.y); h.y = cvtpk(u.z, u.w);
  h.z = cvtpk(w.x, w.y); h.w = cvtpk(w.z, w.w);
  return h;
}
__device__ __forceinline__ unsigned lo2(float a, float b, unsigned hh) {
  float ah = __uint_as_float(hh << 16);
  float bh = __uint_as_float(hh & 0xffff0000u);
  return cvtpk(a - ah, b - bh);
}
__device__ __forceinline__ uint4 pk_lo(float4 u, float4 w, uint4 h) {
  uint4 l;
  l.x = lo2(u.x, u.y, h.x); l.y = lo2(u.z, u.w, h.y);
  l.z = lo2(w.x, w.y, h.z); l.w = lo2(w.z, w.w, h.w);
  return l;
}

__device__ __forceinline__ void gload16(const void* g, void* l) {
  __builtin_amdgcn_global_load_lds(
      (const __attribute__((address_space(1))) unsigned int*)g,
      (__attribute__((address_space(3))) unsigned int*)l, 16, 0, 0);
}

#define MFMA(a, b, c) __builtin_amdgcn_mfma_f32_16x16x32_bf16(a, b, c, 0, 0, 0)

// ---------------------------------------------------------------------------
// K [b][2048][1024] f32 -> KT hi/lo [b][1024][2048] bf16 (transpose + split)
// ---------------------------------------------------------------------------
__global__ __launch_bounds__(256) void cvt_t_hilo(const float* __restrict__ in,
                                                  unsigned short* __restrict__ ohi,
                                                  unsigned short* __restrict__ olo) {
  __shared__ float tbuf[64][65];
  int s0 = blockIdx.x * 64, e0 = blockIdx.y * 64, b = blockIdx.z;
  const float* src = in + ((size_t)b * NS + s0) * ND + e0;
  int tx = threadIdx.x & 15, ty = threadIdx.x >> 4;
#pragma unroll
  for (int rr = 0; rr < 4; ++rr) {
    int row = ty + rr * 16;
    float4 v = *(const float4*)&src[(size_t)row * ND + tx * 4];
    tbuf[row][tx * 4 + 0] = v.x; tbuf[row][tx * 4 + 1] = v.y;
    tbuf[row][tx * 4 + 2] = v.z; tbuf[row][tx * 4 + 3] = v.w;
  }
  __syncthreads();
  size_t obase = ((size_t)b * ND + e0) * NS + s0;
#pragma unroll
  for (int rr = 0; rr < 4; ++rr) {
    int el = ty + rr * 16;
    ushort4 h, l;
    float f0 = tbuf[tx * 4 + 0][el];
    float f1 = tbuf[tx * 4 + 1][el];
    float f2 = tbuf[tx * 4 + 2][el];
    float f3 = tbuf[tx * 4 + 3][el];
    h.x = rnbf(f0); l.x = rnbf(f0 - bf2f(h.x));
    h.y = rnbf(f1); l.y = rnbf(f1 - bf2f(h.y));
    h.z = rnbf(f2); l.z = rnbf(f2 - bf2f(h.z));
    h.w = rnbf(f3); l.w = rnbf(f3 - bf2f(h.w));
    *(ushort4*)&ohi[obase + (size_t)el * NS + tx * 4] = h;
    *(ushort4*)&olo[obase + (size_t)el * NS + tx * 4] = l;
  }
}

// ---------------------------------------------------------------------------
// f32 [rows][cols] -> transpose [cols][rows]
// ---------------------------------------------------------------------------
__global__ __launch_bounds__(256) void transpose_k(const float* __restrict__ in,
                                                   float* __restrict__ out,
                                                   int rows, int cols) {
  __shared__ float tb[64][65];
  int r0 = blockIdx.y * 64, c0 = blockIdx.x * 64;
  int tx = threadIdx.x & 15, ty = threadIdx.x >> 4;
#pragma unroll
  for (int rr = 0; rr < 4; ++rr) {
    int row = ty + rr * 16;
    float4 v = *(const float4*)&in[(size_t)(r0 + row) * cols + c0 + tx * 4];
    tb[row][tx * 4 + 0] = v.x; tb[row][tx * 4 + 1] = v.y;
    tb[row][tx * 4 + 2] = v.z; tb[row][tx * 4 + 3] = v.w;
  }
  __syncthreads();
#pragma unroll
  for (int rr = 0; rr < 4; ++rr) {
    int orow = ty + rr * 16;
    float4 o;
    o.x = tb[tx * 4 + 0][orow];
    o.y = tb[tx * 4 + 1][orow];
    o.z = tb[tx * 4 + 2][orow];
    o.w = tb[tx * 4 + 3][orow];
    *(float4*)&out[(size_t)(c0 + orow) * rows + r0 + tx * 4] = o;
  }
}

// ---------------------------------------------------------------------------
// Wq_eff[b,h,r,e] = sum_d U[b,h,r,d] * W_Q[h*64+d, e]  -> hi/lo bf16
// ---------------------------------------------------------------------------
__global__ __launch_bounds__(256) void build_wqeff(const float* __restrict__ U,
                                                   const float* __restrict__ WQ,
                                                   unsigned short* __restrict__ wqhi,
                                                   unsigned short* __restrict__ wqlo) {
  int idx = blockIdx.x;
  int hr = idx % (NH * NR);
  int h = hr / NR;
  __shared__ float u[NDH];
  int t = threadIdx.x;
  if (t < NDH) u[t] = U[(size_t)idx * NDH + t];
  __syncthreads();
  int e0 = t * 4;
  float a0 = 0.f, a1 = 0.f, a2 = 0.f, a3 = 0.f;
  const float* wbase = WQ + (size_t)h * NDH * ND + e0;
#pragma unroll 4
  for (int d = 0; d < NDH; ++d) {
    float uv = u[d];
    const float* wr = wbase + (size_t)d * ND;
    a0 += uv * wr[0]; a1 += uv * wr[1]; a2 += uv * wr[2]; a3 += uv * wr[3];
  }
  ushort4 h4, l4;
  h4.x = rnbf(a0); l4.x = rnbf(a0 - bf2f(h4.x));
  h4.y = rnbf(a1); l4.y = rnbf(a1 - bf2f(h4.y));
  h4.z = rnbf(a2); l4.z = rnbf(a2 - bf2f(h4.z));
  h4.w = rnbf(a3); l4.w = rnbf(a3 - bf2f(h4.w));
  *(ushort4*)&wqhi[(size_t)idx * ND + e0] = h4;
  *(ushort4*)&wqlo[(size_t)idx * ND + e0] = l4;
}

// ---------------------------------------------------------------------------
// Split-K MFMA GEMM: P[z][m][n] = sum_{k in chunk z} A[m][k]*B[n][k]
// z = split*nbatch + b; SPLIT: hi/lo pair, 3 MFMAs/frag.
// BSRC=0: B from bf16 (pair iff SPLIT) via global_load_lds (pre-swz source)
// BSRC=1: B from fp32 via reg-stage (cvt_pk hi/lo in-reg, swizzled ds_write)
// BM=64, BN=128, BK=64; 256 threads = 4 waves (2x2); fp32 partial out.
// ---------------------------------------------------------------------------
template <bool SPLIT, int BSRC>
__global__ __launch_bounds__(256) void mgemm(
    const unsigned short* __restrict__ Ahi, const unsigned short* __restrict__ Alo,
    const unsigned short* __restrict__ Bhi, const unsigned short* __restrict__ Blo,
    const float* __restrict__ Bf,
    float* __restrict__ P, int kchunk, int lda, int ldb, int ldc,
    long sAb, long sBb, long sPz, int nbatch) {
  constexpr int NBUF = SPLIT ? 2 : 1;
  __shared__ unsigned short As[NBUF][64 * 64];
  __shared__ unsigned short Bs[NBUF][128 * 64];
  const int tid = threadIdx.x;
  const int lane = tid & 63;
  const int wid = tid >> 6;
  const int wm = wid >> 1, wn = wid & 1;
  const int m0 = blockIdx.y * 64, n0 = blockIdx.x * 128;
  const int bz = blockIdx.z;
  const int b = bz % nbatch;
  const int kbeg = (bz / nbatch) * kchunk;
  const unsigned short* pAhi = Ahi + (size_t)b * sAb;
  const unsigned short* pAlo = SPLIT ? (Alo + (size_t)b * sAb) : nullptr;
  const unsigned short* pBhi = (BSRC == 0) ? (Bhi + (size_t)b * sBb) : nullptr;
  const unsigned short* pBlo =
      (BSRC == 0 && SPLIT) ? (Blo + (size_t)b * sBb) : nullptr;
  const float* pBf = (BSRC == 1) ? (Bf + (size_t)b * sBb) : nullptr;

  const int rsub = lane >> 3;
  const int slot = (lane & 7) ^ rsub;

  f32x4 acc[2][4];
#pragma unroll
  for (int i = 0; i < 2; ++i)
#pragma unroll
    for (int j = 0; j < 4; ++j) acc[i][j] = (f32x4){0.f, 0.f, 0.f, 0.f};

  for (int k0 = kbeg; k0 < kbeg + kchunk; k0 += 64) {
    // ---- A: bf16 (pair) via global_load_lds, pre-swizzled source
#pragma unroll
    for (int cc = 0; cc < 2; ++cc) {
      int c = wid * 2 + cc;
      int grow = m0 + c * 8 + rsub;
      gload16(&pAhi[(size_t)grow * lda + k0 + slot * 8], &As[0][c * 512]);
      if (SPLIT)
        gload16(&pAlo[(size_t)grow * lda + k0 + slot * 8], &As[NBUF - 1][c * 512]);
    }
    // ---- B
    if (BSRC == 0) {
#pragma unroll
      for (int cc = 0; cc < 4; ++cc) {
        int c = wid * 4 + cc;
        int grow = n0 + c * 8 + rsub;
        gload16(&pBhi[(size_t)grow * ldb + k0 + slot * 8], &Bs[0][c * 512]);
        if (SPLIT)
          gload16(&pBlo[(size_t)grow * ldb + k0 + slot * 8], &Bs[NBUF - 1][c * 512]);
      }
    } else {
      // reg-stage fp32 -> bf16 (hi[/lo]) with swizzled ds_write
      const int brow = tid >> 1;          // 0..127
      const int jbase = (tid & 1) * 4;    // slot group
      const float* bsrc = pBf + (size_t)(n0 + brow) * ldb + k0 + jbase * 8;
      char* dbase = (char*)&Bs[0][0] + brow * 128;
#pragma unroll
      for (int jj = 0; jj < 4; ++jj) {
        float4 u = *(const float4*)(bsrc + jj * 8);
        float4 w = *(const float4*)(bsrc + jj * 8 + 4);
        uint4 h = pk_hi(u, w);
        char* dst = dbase + (((jbase + jj) ^ (brow & 7)) << 4);
        *(uint4*)dst = h;
        if (SPLIT) *(uint4*)(dst + 16384) = pk_lo(u, w, h);
      }
    }
    __syncthreads();

#pragma unroll
    for (int kk = 0; kk < 64; kk += 32) {
      int sig = (kk >> 3) + (lane >> 4);
      bf16x8 ah[2], al[2], bh[4], bl[4];
#pragma unroll
      for (int fm = 0; fm < 2; ++fm) {
        int r = wm * 32 + fm * 16 + (lane & 15);
        int off = r * 128 + ((sig ^ (r & 7)) << 4);
        ah[fm] = *(const bf16x8*)((const char*)&As[0][0] + off);
        if (SPLIT) al[fm] = *(const bf16x8*)((const char*)&As[0][0] + 8192 + off);
      }
#pragma unroll
      for (int fn = 0; fn < 4; ++fn) {
        int r = wn * 64 + fn * 16 + (lane & 15);
        int off = r * 128 + ((sig ^ (r & 7)) << 4);
        bh[fn] = *(const bf16x8*)((const char*)&Bs[0][0] + off);
        if (SPLIT) bl[fn] = *(const bf16x8*)((const char*)&Bs[0][0] + 16384 + off);
      }
#pragma unroll
      for (int fm = 0; fm < 2; ++fm)
#pragma unroll
        for (int fn = 0; fn < 4; ++fn) {
          acc[fm][fn] = MFMA(ah[fm], bh[fn], acc[fm][fn]);
          if (SPLIT) {
            acc[fm][fn] = MFMA(ah[fm], bl[fn], acc[fm][fn]);
            acc[fm][fn] = MFMA(al[fm], bh[fn], acc[fm][fn]);
          }
        }
    }
    __syncthreads();
  }

  const int jr = lane >> 4, cl = lane & 15;
  float* pc = P + (size_t)bz * sPz;
#pragma unroll
  for (int fm = 0; fm < 2; ++fm)
#pragma unroll
    for (int fn = 0; fn < 4; ++fn) {
      f32x4 v = acc[fm][fn];
      int gcol = n0 + wn * 64 + fn * 16 + cl;
#pragma unroll
      for (int j = 0; j < 4; ++j) {
        int m = m0 + wm * 32 + fm * 16 + jr * 4 + j;
        pc[(size_t)m * ldc + gcol] = v[j];
      }
    }
}

// ---------------------------------------------------------------------------
// Reduce kernels over split partials P[(s*NB + b)][elems]
// ---------------------------------------------------------------------------
__global__ __launch_bounds__(256) void red_hilo(const float* __restrict__ P,
                                                unsigned short* __restrict__ hi,
                                                unsigned short* __restrict__ lo,
                                                int nsplit, int f4pb) {
  int j = blockIdx.x * 256 + threadIdx.x;
  int b = blockIdx.y;
  const float4* p4 = (const float4*)P;
  float4 a = p4[(size_t)b * f4pb + j];
  for (int s = 1; s < nsplit; ++s) {
    float4 v = p4[((size_t)s * NB + b) * f4pb + j];
    a.x += v.x; a.y += v.y; a.z += v.z; a.w += v.w;
  }
  ushort4 h, l;
  h.x = rnbf(a.x); l.x = rnbf(a.x - bf2f(h.x));
  h.y = rnbf(a.y); l.y = rnbf(a.y - bf2f(h.y));
  h.z = rnbf(a.z); l.z = rnbf(a.z - bf2f(h.z));
  h.w = rnbf(a.w); l.w = rnbf(a.w - bf2f(h.w));
  ((ushort4*)hi)[(size_t)b * f4pb + j] = h;
  ((ushort4*)lo)[(size_t)b * f4pb + j] = l;
}

// G3 reduce: sum + bf16 + row remap m=(h*12+r) -> r*16+h
__global__ __launch_bounds__(256) void red_remap(const float* __restrict__ P,
                                                 unsigned short* __restrict__ ctx,
                                                 int nsplit) {
  int m = blockIdx.x;
  int b = blockIdx.y;
  int t = threadIdx.x;
  const size_t slice = (size_t)NRH * NS;
  int orow = (m % NR) * NH + m / NR;
  unsigned short* dst = ctx + ((size_t)b * NRH + orow) * NS;
#pragma unroll
  for (int it = 0; it < 2; ++it) {
    int c4 = t + it * 256;
    float4 a = ((const float4*)(P + ((size_t)b) * slice + (size_t)m * NS))[c4];
    for (int s = 1; s < nsplit; ++s) {
      float4 v =
          ((const float4*)(P + ((size_t)s * NB + b) * slice + (size_t)m * NS))[c4];
      a.x += v.x; a.y += v.y; a.z += v.z; a.w += v.w;
    }
    ushort4 h;
    h.x = rnbf(a.x); h.y = rnbf(a.y); h.z = rnbf(a.z); h.w = rnbf(a.w);
    ((ushort4*)dst)[c4] = h;
  }
}

// G4 reduce: sum + bias + LayerNorm -> out
__global__ __launch_bounds__(256) void red_bias_ln(const float* __restrict__ P,
                                                   const float* __restrict__ bias,
                                                   const float* __restrict__ gamma,
                                                   const float* __restrict__ beta,
                                                   float* __restrict__ out,
                                                   int nsplit) {
  int row = blockIdx.x;
  int t = threadIdx.x;
  const size_t slice = 1536 * (size_t)ND;
  float4 a = ((const float4*)(P + (size_t)row * ND))[t];
  for (int s = 1; s < nsplit; ++s) {
    float4 v = ((const float4*)(P + (size_t)s * slice + (size_t)row * ND))[t];
    a.x += v.x; a.y += v.y; a.z += v.z; a.w += v.w;
  }
  float4 bv = ((const float4*)bias)[t];
  a.x += bv.x; a.y += bv.y; a.z += bv.z; a.w += bv.w;

  float s = a.x + a.y + a.z + a.w;
  float ss = a.x * a.x + a.y * a.y + a.z * a.z + a.w * a.w;
#pragma unroll
  for (int off = 32; off > 0; off >>= 1) {
    s += __shfl_xor(s, off);
    ss += __shfl_xor(ss, off);
  }
  __shared__ float red[8];
  int wave = t >> 6, lane = t & 63;
  if (lane == 0) { red[wave] = s; red[4 + wave] = ss; }
  __syncthreads();
  s = red[0] + red[1] + red[2] + red[3];
  ss = red[4] + red[5] + red[6] + red[7];
  float mu = s * (1.0f / ND);
  float var = ss * (1.0f / ND) - mu * mu;
  float inv = rsqrtf(var + 1e-6f);
  float4 g = ((const float4*)gamma)[t];
  float4 be = ((const float4*)beta)[t];
  float4 o;
  o.x = (a.x - mu) * inv * g.x + be.x;
  o.y = (a.y - mu) * inv * g.y + be.y;
  o.z = (a.z - mu) * inv * g.z + be.z;
  o.w = (a.w - mu) * inv * g.w + be.w;
  ((float4*)(out + (size_t)row * ND))[t] = o;
}

// ---------------------------------------------------------------------------
// sm_k: one block per (b,h,r). Sums G2's split partials inline (drops red_f32):
// T1[e] = sum_s P[(s*NB+b)][rh][e]; s2[d] = sum_e T1[e]*WKT[e][h64+d] (f32);
// softmax over d=64; A2[bhr][e] = sum_d attn[d]*WV[h64+d][e] -> bf16.
// ---------------------------------------------------------------------------
__global__ __launch_bounds__(256) void sm_k(const float* __restrict__ P,
                                            int nsplit,
                                            const float* __restrict__ WKT,
                                            const float* __restrict__ WV,
                                            unsigned short* __restrict__ A2) {
  int x = blockIdx.x;
  int xcd = x & 7, within = x >> 3;
  int h = xcd + 8 * (within & 1);
  int rb = within >> 1;
  int r = rb >> 2, b = rb & 3;
  int idx = (b * NH + h) * NR + r;
  int rh = h * NR + r;

  const int t = threadIdx.x;
  __shared__ float t1s[ND];
  __shared__ float part[4][NDH];
  __shared__ float attns[NDH];

  {
    const size_t sstride = (size_t)NB * NRH * ND;
    const float* base = P + ((size_t)b * NRH + rh) * ND;
    float4 a = ((const float4*)base)[t];
    for (int s = 1; s < nsplit; ++s) {
      float4 v = ((const float4*)(base + (size_t)s * sstride))[t];
      a.x += v.x; a.y += v.y; a.z += v.z; a.w += v.w;
    }
    ((float4*)t1s)[t] = a;
  }
  __syncthreads();

  {
    int d = t & 63, q = t >> 6;
    const float* wcol = WKT + (size_t)(h * NDH + d);
    float acc = 0.f;
    int e0 = q * 256;
#pragma unroll 8
    for (int e = 0; e < 256; ++e)
      acc += t1s[e0 + e] * wcol[(size_t)(e0 + e) * ND];
    part[q][d] = acc;
  }
  __syncthreads();

  if (t < NDH) {
    float s2 = part[0][t] + part[1][t] + part[2][t] + part[3][t];
    float m = s2;
#pragma unroll
    for (int off = 32; off > 0; off >>= 1) m = fmaxf(m, __shfl_xor(m, off));
    float e = __expf(s2 - m);
    float sum = e;
#pragma unroll
    for (int off = 32; off > 0; off >>= 1) sum += __shfl_xor(sum, off);
    attns[t] = e / sum;
  }
  __syncthreads();

  {
    int e0 = t * 4;
    const float* wv = WV + (size_t)h * NDH * ND + e0;
    float a0 = 0.f, a1 = 0.f, a2 = 0.f, a3 = 0.f;
#pragma unroll 4
    for (int dd = 0; dd < NDH; ++dd) {
      float4 wvv = *(const float4*)&wv[(size_t)dd * ND];
      float a = attns[dd];
      a0 += a * wvv.x; a1 += a * wvv.y; a2 += a * wvv.z; a3 += a * wvv.w;
    }
    ushort4 o;
    o.x = rnbf(a0); o.y = rnbf(a1); o.z = rnbf(a2); o.w = rnbf(a3);
    *(ushort4*)&A2[(size_t)idx * ND + e0] = o;
  }
}

// ---------------------------------------------------------------------------
extern "C" void kernel_launch(void* const* d_in, const int* in_sizes, int n_in,
                              void* d_out, int out_size, void* d_ws, size_t ws_size,
                              hipStream_t stream) {
  const float* Q = (const float*)d_in[0];
  const float* K = (const float*)d_in[1];
  const float* V = (const float*)d_in[2];
  const float* U = (const float*)d_in[3];
  const float* WQ = (const float*)d_in[4];
  const float* WK = (const float*)d_in[5];
  const float* WV = (const float*)d_in[6];
  const float* WL = (const float*)d_in[7];
  const float* bl = (const float*)d_in[8];
  const float* ga = (const float*)d_in[9];
  const float* be = (const float*)d_in[10];
  float* out = (float*)d_out;
  char* w = (char*)d_ws;

  // layout (bytes):
  //  [0, 33.5M)   KThi/KTlo
  //  [33.5M)      wq hi/lo (3M)   -> A2b reuse after G1
  //  [36.7M)      s1 hi/lo (6.3M) -> WKT reuse after G2
  //  [43.0M)      ctxb (3M)
  //  [46.1M...)   P split partials (shared by all GEMMs)
  unsigned short* KThi = (unsigned short*)w;
  unsigned short* KTlo = (unsigned short*)(w + 16777216);
  unsigned short* wqhi = (unsigned short*)(w + 33554432);
  unsigned short* wqlo = (unsigned short*)(w + 35127296);
  unsigned short* A2b = wqhi;
  unsigned short* s1hi = (unsigned short*)(w + 36700160);
  unsigned short* s1lo = (unsigned short*)(w + 39845888);
  float* WKT = (float*)s1hi;
  unsigned short* ctxb = (unsigned short*)(w + 42991616);
  float* P = (float*)(w + 46137344);

  size_t avail = ws_size > 46137344 ? ws_size - 46137344 : 0;
  auto pick = [&](size_t bytesPerSplit, int maxs) {
    int s = 1;
    while (s * 2 <= maxs && bytesPerSplit * (size_t)(s * 2) <= avail) s *= 2;
    return s;
  };
  int sG1 = pick(6291456, 4);   // P: [sG1*4][192][2048] f32
  int sG2 = pick(3145728, 8);   // P: [sG2*4][192][1024] f32
  int sG3 = pick(6291456, 4);
  int sG4 = pick(6291456, 4);   // P: [sG4][1536][1024] f32

  build_wqeff<<<NB * NH * NR, 256, 0, stream>>>(U, WQ, wqhi, wqlo);

  // G1: s1[rh][s] = wq_eff[rh] . Q[s]  M=192 N=2048 K=1024 (pair; B=Q fp32)
  mgemm<true, 1><<<dim3(16, 3, NB * sG1), 256, 0, stream>>>(
      wqhi, wqlo, nullptr, nullptr, Q, P, 1024 / sG1,
      1024, 1024, 2048, 192L * 1024, 2048L * 1024, 192L * 2048, NB);
  red_hilo<<<dim3(384, NB), 256, 0, stream>>>(P, s1hi, s1lo, sG1, 98304);

  cvt_t_hilo<<<dim3(32, 16, NB), 256, 0, stream>>>(K, KThi, KTlo);

  // G2: T1[rh][e] = s1[rh] . KT[e]  M=192 N=1024 K=2048 (pair; B bf16 pair)
  mgemm<true, 0><<<dim3(8, 3, NB * sG2), 256, 0, stream>>>(
      s1hi, s1lo, KThi, KTlo, nullptr, P, 2048 / sG2,
      2048, 2048, 1024, 192L * 2048, 1024L * 2048, 192L * 1024, NB);

  // WK -> WKT (s1 region dead after G2)
  transpose_k<<<dim3(16, 16), 256, 0, stream>>>(WK, WKT, ND, ND);

  // s2 -> softmax -> A2, summing G2 partials inline
  sm_k<<<NB * NH * NR, 256, 0, stream>>>(P, sG2, WKT, WV, A2b);

  // G3: ctx[rh][s] = A2[rh] . V[s]  M=192 N=2048 K=1024 (B=V fp32 plain)
  mgemm<false, 1><<<dim3(16, 3, NB * sG3), 256, 0, stream>>>(
      A2b, nullptr, nullptr, nullptr, V, P, 1024 / sG3,
      1024, 1024, 2048, 192L * 1024, 2048L * 1024, 192L * 2048, NB);
  red_remap<<<dim3(192, NB), 256, 0, stream>>>(P, ctxb, sG3);

  // G4: lin = ctx_flat @ WL^T  M=1536 N=1024 K=1024 (B=WL fp32 plain)
  mgemm<false, 1><<<dim3(8, 24, sG4), 256, 0, stream>>>(
      ctxb, nullptr, nullptr, nullptr, WL, P, 1024 / sG4,
      1024, 1024, 1024, 0, 0, 1536L * 1024, 1);
  red_bias_ln<<<1536, 256, 0, stream>>>(P, bl, ga, be, out, sG4);
}

// Round 6
// 139.890 us; speedup vs baseline: 2.5214x; 1.0688x over previous
//
#include <hip/hip_runtime.h>

#define NB 4
#define NS 2048
#define ND 1024
#define NH 16
#define NDH 64
#define NR 12
#define NRH 192

typedef __attribute__((ext_vector_type(8))) short bf16x8;
typedef __attribute__((ext_vector_type(4))) float f32x4;

__device__ __forceinline__ unsigned short rnbf(float f) {
  unsigned u = __float_as_uint(f);
  u += 0x7fffu + ((u >> 16) & 1u);
  return (unsigned short)(u >> 16);
}
__device__ __forceinline__ float bf2f(unsigned short h) {
  return __uint_as_float(((unsigned)h) << 16);
}

// v_cvt_pk_bf16_f32: dst[15:0]=bf16(a) RNE, dst[31:16]=bf16(b)
__device__ __forceinline__ unsigned cvtpk(float a, float b) {
  unsigned r;
  asm("v_cvt_pk_bf16_f32 %0, %1, %2" : "=v"(r) : "v"(a), "v"(b));
  return r;
}
__device__ __forceinline__ uint4 pk_hi(float4 u, float4 w) {
  uint4 h;
  h.x = cvtpk(u.x, u.y); h.y = cvtpk(u.z, u.w);
  h.z = cvtpk(w.x, w.y); h.w = cvtpk(w.z, w.w);
  return h;
}
__device__ __forceinline__ unsigned lo2(float a, float b, unsigned hh) {
  float ah = __uint_as_float(hh << 16);
  float bh = __uint_as_float(hh & 0xffff0000u);
  return cvtpk(a - ah, b - bh);
}
__device__ __forceinline__ uint4 pk_lo(float4 u, float4 w, uint4 h) {
  uint4 l;
  l.x = lo2(u.x, u.y, h.x); l.y = lo2(u.z, u.w, h.y);
  l.z = lo2(w.x, w.y, h.z); l.w = lo2(w.z, w.w, h.w);
  return l;
}

__device__ __forceinline__ void gload16(const void* g, void* l) {
  __builtin_amdgcn_global_load_lds(
      (const __attribute__((address_space(1))) unsigned int*)g,
      (__attribute__((address_space(3))) unsigned int*)l, 16, 0, 0);
}

#define MFMA(a, b, c) __builtin_amdgcn_mfma_f32_16x16x32_bf16(a, b, c, 0, 0, 0)

// ---------------------------------------------------------------------------
// K [b][2048][1024] f32 -> KT hi/lo [b][1024][2048] bf16 (transpose + split)
// ---------------------------------------------------------------------------
__global__ __launch_bounds__(256) void cvt_t_hilo(const float* __restrict__ in,
                                                  unsigned short* __restrict__ ohi,
                                                  unsigned short* __restrict__ olo) {
  __shared__ float tbuf[64][65];
  int s0 = blockIdx.x * 64, e0 = blockIdx.y * 64, b = blockIdx.z;
  const float* src = in + ((size_t)b * NS + s0) * ND + e0;
  int tx = threadIdx.x & 15, ty = threadIdx.x >> 4;
#pragma unroll
  for (int rr = 0; rr < 4; ++rr) {
    int row = ty + rr * 16;
    float4 v = *(const float4*)&src[(size_t)row * ND + tx * 4];
    tbuf[row][tx * 4 + 0] = v.x; tbuf[row][tx * 4 + 1] = v.y;
    tbuf[row][tx * 4 + 2] = v.z; tbuf[row][tx * 4 + 3] = v.w;
  }
  __syncthreads();
  size_t obase = ((size_t)b * ND + e0) * NS + s0;
#pragma unroll
  for (int rr = 0; rr < 4; ++rr) {
    int el = ty + rr * 16;
    ushort4 h, l;
    float f0 = tbuf[tx * 4 + 0][el];
    float f1 = tbuf[tx * 4 + 1][el];
    float f2 = tbuf[tx * 4 + 2][el];
    float f3 = tbuf[tx * 4 + 3][el];
    h.x = rnbf(f0); l.x = rnbf(f0 - bf2f(h.x));
    h.y = rnbf(f1); l.y = rnbf(f1 - bf2f(h.y));
    h.z = rnbf(f2); l.z = rnbf(f2 - bf2f(h.z));
    h.w = rnbf(f3); l.w = rnbf(f3 - bf2f(h.w));
    *(ushort4*)&ohi[obase + (size_t)el * NS + tx * 4] = h;
    *(ushort4*)&olo[obase + (size_t)el * NS + tx * 4] = l;
  }
}

// ---------------------------------------------------------------------------
// f32 [rows][cols] -> transpose [cols][rows]
// ---------------------------------------------------------------------------
__global__ __launch_bounds__(256) void transpose_k(const float* __restrict__ in,
                                                   float* __restrict__ out,
                                                   int rows, int cols) {
  __shared__ float tb[64][65];
  int r0 = blockIdx.y * 64, c0 = blockIdx.x * 64;
  int tx = threadIdx.x & 15, ty = threadIdx.x >> 4;
#pragma unroll
  for (int rr = 0; rr < 4; ++rr) {
    int row = ty + rr * 16;
    float4 v = *(const float4*)&in[(size_t)(r0 + row) * cols + c0 + tx * 4];
    tb[row][tx * 4 + 0] = v.x; tb[row][tx * 4 + 1] = v.y;
    tb[row][tx * 4 + 2] = v.z; tb[row][tx * 4 + 3] = v.w;
  }
  __syncthreads();
#pragma unroll
  for (int rr = 0; rr < 4; ++rr) {
    int orow = ty + rr * 16;
    float4 o;
    o.x = tb[tx * 4 + 0][orow];
    o.y = tb[tx * 4 + 1][orow];
    o.z = tb[tx * 4 + 2][orow];
    o.w = tb[tx * 4 + 3][orow];
    *(float4*)&out[(size_t)(c0 + orow) * rows + r0 + tx * 4] = o;
  }
}

// ---------------------------------------------------------------------------
// Wq_eff[b,h,r,e] = sum_d U[b,h,r,d] * W_Q[h*64+d, e]  -> hi/lo bf16
// ---------------------------------------------------------------------------
__global__ __launch_bounds__(256) void build_wqeff(const float* __restrict__ U,
                                                   const float* __restrict__ WQ,
                                                   unsigned short* __restrict__ wqhi,
                                                   unsigned short* __restrict__ wqlo) {
  int idx = blockIdx.x;
  int hr = idx % (NH * NR);
  int h = hr / NR;
  __shared__ float u[NDH];
  int t = threadIdx.x;
  if (t < NDH) u[t] = U[(size_t)idx * NDH + t];
  __syncthreads();
  int e0 = t * 4;
  float a0 = 0.f, a1 = 0.f, a2 = 0.f, a3 = 0.f;
  const float* wbase = WQ + (size_t)h * NDH * ND + e0;
#pragma unroll 4
  for (int d = 0; d < NDH; ++d) {
    float uv = u[d];
    const float* wr = wbase + (size_t)d * ND;
    a0 += uv * wr[0]; a1 += uv * wr[1]; a2 += uv * wr[2]; a3 += uv * wr[3];
  }
  ushort4 h4, l4;
  h4.x = rnbf(a0); l4.x = rnbf(a0 - bf2f(h4.x));
  h4.y = rnbf(a1); l4.y = rnbf(a1 - bf2f(h4.y));
  h4.z = rnbf(a2); l4.z = rnbf(a2 - bf2f(h4.z));
  h4.w = rnbf(a3); l4.w = rnbf(a3 - bf2f(h4.w));
  *(ushort4*)&wqhi[(size_t)idx * ND + e0] = h4;
  *(ushort4*)&wqlo[(size_t)idx * ND + e0] = l4;
}

// ---------------------------------------------------------------------------
// gemm_tn: C^T-oriented GEMM, no split-K.
//   out[n][m] = sum_k A[m][k] * B[n][k];  M=2048 (m=s), N=192 (n=rh), K=1024.
// A = fp32 (Q or V), reg-staged to bf16 (hi/lo pair iff PAIR), swizzled LDS.
// B = bf16 (pair iff PAIR) via global_load_lds, pre-swizzled source.
// Epilogue writes transposed rows directly (8B bf16x4 per fragment-quad):
//   PAIR:  C0/C1 = s1 hi/lo at row rh
//   !PAIR: C0 = ctx bf16 at remapped row (rh%12)*16 + rh/12
// BM=64, BN=64, BK=64; 4 waves (2x2), wave-tile 32x32. Grid (32, 3, NB).
// ---------------------------------------------------------------------------
template <bool PAIR>
__global__ __launch_bounds__(256) void gemm_tn(
    const float* __restrict__ Af,
    const unsigned short* __restrict__ Bhi, const unsigned short* __restrict__ Blo,
    unsigned short* __restrict__ C0, unsigned short* __restrict__ C1) {
  constexpr int NBUF = PAIR ? 2 : 1;
  __shared__ unsigned short As[NBUF][64 * 64];
  __shared__ unsigned short Bs[NBUF][64 * 64];
  const int tid = threadIdx.x;
  const int lane = tid & 63;
  const int wid = tid >> 6;
  const int wm = wid >> 1, wn = wid & 1;
  const int m0 = blockIdx.x * 64, n0 = blockIdx.y * 64;
  const int b = blockIdx.z;
  const float* pA = Af + (size_t)b * NS * ND;
  const unsigned short* pBhi = Bhi + (size_t)b * NRH * ND;
  const unsigned short* pBlo = PAIR ? Blo + (size_t)b * NRH * ND : nullptr;

  const int rsub = lane >> 3;          // gload row-within-chunk
  const int slot = (lane & 7) ^ rsub;  // pre-swizzled source 16B slot
  const int arow = tid >> 2;           // A-stage row 0..63
  const int jg = (tid & 3) * 2;        // A-stage slot base {0,2,4,6}

  f32x4 acc[2][2];
#pragma unroll
  for (int i = 0; i < 2; ++i)
#pragma unroll
    for (int j = 0; j < 2; ++j) acc[i][j] = (f32x4){0.f, 0.f, 0.f, 0.f};

  for (int k0 = 0; k0 < ND; k0 += 64) {
    // ---- A: fp32 -> bf16 (pair) reg-stage, swizzled ds_write
    const float* asrc = pA + (size_t)(m0 + arow) * ND + k0 + jg * 8;
    char* abase = (char*)&As[0][0] + arow * 128;
#pragma unroll
    for (int jj = 0; jj < 2; ++jj) {
      float4 u = *(const float4*)(asrc + jj * 8);
      float4 v = *(const float4*)(asrc + jj * 8 + 4);
      uint4 h = pk_hi(u, v);
      char* dst = abase + (((jg + jj) ^ (arow & 7)) << 4);
      *(uint4*)dst = h;
      if (PAIR) *(uint4*)(dst + 8192) = pk_lo(u, v, h);
    }
    // ---- B: bf16 via global_load_lds (pre-swizzled source)
#pragma unroll
    for (int cc = 0; cc < 2; ++cc) {
      int c = wid * 2 + cc;
      int grow = n0 + c * 8 + rsub;
      gload16(&pBhi[(size_t)grow * ND + k0 + slot * 8], &Bs[0][c * 512]);
      if (PAIR)
        gload16(&pBlo[(size_t)grow * ND + k0 + slot * 8], &Bs[NBUF - 1][c * 512]);
    }
    __syncthreads();

#pragma unroll
    for (int kk = 0; kk < 64; kk += 32) {
      int sig = (kk >> 3) + (lane >> 4);
      bf16x8 ah[2], al[2], bh[2], bl[2];
#pragma unroll
      for (int fm = 0; fm < 2; ++fm) {
        int r = wm * 32 + fm * 16 + (lane & 15);
        int off = r * 128 + ((sig ^ (r & 7)) << 4);
        ah[fm] = *(const bf16x8*)((const char*)&As[0][0] + off);
        if (PAIR) al[fm] = *(const bf16x8*)((const char*)&As[0][0] + 8192 + off);
      }
#pragma unroll
      for (int fn = 0; fn < 2; ++fn) {
        int r = wn * 32 + fn * 16 + (lane & 15);
        int off = r * 128 + ((sig ^ (r & 7)) << 4);
        bh[fn] = *(const bf16x8*)((const char*)&Bs[0][0] + off);
        if (PAIR) bl[fn] = *(const bf16x8*)((const char*)&Bs[0][0] + 8192 + off);
      }
#pragma unroll
      for (int fm = 0; fm < 2; ++fm)
#pragma unroll
        for (int fn = 0; fn < 2; ++fn) {
          acc[fm][fn] = MFMA(ah[fm], bh[fn], acc[fm][fn]);
          if (PAIR) {
            acc[fm][fn] = MFMA(ah[fm], bl[fn], acc[fm][fn]);
            acc[fm][fn] = MFMA(al[fm], bh[fn], acc[fm][fn]);
          }
        }
    }
    __syncthreads();
  }

  // ---- transposed epilogue: lane's 4 acc values are 4 consecutive m=s
  const int jr = lane >> 4, cl = lane & 15;
#pragma unroll
  for (int fm = 0; fm < 2; ++fm)
#pragma unroll
    for (int fn = 0; fn < 2; ++fn) {
      f32x4 v = acc[fm][fn];
      int s = m0 + wm * 32 + fm * 16 + jr * 4;
      int rh = n0 + wn * 32 + fn * 16 + cl;
      int orow = PAIR ? rh : (rh % NR) * NH + rh / NR;
      size_t o = ((size_t)b * NRH + orow) * NS + s;
      ushort4 h4;
      h4.x = rnbf(v[0]); h4.y = rnbf(v[1]);
      h4.z = rnbf(v[2]); h4.w = rnbf(v[3]);
      *(ushort4*)&C0[o] = h4;
      if (PAIR) {
        ushort4 l4;
        l4.x = rnbf(v[0] - bf2f(h4.x)); l4.y = rnbf(v[1] - bf2f(h4.y));
        l4.z = rnbf(v[2] - bf2f(h4.z)); l4.w = rnbf(v[3] - bf2f(h4.w));
        *(ushort4*)&C1[o] = l4;
      }
    }
}

// ---------------------------------------------------------------------------
// Split-K MFMA GEMM (kept for G2 and G4): P[z][m][n] = partial A.B^T
// BSRC=0: B bf16 (pair iff SPLIT) via global_load_lds
// BSRC=1: B fp32 reg-staged to bf16
// ---------------------------------------------------------------------------
template <bool SPLIT, int BSRC>
__global__ __launch_bounds__(256) void mgemm(
    const unsigned short* __restrict__ Ahi, const unsigned short* __restrict__ Alo,
    const unsigned short* __restrict__ Bhi, const unsigned short* __restrict__ Blo,
    const float* __restrict__ Bf,
    float* __restrict__ P, int kchunk, int lda, int ldb, int ldc,
    long sAb, long sBb, long sPz, int nbatch) {
  constexpr int NBUF = SPLIT ? 2 : 1;
  __shared__ unsigned short As[NBUF][64 * 64];
  __shared__ unsigned short Bs[NBUF][128 * 64];
  const int tid = threadIdx.x;
  const int lane = tid & 63;
  const int wid = tid >> 6;
  const int wm = wid >> 1, wn = wid & 1;
  const int m0 = blockIdx.y * 64, n0 = blockIdx.x * 128;
  const int bz = blockIdx.z;
  const int b = bz % nbatch;
  const int kbeg = (bz / nbatch) * kchunk;
  const unsigned short* pAhi = Ahi + (size_t)b * sAb;
  const unsigned short* pAlo = SPLIT ? (Alo + (size_t)b * sAb) : nullptr;
  const unsigned short* pBhi = (BSRC == 0) ? (Bhi + (size_t)b * sBb) : nullptr;
  const unsigned short* pBlo =
      (BSRC == 0 && SPLIT) ? (Blo + (size_t)b * sBb) : nullptr;
  const float* pBf = (BSRC == 1) ? (Bf + (size_t)b * sBb) : nullptr;

  const int rsub = lane >> 3;
  const int slot = (lane & 7) ^ rsub;

  f32x4 acc[2][4];
#pragma unroll
  for (int i = 0; i < 2; ++i)
#pragma unroll
    for (int j = 0; j < 4; ++j) acc[i][j] = (f32x4){0.f, 0.f, 0.f, 0.f};

  for (int k0 = kbeg; k0 < kbeg + kchunk; k0 += 64) {
#pragma unroll
    for (int cc = 0; cc < 2; ++cc) {
      int c = wid * 2 + cc;
      int grow = m0 + c * 8 + rsub;
      gload16(&pAhi[(size_t)grow * lda + k0 + slot * 8], &As[0][c * 512]);
      if (SPLIT)
        gload16(&pAlo[(size_t)grow * lda + k0 + slot * 8], &As[NBUF - 1][c * 512]);
    }
    if (BSRC == 0) {
#pragma unroll
      for (int cc = 0; cc < 4; ++cc) {
        int c = wid * 4 + cc;
        int grow = n0 + c * 8 + rsub;
        gload16(&pBhi[(size_t)grow * ldb + k0 + slot * 8], &Bs[0][c * 512]);
        if (SPLIT)
          gload16(&pBlo[(size_t)grow * ldb + k0 + slot * 8], &Bs[NBUF - 1][c * 512]);
      }
    } else {
      const int brow = tid >> 1;
      const int jbase = (tid & 1) * 4;
      const float* bsrc = pBf + (size_t)(n0 + brow) * ldb + k0 + jbase * 8;
      char* dbase = (char*)&Bs[0][0] + brow * 128;
#pragma unroll
      for (int jj = 0; jj < 4; ++jj) {
        float4 u = *(const float4*)(bsrc + jj * 8);
        float4 w = *(const float4*)(bsrc + jj * 8 + 4);
        uint4 h = pk_hi(u, w);
        char* dst = dbase + (((jbase + jj) ^ (brow & 7)) << 4);
        *(uint4*)dst = h;
        if (SPLIT) *(uint4*)(dst + 16384) = pk_lo(u, w, h);
      }
    }
    __syncthreads();

#pragma unroll
    for (int kk = 0; kk < 64; kk += 32) {
      int sig = (kk >> 3) + (lane >> 4);
      bf16x8 ah[2], al[2], bh[4], bl[4];
#pragma unroll
      for (int fm = 0; fm < 2; ++fm) {
        int r = wm * 32 + fm * 16 + (lane & 15);
        int off = r * 128 + ((sig ^ (r & 7)) << 4);
        ah[fm] = *(const bf16x8*)((const char*)&As[0][0] + off);
        if (SPLIT) al[fm] = *(const bf16x8*)((const char*)&As[0][0] + 8192 + off);
      }
#pragma unroll
      for (int fn = 0; fn < 4; ++fn) {
        int r = wn * 64 + fn * 16 + (lane & 15);
        int off = r * 128 + ((sig ^ (r & 7)) << 4);
        bh[fn] = *(const bf16x8*)((const char*)&Bs[0][0] + off);
        if (SPLIT) bl[fn] = *(const bf16x8*)((const char*)&Bs[0][0] + 16384 + off);
      }
#pragma unroll
      for (int fm = 0; fm < 2; ++fm)
#pragma unroll
        for (int fn = 0; fn < 4; ++fn) {
          acc[fm][fn] = MFMA(ah[fm], bh[fn], acc[fm][fn]);
          if (SPLIT) {
            acc[fm][fn] = MFMA(ah[fm], bl[fn], acc[fm][fn]);
            acc[fm][fn] = MFMA(al[fm], bh[fn], acc[fm][fn]);
          }
        }
    }
    __syncthreads();
  }

  const int jr = lane >> 4, cl = lane & 15;
  float* pc = P + (size_t)bz * sPz;
#pragma unroll
  for (int fm = 0; fm < 2; ++fm)
#pragma unroll
    for (int fn = 0; fn < 4; ++fn) {
      f32x4 v = acc[fm][fn];
      int gcol = n0 + wn * 64 + fn * 16 + cl;
#pragma unroll
      for (int j = 0; j < 4; ++j) {
        int m = m0 + wm * 32 + fm * 16 + jr * 4 + j;
        pc[(size_t)m * ldc + gcol] = v[j];
      }
    }
}

// ---------------------------------------------------------------------------
// G4 reduce: sum + bias + LayerNorm -> out
// ---------------------------------------------------------------------------
__global__ __launch_bounds__(256) void red_bias_ln(const float* __restrict__ P,
                                                   const float* __restrict__ bias,
                                                   const float* __restrict__ gamma,
                                                   const float* __restrict__ beta,
                                                   float* __restrict__ out,
                                                   int nsplit) {
  int row = blockIdx.x;
  int t = threadIdx.x;
  const size_t slice = 1536 * (size_t)ND;
  float4 a = ((const float4*)(P + (size_t)row * ND))[t];
  for (int s = 1; s < nsplit; ++s) {
    float4 v = ((const float4*)(P + (size_t)s * slice + (size_t)row * ND))[t];
    a.x += v.x; a.y += v.y; a.z += v.z; a.w += v.w;
  }
  float4 bv = ((const float4*)bias)[t];
  a.x += bv.x; a.y += bv.y; a.z += bv.z; a.w += bv.w;

  float s = a.x + a.y + a.z + a.w;
  float ss = a.x * a.x + a.y * a.y + a.z * a.z + a.w * a.w;
#pragma unroll
  for (int off = 32; off > 0; off >>= 1) {
    s += __shfl_xor(s, off);
    ss += __shfl_xor(ss, off);
  }
  __shared__ float red[8];
  int wave = t >> 6, lane = t & 63;
  if (lane == 0) { red[wave] = s; red[4 + wave] = ss; }
  __syncthreads();
  s = red[0] + red[1] + red[2] + red[3];
  ss = red[4] + red[5] + red[6] + red[7];
  float mu = s * (1.0f / ND);
  float var = ss * (1.0f / ND) - mu * mu;
  float inv = rsqrtf(var + 1e-6f);
  float4 g = ((const float4*)gamma)[t];
  float4 be = ((const float4*)beta)[t];
  float4 o;
  o.x = (a.x - mu) * inv * g.x + be.x;
  o.y = (a.y - mu) * inv * g.y + be.y;
  o.z = (a.z - mu) * inv * g.z + be.z;
  o.w = (a.w - mu) * inv * g.w + be.w;
  ((float4*)(out + (size_t)row * ND))[t] = o;
}

// ---------------------------------------------------------------------------
// sm_k: one block per (b,h,r). Sums G2's split partials inline:
// T1[e] = sum_s P[(s*NB+b)][rh][e]; s2[d] = sum_e T1[e]*WKT[e][h64+d] (f32);
// softmax over d=64; A2[bhr][e] = sum_d attn[d]*WV[h64+d][e] -> bf16.
// ---------------------------------------------------------------------------
__global__ __launch_bounds__(256) void sm_k(const float* __restrict__ P,
                                            int nsplit,
                                            const float* __restrict__ WKT,
                                            const float* __restrict__ WV,
                                            unsigned short* __restrict__ A2) {
  int x = blockIdx.x;
  int xcd = x & 7, within = x >> 3;
  int h = xcd + 8 * (within & 1);
  int rb = within >> 1;
  int r = rb >> 2, b = rb & 3;
  int idx = (b * NH + h) * NR + r;
  int rh = h * NR + r;

  const int t = threadIdx.x;
  __shared__ float t1s[ND];
  __shared__ float part[4][NDH];
  __shared__ float attns[NDH];

  {
    const size_t sstride = (size_t)NB * NRH * ND;
    const float* base = P + ((size_t)b * NRH + rh) * ND;
    float4 a = ((const float4*)base)[t];
    for (int s = 1; s < nsplit; ++s) {
      float4 v = ((const float4*)(base + (size_t)s * sstride))[t];
      a.x += v.x; a.y += v.y; a.z += v.z; a.w += v.w;
    }
    ((float4*)t1s)[t] = a;
  }
  __syncthreads();

  {
    int d = t & 63, q = t >> 6;
    const float* wcol = WKT + (size_t)(h * NDH + d);
    float acc = 0.f;
    int e0 = q * 256;
#pragma unroll 8
    for (int e = 0; e < 256; ++e)
      acc += t1s[e0 + e] * wcol[(size_t)(e0 + e) * ND];
    part[q][d] = acc;
  }
  __syncthreads();

  if (t < NDH) {
    float s2 = part[0][t] + part[1][t] + part[2][t] + part[3][t];
    float m = s2;
#pragma unroll
    for (int off = 32; off > 0; off >>= 1) m = fmaxf(m, __shfl_xor(m, off));
    float e = __expf(s2 - m);
    float sum = e;
#pragma unroll
    for (int off = 32; off > 0; off >>= 1) sum += __shfl_xor(sum, off);
    attns[t] = e / sum;
  }
  __syncthreads();

  {
    int e0 = t * 4;
    const float* wv = WV + (size_t)h * NDH * ND + e0;
    float a0 = 0.f, a1 = 0.f, a2 = 0.f, a3 = 0.f;
#pragma unroll 4
    for (int dd = 0; dd < NDH; ++dd) {
      float4 wvv = *(const float4*)&wv[(size_t)dd * ND];
      float a = attns[dd];
      a0 += a * wvv.x; a1 += a * wvv.y; a2 += a * wvv.z; a3 += a * wvv.w;
    }
    ushort4 o;
    o.x = rnbf(a0); o.y = rnbf(a1); o.z = rnbf(a2); o.w = rnbf(a3);
    *(ushort4*)&A2[(size_t)idx * ND + e0] = o;
  }
}

// ---------------------------------------------------------------------------
extern "C" void kernel_launch(void* const* d_in, const int* in_sizes, int n_in,
                              void* d_out, int out_size, void* d_ws, size_t ws_size,
                              hipStream_t stream) {
  const float* Q = (const float*)d_in[0];
  const float* K = (const float*)d_in[1];
  const float* V = (const float*)d_in[2];
  const float* U = (const float*)d_in[3];
  const float* WQ = (const float*)d_in[4];
  const float* WK = (const float*)d_in[5];
  const float* WV = (const float*)d_in[6];
  const float* WL = (const float*)d_in[7];
  const float* bl = (const float*)d_in[8];
  const float* ga = (const float*)d_in[9];
  const float* be = (const float*)d_in[10];
  float* out = (float*)d_out;
  char* w = (char*)d_ws;

  // layout (bytes):
  //  [0, 33.5M)   KThi/KTlo
  //  [33.5M)      wq hi/lo (3.1M)  -> A2b reuse after G1t
  //  [36.7M)      s1 hi/lo (6.3M)  -> WKT reuse after G2
  //  [43.0M)      ctxb (3.1M)
  //  [46.1M...)   P split partials (G2, then G4)
  unsigned short* KThi = (unsigned short*)w;
  unsigned short* KTlo = (unsigned short*)(w + 16777216);
  unsigned short* wqhi = (unsigned short*)(w + 33554432);
  unsigned short* wqlo = (unsigned short*)(w + 35127296);
  unsigned short* A2b = wqhi;
  unsigned short* s1hi = (unsigned short*)(w + 36700160);
  unsigned short* s1lo = (unsigned short*)(w + 39845888);
  float* WKT = (float*)s1hi;
  unsigned short* ctxb = (unsigned short*)(w + 42991616);
  float* P = (float*)(w + 46137344);

  size_t avail = ws_size > 46137344 ? ws_size - 46137344 : 0;
  auto pick = [&](size_t bytesPerSplit, int maxs) {
    int s = 1;
    while (s * 2 <= maxs && bytesPerSplit * (size_t)(s * 2) <= avail) s *= 2;
    return s;
  };
  int sG2 = pick(3145728, 4);   // P: [sG2*4][192][1024] f32
  int sG4 = pick(6291456, 2);   // P: [sG4][1536][1024] f32

  build_wqeff<<<NB * NH * NR, 256, 0, stream>>>(U, WQ, wqhi, wqlo);

  // G1t: s1^T orientation, no split-K. out s1[rh][s] hi/lo directly.
  gemm_tn<true><<<dim3(32, 3, NB), 256, 0, stream>>>(
      Q, wqhi, wqlo, s1hi, s1lo);

  cvt_t_hilo<<<dim3(32, 16, NB), 256, 0, stream>>>(K, KThi, KTlo);

  // G2: T1[rh][e] = s1[rh] . KT[e]  M=192 N=1024 K=2048 (pair, split-K)
  mgemm<true, 0><<<dim3(8, 3, NB * sG2), 256, 0, stream>>>(
      s1hi, s1lo, KThi, KTlo, nullptr, P, 2048 / sG2,
      2048, 2048, 1024, 192L * 2048, 1024L * 2048, 192L * 1024, NB);

  // WK -> WKT (s1 region dead after G2)
  transpose_k<<<dim3(16, 16), 256, 0, stream>>>(WK, WKT, ND, ND);

  // s2 -> softmax -> A2, summing G2 partials inline
  sm_k<<<NB * NH * NR, 256, 0, stream>>>(P, sG2, WKT, WV, A2b);

  // G3t: ctx^T orientation, no split-K; remapped rows (r*16+h) written direct.
  gemm_tn<false><<<dim3(32, 3, NB), 256, 0, stream>>>(
      V, A2b, nullptr, ctxb, nullptr);

  // G4: lin = ctx_flat @ WL^T  M=1536 N=1024 K=1024 (B=WL fp32, split-K)
  mgemm<false, 1><<<dim3(8, 24, sG4), 256, 0, stream>>>(
      ctxb, nullptr, nullptr, nullptr, WL, P, 1024 / sG4,
      1024, 1024, 1024, 0, 0, 1536L * 1024, 1);
  red_bias_ln<<<1536, 256, 0, stream>>>(P, bl, ga, be, out, sG4);
}

// Round 7
// 130.435 us; speedup vs baseline: 2.7042x; 1.0725x over previous
//
#include <hip/hip_runtime.h>

#define NB 4
#define NS 2048
#define ND 1024
#define NH 16
#define NDH 64
#define NR 12
#define NRH 192

typedef __attribute__((ext_vector_type(8))) short bf16x8;
typedef __attribute__((ext_vector_type(4))) float f32x4;

__device__ __forceinline__ unsigned short rnbf(float f) {
  unsigned u = __float_as_uint(f);
  u += 0x7fffu + ((u >> 16) & 1u);
  return (unsigned short)(u >> 16);
}
__device__ __forceinline__ float bf2f(unsigned short h) {
  return __uint_as_float(((unsigned)h) << 16);
}

// v_cvt_pk_bf16_f32: dst[15:0]=bf16(a) RNE, dst[31:16]=bf16(b)
__device__ __forceinline__ unsigned cvtpk(float a, float b) {
  unsigned r;
  asm("v_cvt_pk_bf16_f32 %0, %1, %2" : "=v"(r) : "v"(a), "v"(b));
  return r;
}
__device__ __forceinline__ uint4 pk_hi(float4 u, float4 w) {
  uint4 h;
  h.x = cvtpk(u.x, u.y); h.y = cvtpk(u.z, u.w);
  h.z = cvtpk(w.x, w.y); h.w = cvtpk(w.z, w.w);
  return h;
}
__device__ __forceinline__ unsigned lo2(float a, float b, unsigned hh) {
  float ah = __uint_as_float(hh << 16);
  float bh = __uint_as_float(hh & 0xffff0000u);
  return cvtpk(a - ah, b - bh);
}
__device__ __forceinline__ uint4 pk_lo(float4 u, float4 w, uint4 h) {
  uint4 l;
  l.x = lo2(u.x, u.y, h.x); l.y = lo2(u.z, u.w, h.y);
  l.z = lo2(w.x, w.y, h.z); l.w = lo2(w.z, w.w, h.w);
  return l;
}

__device__ __forceinline__ void gload16(const void* g, void* l) {
  __builtin_amdgcn_global_load_lds(
      (const __attribute__((address_space(1))) unsigned int*)g,
      (__attribute__((address_space(3))) unsigned int*)l, 16, 0, 0);
}

#define MFMA(a, b, c) __builtin_amdgcn_mfma_f32_16x16x32_bf16(a, b, c, 0, 0, 0)

// ---------------------------------------------------------------------------
// f32 [rows][cols] -> transpose [cols][rows]
// ---------------------------------------------------------------------------
__global__ __launch_bounds__(256) void transpose_k(const float* __restrict__ in,
                                                   float* __restrict__ out,
                                                   int rows, int cols) {
  __shared__ float tb[64][65];
  int r0 = blockIdx.y * 64, c0 = blockIdx.x * 64;
  int tx = threadIdx.x & 15, ty = threadIdx.x >> 4;
#pragma unroll
  for (int rr = 0; rr < 4; ++rr) {
    int row = ty + rr * 16;
    float4 v = *(const float4*)&in[(size_t)(r0 + row) * cols + c0 + tx * 4];
    tb[row][tx * 4 + 0] = v.x; tb[row][tx * 4 + 1] = v.y;
    tb[row][tx * 4 + 2] = v.z; tb[row][tx * 4 + 3] = v.w;
  }
  __syncthreads();
#pragma unroll
  for (int rr = 0; rr < 4; ++rr) {
    int orow = ty + rr * 16;
    float4 o;
    o.x = tb[tx * 4 + 0][orow];
    o.y = tb[tx * 4 + 1][orow];
    o.z = tb[tx * 4 + 2][orow];
    o.w = tb[tx * 4 + 3][orow];
    *(float4*)&out[(size_t)(c0 + orow) * rows + r0 + tx * 4] = o;
  }
}

// ---------------------------------------------------------------------------
// Wq_eff[b,h,r,e] = sum_d U[b,h,r,d] * W_Q[h*64+d, e]  -> hi/lo bf16
// ---------------------------------------------------------------------------
__global__ __launch_bounds__(256) void build_wqeff(const float* __restrict__ U,
                                                   const float* __restrict__ WQ,
                                                   unsigned short* __restrict__ wqhi,
                                                   unsigned short* __restrict__ wqlo) {
  int idx = blockIdx.x;
  int hr = idx % (NH * NR);
  int h = hr / NR;
  __shared__ float u[NDH];
  int t = threadIdx.x;
  if (t < NDH) u[t] = U[(size_t)idx * NDH + t];
  __syncthreads();
  int e0 = t * 4;
  float a0 = 0.f, a1 = 0.f, a2 = 0.f, a3 = 0.f;
  const float* wbase = WQ + (size_t)h * NDH * ND + e0;
#pragma unroll 4
  for (int d = 0; d < NDH; ++d) {
    float uv = u[d];
    const float* wr = wbase + (size_t)d * ND;
    a0 += uv * wr[0]; a1 += uv * wr[1]; a2 += uv * wr[2]; a3 += uv * wr[3];
  }
  ushort4 h4, l4;
  h4.x = rnbf(a0); l4.x = rnbf(a0 - bf2f(h4.x));
  h4.y = rnbf(a1); l4.y = rnbf(a1 - bf2f(h4.y));
  h4.z = rnbf(a2); l4.z = rnbf(a2 - bf2f(h4.z));
  h4.w = rnbf(a3); l4.w = rnbf(a3 - bf2f(h4.w));
  *(ushort4*)&wqhi[(size_t)idx * ND + e0] = h4;
  *(ushort4*)&wqlo[(size_t)idx * ND + e0] = l4;
}

// ---------------------------------------------------------------------------
// gemm_tn: C^T-oriented GEMM, no split-K (unchanged from round 6).
// ---------------------------------------------------------------------------
template <bool PAIR>
__global__ __launch_bounds__(256) void gemm_tn(
    const float* __restrict__ Af,
    const unsigned short* __restrict__ Bhi, const unsigned short* __restrict__ Blo,
    unsigned short* __restrict__ C0, unsigned short* __restrict__ C1) {
  constexpr int NBUF = PAIR ? 2 : 1;
  __shared__ unsigned short As[NBUF][64 * 64];
  __shared__ unsigned short Bs[NBUF][64 * 64];
  const int tid = threadIdx.x;
  const int lane = tid & 63;
  const int wid = tid >> 6;
  const int wm = wid >> 1, wn = wid & 1;
  const int m0 = blockIdx.x * 64, n0 = blockIdx.y * 64;
  const int b = blockIdx.z;
  const float* pA = Af + (size_t)b * NS * ND;
  const unsigned short* pBhi = Bhi + (size_t)b * NRH * ND;
  const unsigned short* pBlo = PAIR ? Blo + (size_t)b * NRH * ND : nullptr;

  const int rsub = lane >> 3;
  const int slot = (lane & 7) ^ rsub;
  const int arow = tid >> 2;
  const int jg = (tid & 3) * 2;

  f32x4 acc[2][2];
#pragma unroll
  for (int i = 0; i < 2; ++i)
#pragma unroll
    for (int j = 0; j < 2; ++j) acc[i][j] = (f32x4){0.f, 0.f, 0.f, 0.f};

  for (int k0 = 0; k0 < ND; k0 += 64) {
    const float* asrc = pA + (size_t)(m0 + arow) * ND + k0 + jg * 8;
    char* abase = (char*)&As[0][0] + arow * 128;
#pragma unroll
    for (int jj = 0; jj < 2; ++jj) {
      float4 u = *(const float4*)(asrc + jj * 8);
      float4 v = *(const float4*)(asrc + jj * 8 + 4);
      uint4 h = pk_hi(u, v);
      char* dst = abase + (((jg + jj) ^ (arow & 7)) << 4);
      *(uint4*)dst = h;
      if (PAIR) *(uint4*)(dst + 8192) = pk_lo(u, v, h);
    }
#pragma unroll
    for (int cc = 0; cc < 2; ++cc) {
      int c = wid * 2 + cc;
      int grow = n0 + c * 8 + rsub;
      gload16(&pBhi[(size_t)grow * ND + k0 + slot * 8], &Bs[0][c * 512]);
      if (PAIR)
        gload16(&pBlo[(size_t)grow * ND + k0 + slot * 8], &Bs[NBUF - 1][c * 512]);
    }
    __syncthreads();

#pragma unroll
    for (int kk = 0; kk < 64; kk += 32) {
      int sig = (kk >> 3) + (lane >> 4);
      bf16x8 ah[2], al[2], bh[2], bl[2];
#pragma unroll
      for (int fm = 0; fm < 2; ++fm) {
        int r = wm * 32 + fm * 16 + (lane & 15);
        int off = r * 128 + ((sig ^ (r & 7)) << 4);
        ah[fm] = *(const bf16x8*)((const char*)&As[0][0] + off);
        if (PAIR) al[fm] = *(const bf16x8*)((const char*)&As[0][0] + 8192 + off);
      }
#pragma unroll
      for (int fn = 0; fn < 2; ++fn) {
        int r = wn * 32 + fn * 16 + (lane & 15);
        int off = r * 128 + ((sig ^ (r & 7)) << 4);
        bh[fn] = *(const bf16x8*)((const char*)&Bs[0][0] + off);
        if (PAIR) bl[fn] = *(const bf16x8*)((const char*)&Bs[0][0] + 8192 + off);
      }
#pragma unroll
      for (int fm = 0; fm < 2; ++fm)
#pragma unroll
        for (int fn = 0; fn < 2; ++fn) {
          acc[fm][fn] = MFMA(ah[fm], bh[fn], acc[fm][fn]);
          if (PAIR) {
            acc[fm][fn] = MFMA(ah[fm], bl[fn], acc[fm][fn]);
            acc[fm][fn] = MFMA(al[fm], bh[fn], acc[fm][fn]);
          }
        }
    }
    __syncthreads();
  }

  const int jr = lane >> 4, cl = lane & 15;
#pragma unroll
  for (int fm = 0; fm < 2; ++fm)
#pragma unroll
    for (int fn = 0; fn < 2; ++fn) {
      f32x4 v = acc[fm][fn];
      int s = m0 + wm * 32 + fm * 16 + jr * 4;
      int rh = n0 + wn * 32 + fn * 16 + cl;
      int orow = PAIR ? rh : (rh % NR) * NH + rh / NR;
      size_t o = ((size_t)b * NRH + orow) * NS + s;
      ushort4 h4;
      h4.x = rnbf(v[0]); h4.y = rnbf(v[1]);
      h4.z = rnbf(v[2]); h4.w = rnbf(v[3]);
      *(ushort4*)&C0[o] = h4;
      if (PAIR) {
        ushort4 l4;
        l4.x = rnbf(v[0] - bf2f(h4.x)); l4.y = rnbf(v[1] - bf2f(h4.y));
        l4.z = rnbf(v[2] - bf2f(h4.z)); l4.w = rnbf(v[3] - bf2f(h4.w));
        *(ushort4*)&C1[o] = l4;
      }
    }
}

// ---------------------------------------------------------------------------
// Split-K MFMA GEMM: P[z][m][n] = partial sum_k A[m][k]*B[n][k]
// BSRC=1: B fp32 [n][k] reg-staged to bf16 (BNT=128)
// BSRC=2: B fp32 [k][n] (K matrix) — in-kernel LDS transpose + hi/lo convert
//         (BNT=64): f32 tile -> tbuf -> column read -> cvt_pk -> swizzled Bs
// ---------------------------------------------------------------------------
template <bool SPLIT, int BSRC, int BNT>
__global__ __launch_bounds__(256) void mgemm(
    const unsigned short* __restrict__ Ahi, const unsigned short* __restrict__ Alo,
    const float* __restrict__ Bf,
    float* __restrict__ P, int kchunk, int lda, int ldb, int ldc,
    long sAb, long sBb, long sPz, int nbatch) {
  constexpr int NBUF = SPLIT ? 2 : 1;
  constexpr int NFN = BNT / 32;
  __shared__ unsigned short As[NBUF][64 * 64];
  __shared__ unsigned short Bs[NBUF][BNT * 64];
  __shared__ float tbuf[(BSRC == 2) ? 64 * 68 : 4];
  const int tid = threadIdx.x;
  const int lane = tid & 63;
  const int wid = tid >> 6;
  const int wm = wid >> 1, wn = wid & 1;
  const int m0 = blockIdx.y * 64, n0 = blockIdx.x * BNT;
  const int bz = blockIdx.z;
  const int b = bz % nbatch;
  const int kbeg = (bz / nbatch) * kchunk;
  const unsigned short* pAhi = Ahi + (size_t)b * sAb;
  const unsigned short* pAlo = SPLIT ? (Alo + (size_t)b * sAb) : nullptr;
  const float* pBf = Bf + (size_t)b * sBb;

  const int rsub = lane >> 3;
  const int slot = (lane & 7) ^ rsub;

  f32x4 acc[2][NFN];
#pragma unroll
  for (int i = 0; i < 2; ++i)
#pragma unroll
    for (int j = 0; j < NFN; ++j) acc[i][j] = (f32x4){0.f, 0.f, 0.f, 0.f};

  for (int k0 = kbeg; k0 < kbeg + kchunk; k0 += 64) {
    // ---- A: bf16 (pair iff SPLIT) via global_load_lds, pre-swizzled source
#pragma unroll
    for (int cc = 0; cc < 2; ++cc) {
      int c = wid * 2 + cc;
      int grow = m0 + c * 8 + rsub;
      gload16(&pAhi[(size_t)grow * lda + k0 + slot * 8], &As[0][c * 512]);
      if (SPLIT)
        gload16(&pAlo[(size_t)grow * lda + k0 + slot * 8], &As[NBUF - 1][c * 512]);
    }
    // ---- B
    if constexpr (BSRC == 1) {
      // fp32 [n][k], k contiguous: reg-stage, swizzled ds_write (BNT=128)
      const int brow = tid >> 1;
      const int jbase = (tid & 1) * 4;
      const float* bsrc = pBf + (size_t)(n0 + brow) * ldb + k0 + jbase * 8;
      char* dbase = (char*)&Bs[0][0] + brow * 128;
#pragma unroll
      for (int jj = 0; jj < 4; ++jj) {
        float4 u = *(const float4*)(bsrc + jj * 8);
        float4 w = *(const float4*)(bsrc + jj * 8 + 4);
        uint4 h = pk_hi(u, w);
        char* dst = dbase + (((jbase + jj) ^ (brow & 7)) << 4);
        *(uint4*)dst = h;
        if (SPLIT) *(uint4*)(dst + 2 * 64 * BNT) = pk_lo(u, w, h);
      }
      __syncthreads();
    } else {
      // BSRC == 2: fp32 [k][n] (K). Stage f32 tile then transpose+convert.
      {
        const int sr = tid >> 2;          // s-row 0..63
        const int eg = (tid & 3) * 16;    // e group (BNT=64)
        const float* ksrc = pBf + (size_t)(k0 + sr) * ldb + n0 + eg;
        float* td = &tbuf[sr * 68 + eg];
        *(float4*)(td + 0)  = *(const float4*)(ksrc + 0);
        *(float4*)(td + 4)  = *(const float4*)(ksrc + 4);
        *(float4*)(td + 8)  = *(const float4*)(ksrc + 8);
        *(float4*)(td + 12) = *(const float4*)(ksrc + 12);
      }
      __syncthreads();
      {
        const int e = tid & 63;
        const int sg = (tid >> 6) * 16;   // 16 s-values per thread
        float v[16];
#pragma unroll
        for (int i = 0; i < 16; ++i) v[i] = tbuf[(sg + i) * 68 + e];
        float4 u0 = {v[0], v[1], v[2], v[3]},   w0 = {v[4], v[5], v[6], v[7]};
        float4 u1 = {v[8], v[9], v[10], v[11]}, w1 = {v[12], v[13], v[14], v[15]};
        uint4 h0 = pk_hi(u0, w0), h1 = pk_hi(u1, w1);
        int j0 = sg >> 3;
        char* dbase = (char*)&Bs[0][0] + e * 128;
        *(uint4*)(dbase + (((j0 + 0) ^ (e & 7)) << 4)) = h0;
        *(uint4*)(dbase + (((j0 + 1) ^ (e & 7)) << 4)) = h1;
        if (SPLIT) {
          *(uint4*)(dbase + 2 * 64 * BNT + (((j0 + 0) ^ (e & 7)) << 4)) =
              pk_lo(u0, w0, h0);
          *(uint4*)(dbase + 2 * 64 * BNT + (((j0 + 1) ^ (e & 7)) << 4)) =
              pk_lo(u1, w1, h1);
        }
      }
      __syncthreads();
    }

    // ---- compute
#pragma unroll
    for (int kk = 0; kk < 64; kk += 32) {
      int sig = (kk >> 3) + (lane >> 4);
      bf16x8 ah[2], al[2], bh[NFN], bl[NFN];
#pragma unroll
      for (int fm = 0; fm < 2; ++fm) {
        int r = wm * 32 + fm * 16 + (lane & 15);
        int off = r * 128 + ((sig ^ (r & 7)) << 4);
        ah[fm] = *(const bf16x8*)((const char*)&As[0][0] + off);
        if (SPLIT) al[fm] = *(const bf16x8*)((const char*)&As[0][0] + 8192 + off);
      }
#pragma unroll
      for (int fn = 0; fn < NFN; ++fn) {
        int r = wn * (BNT / 2) + fn * 16 + (lane & 15);
        int off = r * 128 + ((sig ^ (r & 7)) << 4);
        bh[fn] = *(const bf16x8*)((const char*)&Bs[0][0] + off);
        if (SPLIT)
          bl[fn] = *(const bf16x8*)((const char*)&Bs[0][0] + 2 * 64 * BNT + off);
      }
#pragma unroll
      for (int fm = 0; fm < 2; ++fm)
#pragma unroll
        for (int fn = 0; fn < NFN; ++fn) {
          acc[fm][fn] = MFMA(ah[fm], bh[fn], acc[fm][fn]);
          if (SPLIT) {
            acc[fm][fn] = MFMA(ah[fm], bl[fn], acc[fm][fn]);
            acc[fm][fn] = MFMA(al[fm], bh[fn], acc[fm][fn]);
          }
        }
    }
    __syncthreads();
  }

  const int jr = lane >> 4, cl = lane & 15;
  float* pc = P + (size_t)bz * sPz;
#pragma unroll
  for (int fm = 0; fm < 2; ++fm)
#pragma unroll
    for (int fn = 0; fn < NFN; ++fn) {
      f32x4 v = acc[fm][fn];
      int gcol = n0 + wn * (BNT / 2) + fn * 16 + cl;
#pragma unroll
      for (int j = 0; j < 4; ++j) {
        int m = m0 + wm * 32 + fm * 16 + jr * 4 + j;
        pc[(size_t)m * ldc + gcol] = v[j];
      }
    }
}

// ---------------------------------------------------------------------------
// G4 reduce: sum + bias + LayerNorm -> out
// ---------------------------------------------------------------------------
__global__ __launch_bounds__(256) void red_bias_ln(const float* __restrict__ P,
                                                   const float* __restrict__ bias,
                                                   const float* __restrict__ gamma,
                                                   const float* __restrict__ beta,
                                                   float* __restrict__ out,
                                                   int nsplit) {
  int row = blockIdx.x;
  int t = threadIdx.x;
  const size_t slice = 1536 * (size_t)ND;
  float4 a = ((const float4*)(P + (size_t)row * ND))[t];
  for (int s = 1; s < nsplit; ++s) {
    float4 v = ((const float4*)(P + (size_t)s * slice + (size_t)row * ND))[t];
    a.x += v.x; a.y += v.y; a.z += v.z; a.w += v.w;
  }
  float4 bv = ((const float4*)bias)[t];
  a.x += bv.x; a.y += bv.y; a.z += bv.z; a.w += bv.w;

  float s = a.x + a.y + a.z + a.w;
  float ss = a.x * a.x + a.y * a.y + a.z * a.z + a.w * a.w;
#pragma unroll
  for (int off = 32; off > 0; off >>= 1) {
    s += __shfl_xor(s, off);
    ss += __shfl_xor(ss, off);
  }
  __shared__ float red[8];
  int wave = t >> 6, lane = t & 63;
  if (lane == 0) { red[wave] = s; red[4 + wave] = ss; }
  __syncthreads();
  s = red[0] + red[1] + red[2] + red[3];
  ss = red[4] + red[5] + red[6] + red[7];
  float mu = s * (1.0f / ND);
  float var = ss * (1.0f / ND) - mu * mu;
  float inv = rsqrtf(var + 1e-6f);
  float4 g = ((const float4*)gamma)[t];
  float4 be = ((const float4*)beta)[t];
  float4 o;
  o.x = (a.x - mu) * inv * g.x + be.x;
  o.y = (a.y - mu) * inv * g.y + be.y;
  o.z = (a.z - mu) * inv * g.z + be.z;
  o.w = (a.w - mu) * inv * g.w + be.w;
  ((float4*)(out + (size_t)row * ND))[t] = o;
}

// ---------------------------------------------------------------------------
// sm_k: one block per (b,h,r). Sums G2's split partials inline.
// ---------------------------------------------------------------------------
__global__ __launch_bounds__(256) void sm_k(const float* __restrict__ P,
                                            int nsplit,
                                            const float* __restrict__ WKT,
                                            const float* __restrict__ WV,
                                            unsigned short* __restrict__ A2) {
  int x = blockIdx.x;
  int xcd = x & 7, within = x >> 3;
  int h = xcd + 8 * (within & 1);
  int rb = within >> 1;
  int r = rb >> 2, b = rb & 3;
  int idx = (b * NH + h) * NR + r;
  int rh = h * NR + r;

  const int t = threadIdx.x;
  __shared__ float t1s[ND];
  __shared__ float part[4][NDH];
  __shared__ float attns[NDH];

  {
    const size_t sstride = (size_t)NB * NRH * ND;
    const float* base = P + ((size_t)b * NRH + rh) * ND;
    float4 a = ((const float4*)base)[t];
    for (int s = 1; s < nsplit; ++s) {
      float4 v = ((const float4*)(base + (size_t)s * sstride))[t];
      a.x += v.x; a.y += v.y; a.z += v.z; a.w += v.w;
    }
    ((float4*)t1s)[t] = a;
  }
  __syncthreads();

  {
    int d = t & 63, q = t >> 6;
    const float* wcol = WKT + (size_t)(h * NDH + d);
    float acc = 0.f;
    int e0 = q * 256;
#pragma unroll 8
    for (int e = 0; e < 256; ++e)
      acc += t1s[e0 + e] * wcol[(size_t)(e0 + e) * ND];
    part[q][d] = acc;
  }
  __syncthreads();

  if (t < NDH) {
    float s2 = part[0][t] + part[1][t] + part[2][t] + part[3][t];
    float m = s2;
#pragma unroll
    for (int off = 32; off > 0; off >>= 1) m = fmaxf(m, __shfl_xor(m, off));
    float e = __expf(s2 - m);
    float sum = e;
#pragma unroll
    for (int off = 32; off > 0; off >>= 1) sum += __shfl_xor(sum, off);
    attns[t] = e / sum;
  }
  __syncthreads();

  {
    int e0 = t * 4;
    const float* wv = WV + (size_t)h * NDH * ND + e0;
    float a0 = 0.f, a1 = 0.f, a2 = 0.f, a3 = 0.f;
#pragma unroll 4
    for (int dd = 0; dd < NDH; ++dd) {
      float4 wvv = *(const float4*)&wv[(size_t)dd * ND];
      float a = attns[dd];
      a0 += a * wvv.x; a1 += a * wvv.y; a2 += a * wvv.z; a3 += a * wvv.w;
    }
    ushort4 o;
    o.x = rnbf(a0); o.y = rnbf(a1); o.z = rnbf(a2); o.w = rnbf(a3);
    *(ushort4*)&A2[(size_t)idx * ND + e0] = o;
  }
}

// ---------------------------------------------------------------------------
extern "C" void kernel_launch(void* const* d_in, const int* in_sizes, int n_in,
                              void* d_out, int out_size, void* d_ws, size_t ws_size,
                              hipStream_t stream) {
  const float* Q = (const float*)d_in[0];
  const float* K = (const float*)d_in[1];
  const float* V = (const float*)d_in[2];
  const float* U = (const float*)d_in[3];
  const float* WQ = (const float*)d_in[4];
  const float* WK = (const float*)d_in[5];
  const float* WV = (const float*)d_in[6];
  const float* WL = (const float*)d_in[7];
  const float* bl = (const float*)d_in[8];
  const float* ga = (const float*)d_in[9];
  const float* be = (const float*)d_in[10];
  float* out = (float*)d_out;
  char* w = (char*)d_ws;

  // layout (bytes):
  //  [0)        wq hi/lo (3.1M)  -> A2b reuse after G1t
  //  [3.1M)     s1hi (3.1M)
  //  [6.3M)     s1lo (3.1M)
  //  [9.4M)     ctxb (3.1M)
  //  [12.6M)    WKT (4.2M)
  //  [16.8M...) P split partials (G2, then G4)
  unsigned short* wqhi = (unsigned short*)w;
  unsigned short* wqlo = (unsigned short*)(w + 1572864);
  unsigned short* A2b = wqhi;
  unsigned short* s1hi = (unsigned short*)(w + 3145728);
  unsigned short* s1lo = (unsigned short*)(w + 6291456);
  unsigned short* ctxb = (unsigned short*)(w + 9437184);
  float* WKT = (float*)(w + 12582912);
  float* P = (float*)(w + 16777216);

  size_t avail = ws_size > 16777216 ? ws_size - 16777216 : 0;
  auto pick = [&](size_t bytesPerSplit, int maxs) {
    int s = 1;
    while (s * 2 <= maxs && bytesPerSplit * (size_t)(s * 2) <= avail) s *= 2;
    return s;
  };
  int sG2 = pick(3145728, 4);   // P: [sG2*4][192][1024] f32
  int sG4 = pick(6291456, 2);   // P: [sG4][1536][1024] f32

  build_wqeff<<<NB * NH * NR, 256, 0, stream>>>(U, WQ, wqhi, wqlo);

  // G1t: s1^T orientation, no split-K. out s1[rh][s] hi/lo directly.
  gemm_tn<true><<<dim3(32, 3, NB), 256, 0, stream>>>(
      Q, wqhi, wqlo, s1hi, s1lo);

  // G2: T1[rh][e] = s1[rh] . K[.][e]  M=192 N=1024 K=2048 (pair, split-K,
  //     fused in-kernel K transpose+convert; BNT=64)
  mgemm<true, 2, 64><<<dim3(16, 3, NB * sG2), 256, 0, stream>>>(
      s1hi, s1lo, K, P, 2048 / sG2,
      2048, 1024, 1024, 192L * 2048, 2048L * 1024, 192L * 1024, NB);

  // WK -> WKT
  transpose_k<<<dim3(16, 16), 256, 0, stream>>>(WK, WKT, ND, ND);

  // s2 -> softmax -> A2, summing G2 partials inline
  sm_k<<<NB * NH * NR, 256, 0, stream>>>(P, sG2, WKT, WV, A2b);

  // G3t: ctx^T orientation, no split-K; remapped rows (r*16+h) written direct.
  gemm_tn<false><<<dim3(32, 3, NB), 256, 0, stream>>>(
      V, A2b, nullptr, ctxb, nullptr);

  // G4: lin = ctx_flat @ WL^T  M=1536 N=1024 K=1024 (B=WL fp32, split-K)
  mgemm<false, 1, 128><<<dim3(8, 24, sG4), 256, 0, stream>>>(
      ctxb, nullptr, WL, P, 1024 / sG4,
      1024, 1024, 1024, 0, 0, 1536L * 1024, 1);
  red_bias_ln<<<1536, 256, 0, stream>>>(P, bl, ga, be, out, sG4);
}

// Round 8
// 107.854 us; speedup vs baseline: 3.2704x; 1.2094x over previous
//
#include <hip/hip_runtime.h>

#define NB 4
#define NS 2048
#define ND 1024
#define NH 16
#define NDH 64
#define NR 12
#define NRH 192

typedef __attribute__((ext_vector_type(8))) short bf16x8;
typedef __attribute__((ext_vector_type(4))) float f32x4;

__device__ __forceinline__ unsigned short rnbf(float f) {
  unsigned u = __float_as_uint(f);
  u += 0x7fffu + ((u >> 16) & 1u);
  return (unsigned short)(u >> 16);
}
__device__ __forceinline__ float bf2f(unsigned short h) {
  return __uint_as_float(((unsigned)h) << 16);
}

// v_cvt_pk_bf16_f32: dst[15:0]=bf16(a) RNE, dst[31:16]=bf16(b)
__device__ __forceinline__ unsigned cvtpk(float a, float b) {
  unsigned r;
  asm("v_cvt_pk_bf16_f32 %0, %1, %2" : "=v"(r) : "v"(a), "v"(b));
  return r;
}
__device__ __forceinline__ uint4 pk_hi(float4 u, float4 w) {
  uint4 h;
  h.x = cvtpk(u.x, u.y); h.y = cvtpk(u.z, u.w);
  h.z = cvtpk(w.x, w.y); h.w = cvtpk(w.z, w.w);
  return h;
}
__device__ __forceinline__ unsigned lo2(float a, float b, unsigned hh) {
  float ah = __uint_as_float(hh << 16);
  float bh = __uint_as_float(hh & 0xffff0000u);
  return cvtpk(a - ah, b - bh);
}
__device__ __forceinline__ uint4 pk_lo(float4 u, float4 w, uint4 h) {
  uint4 l;
  l.x = lo2(u.x, u.y, h.x); l.y = lo2(u.z, u.w, h.y);
  l.z = lo2(w.x, w.y, h.z); l.w = lo2(w.z, w.w, h.w);
  return l;
}

__device__ __forceinline__ void gload16(const void* g, void* l) {
  __builtin_amdgcn_global_load_lds(
      (const __attribute__((address_space(1))) unsigned int*)g,
      (__attribute__((address_space(3))) unsigned int*)l, 16, 0, 0);
}

#define MFMA(a, b, c) __builtin_amdgcn_mfma_f32_16x16x32_bf16(a, b, c, 0, 0, 0)

// ---------------------------------------------------------------------------
// Wq_eff[b,h,r,e] = sum_d U[b,h,r,d] * W_Q[h*64+d, e]  -> hi/lo bf16
// ---------------------------------------------------------------------------
__global__ __launch_bounds__(256) void build_wqeff(const float* __restrict__ U,
                                                   const float* __restrict__ WQ,
                                                   unsigned short* __restrict__ wqhi,
                                                   unsigned short* __restrict__ wqlo) {
  int idx = blockIdx.x;
  int hr = idx % (NH * NR);
  int h = hr / NR;
  __shared__ float u[NDH];
  int t = threadIdx.x;
  if (t < NDH) u[t] = U[(size_t)idx * NDH + t];
  __syncthreads();
  int e0 = t * 4;
  float a0 = 0.f, a1 = 0.f, a2 = 0.f, a3 = 0.f;
  const float* wbase = WQ + (size_t)h * NDH * ND + e0;
#pragma unroll 4
  for (int d = 0; d < NDH; ++d) {
    float uv = u[d];
    const float* wr = wbase + (size_t)d * ND;
    a0 += uv * wr[0]; a1 += uv * wr[1]; a2 += uv * wr[2]; a3 += uv * wr[3];
  }
  ushort4 h4, l4;
  h4.x = rnbf(a0); l4.x = rnbf(a0 - bf2f(h4.x));
  h4.y = rnbf(a1); l4.y = rnbf(a1 - bf2f(h4.y));
  h4.z = rnbf(a2); l4.z = rnbf(a2 - bf2f(h4.z));
  h4.w = rnbf(a3); l4.w = rnbf(a3 - bf2f(h4.w));
  *(ushort4*)&wqhi[(size_t)idx * ND + e0] = h4;
  *(ushort4*)&wqlo[(size_t)idx * ND + e0] = l4;
}

// ---------------------------------------------------------------------------
// gemm_tn: C^T-oriented GEMM, no split-K.
//   out[n][m] = sum_k A[m][k]*B[n][k]; M=2048(s), N=192(rh), K=1024.
// BMT = 32 or 64 m-rows per block; grid (NS/BMT, 3, NB).
// A = fp32 reg-staged to bf16 (pair iff PAIR), swizzled LDS.
// B = bf16 (pair iff PAIR) via global_load_lds, pre-swizzled source.
// Epilogue: PAIR -> s1 hi/lo rows rh; !PAIR -> ctx bf16 rows (rh%12)*16+rh/12.
// ---------------------------------------------------------------------------
template <bool PAIR, int BMT>
__global__ __launch_bounds__(256) void gemm_tn(
    const float* __restrict__ Af,
    const unsigned short* __restrict__ Bhi, const unsigned short* __restrict__ Blo,
    unsigned short* __restrict__ C0, unsigned short* __restrict__ C1) {
  constexpr int NBUF = PAIR ? 2 : 1;
  constexpr int FM = BMT / 32;
  constexpr int ALO = BMT * 128;  // bytes in one As plane
  __shared__ unsigned short As[NBUF][BMT * 64];
  __shared__ unsigned short Bs[NBUF][64 * 64];
  const int tid = threadIdx.x;
  const int lane = tid & 63;
  const int wid = tid >> 6;
  const int wm = wid >> 1, wn = wid & 1;
  const int m0 = blockIdx.x * BMT, n0 = blockIdx.y * 64;
  const int b = blockIdx.z;
  const float* pA = Af + (size_t)b * NS * ND;
  const unsigned short* pBhi = Bhi + (size_t)b * NRH * ND;
  const unsigned short* pBlo = PAIR ? Blo + (size_t)b * NRH * ND : nullptr;

  const int rsub = lane >> 3;
  const int slot = (lane & 7) ^ rsub;

  f32x4 acc[FM][2];
#pragma unroll
  for (int i = 0; i < FM; ++i)
#pragma unroll
    for (int j = 0; j < 2; ++j) acc[i][j] = (f32x4){0.f, 0.f, 0.f, 0.f};

  for (int k0 = 0; k0 < ND; k0 += 64) {
    // ---- A: fp32 -> bf16 (pair) reg-stage, swizzled ds_write
    if constexpr (BMT == 64) {
      const int arow = tid >> 2;
      const int jg = (tid & 3) * 2;
      const float* asrc = pA + (size_t)(m0 + arow) * ND + k0 + jg * 8;
      char* abase = (char*)&As[0][0] + arow * 128;
#pragma unroll
      for (int jj = 0; jj < 2; ++jj) {
        float4 u = *(const float4*)(asrc + jj * 8);
        float4 v = *(const float4*)(asrc + jj * 8 + 4);
        uint4 h = pk_hi(u, v);
        char* dst = abase + (((jg + jj) ^ (arow & 7)) << 4);
        *(uint4*)dst = h;
        if (PAIR) *(uint4*)(dst + ALO) = pk_lo(u, v, h);
      }
    } else {
      const int arow = tid >> 3;
      const int jg = tid & 7;
      const float* asrc = pA + (size_t)(m0 + arow) * ND + k0 + jg * 8;
      float4 u = *(const float4*)(asrc);
      float4 v = *(const float4*)(asrc + 4);
      uint4 h = pk_hi(u, v);
      char* dst = (char*)&As[0][0] + arow * 128 + ((jg ^ (arow & 7)) << 4);
      *(uint4*)dst = h;
      if (PAIR) *(uint4*)(dst + ALO) = pk_lo(u, v, h);
    }
    // ---- B: bf16 via global_load_lds (pre-swizzled source)
#pragma unroll
    for (int cc = 0; cc < 2; ++cc) {
      int c = wid * 2 + cc;
      int grow = n0 + c * 8 + rsub;
      gload16(&pBhi[(size_t)grow * ND + k0 + slot * 8], &Bs[0][c * 512]);
      if (PAIR)
        gload16(&pBlo[(size_t)grow * ND + k0 + slot * 8], &Bs[NBUF - 1][c * 512]);
    }
    __syncthreads();

#pragma unroll
    for (int kk = 0; kk < 64; kk += 32) {
      int sig = (kk >> 3) + (lane >> 4);
      bf16x8 ah[FM], al[FM], bh[2], bl[2];
#pragma unroll
      for (int fm = 0; fm < FM; ++fm) {
        int r = wm * (BMT / 2) + fm * 16 + (lane & 15);
        int off = r * 128 + ((sig ^ (r & 7)) << 4);
        ah[fm] = *(const bf16x8*)((const char*)&As[0][0] + off);
        if (PAIR) al[fm] = *(const bf16x8*)((const char*)&As[0][0] + ALO + off);
      }
#pragma unroll
      for (int fn = 0; fn < 2; ++fn) {
        int r = wn * 32 + fn * 16 + (lane & 15);
        int off = r * 128 + ((sig ^ (r & 7)) << 4);
        bh[fn] = *(const bf16x8*)((const char*)&Bs[0][0] + off);
        if (PAIR) bl[fn] = *(const bf16x8*)((const char*)&Bs[0][0] + 8192 + off);
      }
#pragma unroll
      for (int fm = 0; fm < FM; ++fm)
#pragma unroll
        for (int fn = 0; fn < 2; ++fn) {
          acc[fm][fn] = MFMA(ah[fm], bh[fn], acc[fm][fn]);
          if (PAIR) {
            acc[fm][fn] = MFMA(ah[fm], bl[fn], acc[fm][fn]);
            acc[fm][fn] = MFMA(al[fm], bh[fn], acc[fm][fn]);
          }
        }
    }
    __syncthreads();
  }

  const int jr = lane >> 4, cl = lane & 15;
#pragma unroll
  for (int fm = 0; fm < FM; ++fm)
#pragma unroll
    for (int fn = 0; fn < 2; ++fn) {
      f32x4 v = acc[fm][fn];
      int s = m0 + wm * (BMT / 2) + fm * 16 + jr * 4;
      int rh = n0 + wn * 32 + fn * 16 + cl;
      int orow = PAIR ? rh : (rh % NR) * NH + rh / NR;
      size_t o = ((size_t)b * NRH + orow) * NS + s;
      ushort4 h4;
      h4.x = rnbf(v[0]); h4.y = rnbf(v[1]);
      h4.z = rnbf(v[2]); h4.w = rnbf(v[3]);
      *(ushort4*)&C0[o] = h4;
      if (PAIR) {
        ushort4 l4;
        l4.x = rnbf(v[0] - bf2f(h4.x)); l4.y = rnbf(v[1] - bf2f(h4.y));
        l4.z = rnbf(v[2] - bf2f(h4.z)); l4.w = rnbf(v[3] - bf2f(h4.w));
        *(ushort4*)&C1[o] = l4;
      }
    }
}

// ---------------------------------------------------------------------------
// Split-K MFMA GEMM: P[z][m][n] = partial sum_k A[m][k]*B[n][k]
// BSRC=1: B fp32 [n][k] reg-staged to bf16 (BNT 64 or 128)
// BSRC=2: B fp32 [k][n] (K matrix) — in-kernel LDS transpose + hi/lo convert
// ---------------------------------------------------------------------------
template <bool SPLIT, int BSRC, int BNT>
__global__ __launch_bounds__(256) void mgemm(
    const unsigned short* __restrict__ Ahi, const unsigned short* __restrict__ Alo,
    const float* __restrict__ Bf,
    float* __restrict__ P, int kchunk, int lda, int ldb, int ldc,
    long sAb, long sBb, long sPz, int nbatch) {
  constexpr int NBUF = SPLIT ? 2 : 1;
  constexpr int NFN = BNT / 32;
  __shared__ unsigned short As[NBUF][64 * 64];
  __shared__ unsigned short Bs[NBUF][BNT * 64];
  __shared__ float tbuf[(BSRC == 2) ? 64 * 68 : 4];
  const int tid = threadIdx.x;
  const int lane = tid & 63;
  const int wid = tid >> 6;
  const int wm = wid >> 1, wn = wid & 1;
  const int m0 = blockIdx.y * 64, n0 = blockIdx.x * BNT;
  const int bz = blockIdx.z;
  const int b = bz % nbatch;
  const int kbeg = (bz / nbatch) * kchunk;
  const unsigned short* pAhi = Ahi + (size_t)b * sAb;
  const unsigned short* pAlo = SPLIT ? (Alo + (size_t)b * sAb) : nullptr;
  const float* pBf = Bf + (size_t)b * sBb;

  const int rsub = lane >> 3;
  const int slot = (lane & 7) ^ rsub;

  f32x4 acc[2][NFN];
#pragma unroll
  for (int i = 0; i < 2; ++i)
#pragma unroll
    for (int j = 0; j < NFN; ++j) acc[i][j] = (f32x4){0.f, 0.f, 0.f, 0.f};

  for (int k0 = kbeg; k0 < kbeg + kchunk; k0 += 64) {
    // ---- A: bf16 (pair iff SPLIT) via global_load_lds, pre-swizzled source
#pragma unroll
    for (int cc = 0; cc < 2; ++cc) {
      int c = wid * 2 + cc;
      int grow = m0 + c * 8 + rsub;
      gload16(&pAhi[(size_t)grow * lda + k0 + slot * 8], &As[0][c * 512]);
      if (SPLIT)
        gload16(&pAlo[(size_t)grow * lda + k0 + slot * 8], &As[NBUF - 1][c * 512]);
    }
    // ---- B
    if constexpr (BSRC == 1) {
      if constexpr (BNT == 128) {
        const int brow = tid >> 1;
        const int jbase = (tid & 1) * 4;
        const float* bsrc = pBf + (size_t)(n0 + brow) * ldb + k0 + jbase * 8;
        char* dbase = (char*)&Bs[0][0] + brow * 128;
#pragma unroll
        for (int jj = 0; jj < 4; ++jj) {
          float4 u = *(const float4*)(bsrc + jj * 8);
          float4 w = *(const float4*)(bsrc + jj * 8 + 4);
          uint4 h = pk_hi(u, w);
          char* dst = dbase + (((jbase + jj) ^ (brow & 7)) << 4);
          *(uint4*)dst = h;
          if (SPLIT) *(uint4*)(dst + 2 * 64 * BNT) = pk_lo(u, w, h);
        }
      } else {
        const int brow = tid >> 2;
        const int jbase = (tid & 3) * 2;
        const float* bsrc = pBf + (size_t)(n0 + brow) * ldb + k0 + jbase * 8;
        char* dbase = (char*)&Bs[0][0] + brow * 128;
#pragma unroll
        for (int jj = 0; jj < 2; ++jj) {
          float4 u = *(const float4*)(bsrc + jj * 8);
          float4 w = *(const float4*)(bsrc + jj * 8 + 4);
          uint4 h = pk_hi(u, w);
          char* dst = dbase + (((jbase + jj) ^ (brow & 7)) << 4);
          *(uint4*)dst = h;
          if (SPLIT) *(uint4*)(dst + 2 * 64 * BNT) = pk_lo(u, w, h);
        }
      }
      __syncthreads();
    } else {
      // BSRC == 2: fp32 [k][n] (K). Stage f32 tile then transpose+convert.
      {
        const int sr = tid >> 2;          // s-row 0..63
        const int eg = (tid & 3) * 16;    // e group (BNT=64)
        const float* ksrc = pBf + (size_t)(k0 + sr) * ldb + n0 + eg;
        float* td = &tbuf[sr * 68 + eg];
        *(float4*)(td + 0)  = *(const float4*)(ksrc + 0);
        *(float4*)(td + 4)  = *(const float4*)(ksrc + 4);
        *(float4*)(td + 8)  = *(const float4*)(ksrc + 8);
        *(float4*)(td + 12) = *(const float4*)(ksrc + 12);
      }
      __syncthreads();
      {
        const int e = tid & 63;
        const int sg = (tid >> 6) * 16;   // 16 s-values per thread
        float v[16];
#pragma unroll
        for (int i = 0; i < 16; ++i) v[i] = tbuf[(sg + i) * 68 + e];
        float4 u0 = {v[0], v[1], v[2], v[3]},   w0 = {v[4], v[5], v[6], v[7]};
        float4 u1 = {v[8], v[9], v[10], v[11]}, w1 = {v[12], v[13], v[14], v[15]};
        uint4 h0 = pk_hi(u0, w0), h1 = pk_hi(u1, w1);
        int j0 = sg >> 3;
        char* dbase = (char*)&Bs[0][0] + e * 128;
        *(uint4*)(dbase + (((j0 + 0) ^ (e & 7)) << 4)) = h0;
        *(uint4*)(dbase + (((j0 + 1) ^ (e & 7)) << 4)) = h1;
        if (SPLIT) {
          *(uint4*)(dbase + 2 * 64 * BNT + (((j0 + 0) ^ (e & 7)) << 4)) =
              pk_lo(u0, w0, h0);
          *(uint4*)(dbase + 2 * 64 * BNT + (((j0 + 1) ^ (e & 7)) << 4)) =
              pk_lo(u1, w1, h1);
        }
      }
      __syncthreads();
    }

    // ---- compute
#pragma unroll
    for (int kk = 0; kk < 64; kk += 32) {
      int sig = (kk >> 3) + (lane >> 4);
      bf16x8 ah[2], al[2], bh[NFN], bl[NFN];
#pragma unroll
      for (int fm = 0; fm < 2; ++fm) {
        int r = wm * 32 + fm * 16 + (lane & 15);
        int off = r * 128 + ((sig ^ (r & 7)) << 4);
        ah[fm] = *(const bf16x8*)((const char*)&As[0][0] + off);
        if (SPLIT) al[fm] = *(const bf16x8*)((const char*)&As[0][0] + 8192 + off);
      }
#pragma unroll
      for (int fn = 0; fn < NFN; ++fn) {
        int r = wn * (BNT / 2) + fn * 16 + (lane & 15);
        int off = r * 128 + ((sig ^ (r & 7)) << 4);
        bh[fn] = *(const bf16x8*)((const char*)&Bs[0][0] + off);
        if (SPLIT)
          bl[fn] = *(const bf16x8*)((const char*)&Bs[0][0] + 2 * 64 * BNT + off);
      }
#pragma unroll
      for (int fm = 0; fm < 2; ++fm)
#pragma unroll
        for (int fn = 0; fn < NFN; ++fn) {
          acc[fm][fn] = MFMA(ah[fm], bh[fn], acc[fm][fn]);
          if (SPLIT) {
            acc[fm][fn] = MFMA(ah[fm], bl[fn], acc[fm][fn]);
            acc[fm][fn] = MFMA(al[fm], bh[fn], acc[fm][fn]);
          }
        }
    }
    __syncthreads();
  }

  const int jr = lane >> 4, cl = lane & 15;
  float* pc = P + (size_t)bz * sPz;
#pragma unroll
  for (int fm = 0; fm < 2; ++fm)
#pragma unroll
    for (int fn = 0; fn < NFN; ++fn) {
      f32x4 v = acc[fm][fn];
      int gcol = n0 + wn * (BNT / 2) + fn * 16 + cl;
#pragma unroll
      for (int j = 0; j < 4; ++j) {
        int m = m0 + wm * 32 + fm * 16 + jr * 4 + j;
        pc[(size_t)m * ldc + gcol] = v[j];
      }
    }
}

// ---------------------------------------------------------------------------
// bias + LayerNorm -> out  (reads f32 lin)
// ---------------------------------------------------------------------------
__global__ __launch_bounds__(256) void bias_ln(const float* __restrict__ lin,
                                               const float* __restrict__ bias,
                                               const float* __restrict__ gamma,
                                               const float* __restrict__ beta,
                                               float* __restrict__ out) {
  int row = blockIdx.x;
  int t = threadIdx.x;
  float4 a = ((const float4*)(lin + (size_t)row * ND))[t];
  float4 bv = ((const float4*)bias)[t];
  a.x += bv.x; a.y += bv.y; a.z += bv.z; a.w += bv.w;

  float s = a.x + a.y + a.z + a.w;
  float ss = a.x * a.x + a.y * a.y + a.z * a.z + a.w * a.w;
#pragma unroll
  for (int off = 32; off > 0; off >>= 1) {
    s += __shfl_xor(s, off);
    ss += __shfl_xor(ss, off);
  }
  __shared__ float red[8];
  int wave = t >> 6, lane = t & 63;
  if (lane == 0) { red[wave] = s; red[4 + wave] = ss; }
  __syncthreads();
  s = red[0] + red[1] + red[2] + red[3];
  ss = red[4] + red[5] + red[6] + red[7];
  float mu = s * (1.0f / ND);
  float var = ss * (1.0f / ND) - mu * mu;
  float inv = rsqrtf(var + 1e-6f);
  float4 g = ((const float4*)gamma)[t];
  float4 be = ((const float4*)beta)[t];
  float4 o;
  o.x = (a.x - mu) * inv * g.x + be.x;
  o.y = (a.y - mu) * inv * g.y + be.y;
  o.z = (a.z - mu) * inv * g.z + be.z;
  o.w = (a.w - mu) * inv * g.w + be.w;
  ((float4*)(out + (size_t)row * ND))[t] = o;
}

// ---------------------------------------------------------------------------
// sm_k: one block per (b,h,r). Sums G2's split partials inline.
// s2[d] = T1 . WK[h*64+d] via one wave per d-group (coalesced row-dot).
// softmax over d=64; A2[bhr][e] = sum_d attn[d]*WV[h64+d][e] -> bf16.
// ---------------------------------------------------------------------------
__global__ __launch_bounds__(256) void sm_k(const float* __restrict__ P,
                                            int nsplit,
                                            const float* __restrict__ WK,
                                            const float* __restrict__ WV,
                                            unsigned short* __restrict__ A2) {
  int x = blockIdx.x;
  int xcd = x & 7, within = x >> 3;
  int h = xcd + 8 * (within & 1);
  int rb = within >> 1;
  int r = rb >> 2, b = rb & 3;
  int idx = (b * NH + h) * NR + r;
  int rh = h * NR + r;

  const int t = threadIdx.x;
  const int lane = t & 63, wv = t >> 6;
  __shared__ float t1s[ND];
  __shared__ float s2s[NDH];
  __shared__ float attns[NDH];

  {
    const size_t sstride = (size_t)NB * NRH * ND;
    const float* base = P + ((size_t)b * NRH + rh) * ND;
    float4 a = ((const float4*)base)[t];
    for (int s = 1; s < nsplit; ++s) {
      float4 v = ((const float4*)(base + (size_t)s * sstride))[t];
      a.x += v.x; a.y += v.y; a.z += v.z; a.w += v.w;
    }
    ((float4*)t1s)[t] = a;
  }
  __syncthreads();

  // s2: wave wv computes d = wv*16 + j (coalesced row-dot + shfl reduce)
  for (int j = 0; j < 16; ++j) {
    int d = wv * 16 + j;
    const float* row = WK + (size_t)(h * NDH + d) * ND;
    float acc = 0.f;
#pragma unroll
    for (int i = 0; i < 16; ++i) acc += row[lane + i * 64] * t1s[lane + i * 64];
#pragma unroll
    for (int off = 32; off > 0; off >>= 1) acc += __shfl_xor(acc, off);
    if (lane == 0) s2s[d] = acc;
  }
  __syncthreads();

  if (t < NDH) {
    float s2 = s2s[t];
    float m = s2;
#pragma unroll
    for (int off = 32; off > 0; off >>= 1) m = fmaxf(m, __shfl_xor(m, off));
    float e = __expf(s2 - m);
    float sum = e;
#pragma unroll
    for (int off = 32; off > 0; off >>= 1) sum += __shfl_xor(sum, off);
    attns[t] = e / sum;
  }
  __syncthreads();

  {
    int e0 = t * 4;
    const float* wvp = WV + (size_t)h * NDH * ND + e0;
    float a0 = 0.f, a1 = 0.f, a2 = 0.f, a3 = 0.f;
#pragma unroll 4
    for (int dd = 0; dd < NDH; ++dd) {
      float4 wvv = *(const float4*)&wvp[(size_t)dd * ND];
      float a = attns[dd];
      a0 += a * wvv.x; a1 += a * wvv.y; a2 += a * wvv.z; a3 += a * wvv.w;
    }
    ushort4 o;
    o.x = rnbf(a0); o.y = rnbf(a1); o.z = rnbf(a2); o.w = rnbf(a3);
    *(ushort4*)&A2[(size_t)idx * ND + e0] = o;
  }
}

// ---------------------------------------------------------------------------
extern "C" void kernel_launch(void* const* d_in, const int* in_sizes, int n_in,
                              void* d_out, int out_size, void* d_ws, size_t ws_size,
                              hipStream_t stream) {
  const float* Q = (const float*)d_in[0];
  const float* K = (const float*)d_in[1];
  const float* V = (const float*)d_in[2];
  const float* U = (const float*)d_in[3];
  const float* WQ = (const float*)d_in[4];
  const float* WK = (const float*)d_in[5];
  const float* WV = (const float*)d_in[6];
  const float* WL = (const float*)d_in[7];
  const float* bl = (const float*)d_in[8];
  const float* ga = (const float*)d_in[9];
  const float* be = (const float*)d_in[10];
  float* out = (float*)d_out;
  char* w = (char*)d_ws;

  // layout (bytes):
  //  [0)        wq hi/lo (3.1M)  -> A2b reuse after G1t
  //  [3.1M)     s1hi (3.1M)
  //  [6.3M)     s1lo (3.1M)
  //  [9.4M)     ctxb (3.1M)
  //  [12.6M)    lin  (6.3M)
  //  [18.9M...) P split partials (G2)
  unsigned short* wqhi = (unsigned short*)w;
  unsigned short* wqlo = (unsigned short*)(w + 1572864);
  unsigned short* A2b = wqhi;
  unsigned short* s1hi = (unsigned short*)(w + 3145728);
  unsigned short* s1lo = (unsigned short*)(w + 6291456);
  unsigned short* ctxb = (unsigned short*)(w + 9437184);
  float* lin = (float*)(w + 12582912);
  float* P = (float*)(w + 18874368);

  size_t avail = ws_size > 18874368 ? ws_size - 18874368 : 0;
  auto pick = [&](size_t bytesPerSplit, int maxs) {
    int s = 1;
    while (s * 2 <= maxs && bytesPerSplit * (size_t)(s * 2) <= avail) s *= 2;
    return s;
  };
  int sG2 = pick(3145728, 4);   // P: [sG2*4][192][1024] f32

  build_wqeff<<<NB * NH * NR, 256, 0, stream>>>(U, WQ, wqhi, wqlo);

  // G1t: s1^T orientation, BM=32, 768 blocks. out s1[rh][s] hi/lo directly.
  gemm_tn<true, 32><<<dim3(64, 3, NB), 256, 0, stream>>>(
      Q, wqhi, wqlo, s1hi, s1lo);

  // G2: T1[rh][e] = s1[rh] . K[.][e]  M=192 N=1024 K=2048 (pair, split-K,
  //     fused in-kernel K transpose+convert; BNT=64)
  mgemm<true, 2, 64><<<dim3(16, 3, NB * sG2), 256, 0, stream>>>(
      s1hi, s1lo, K, P, 2048 / sG2,
      2048, 1024, 1024, 192L * 2048, 2048L * 1024, 192L * 1024, NB);

  // s2 -> softmax -> A2, summing G2 partials inline; WK read directly
  sm_k<<<NB * NH * NR, 256, 0, stream>>>(P, sG2, WK, WV, A2b);

  // G3t: ctx^T orientation, BM=32, 768 blocks; remapped rows written direct.
  gemm_tn<false, 32><<<dim3(64, 3, NB), 256, 0, stream>>>(
      V, A2b, nullptr, ctxb, nullptr);

  // G4: lin = ctx_flat @ WL^T  M=1536 N=1024 K=1024, no split (384 blocks)
  mgemm<false, 1, 64><<<dim3(16, 24, 1), 256, 0, stream>>>(
      ctxb, nullptr, WL, lin, 1024,
      1024, 1024, 1024, 0, 0, 0, 1);

  // bias + LayerNorm -> out
  bias_ln<<<1536, 256, 0, stream>>>(lin, bl, ga, be, out);
}

// Round 9
// 107.760 us; speedup vs baseline: 3.2732x; 1.0009x over previous
//
#include <hip/hip_runtime.h>

#define NB 4
#define NS 2048
#define ND 1024
#define NH 16
#define NDH 64
#define NR 12
#define NRH 192

typedef __attribute__((ext_vector_type(8))) short bf16x8;
typedef __attribute__((ext_vector_type(4))) float f32x4;

__device__ __forceinline__ unsigned short rnbf(float f) {
  unsigned u = __float_as_uint(f);
  u += 0x7fffu + ((u >> 16) & 1u);
  return (unsigned short)(u >> 16);
}
__device__ __forceinline__ float bf2f(unsigned short h) {
  return __uint_as_float(((unsigned)h) << 16);
}

// v_cvt_pk_bf16_f32: dst[15:0]=bf16(a) RNE, dst[31:16]=bf16(b)
__device__ __forceinline__ unsigned cvtpk(float a, float b) {
  unsigned r;
  asm("v_cvt_pk_bf16_f32 %0, %1, %2" : "=v"(r) : "v"(a), "v"(b));
  return r;
}
__device__ __forceinline__ uint4 pk_hi(float4 u, float4 w) {
  uint4 h;
  h.x = cvtpk(u.x, u.y); h.y = cvtpk(u.z, u.w);
  h.z = cvtpk(w.x, w.y); h.w = cvtpk(w.z, w.w);
  return h;
}
__device__ __forceinline__ unsigned lo2(float a, float b, unsigned hh) {
  float ah = __uint_as_float(hh << 16);
  float bh = __uint_as_float(hh & 0xffff0000u);
  return cvtpk(a - ah, b - bh);
}
__device__ __forceinline__ uint4 pk_lo(float4 u, float4 w, uint4 h) {
  uint4 l;
  l.x = lo2(u.x, u.y, h.x); l.y = lo2(u.z, u.w, h.y);
  l.z = lo2(w.x, w.y, h.z); l.w = lo2(w.z, w.w, h.w);
  return l;
}

__device__ __forceinline__ void gload16(const void* g, void* l) {
  __builtin_amdgcn_global_load_lds(
      (const __attribute__((address_space(1))) unsigned int*)g,
      (__attribute__((address_space(3))) unsigned int*)l, 16, 0, 0);
}

#define MFMA(a, b, c) __builtin_amdgcn_mfma_f32_16x16x32_bf16(a, b, c, 0, 0, 0)

// ---------------------------------------------------------------------------
// Wq_eff[b,h,r,e] = sum_d U[b,h,r,d] * W_Q[h*64+d, e]  -> hi/lo bf16
// ---------------------------------------------------------------------------
__global__ __launch_bounds__(256) void build_wqeff(const float* __restrict__ U,
                                                   const float* __restrict__ WQ,
                                                   unsigned short* __restrict__ wqhi,
                                                   unsigned short* __restrict__ wqlo) {
  int idx = blockIdx.x;
  int hr = idx % (NH * NR);
  int h = hr / NR;
  __shared__ float u[NDH];
  int t = threadIdx.x;
  if (t < NDH) u[t] = U[(size_t)idx * NDH + t];
  __syncthreads();
  int e0 = t * 4;
  float a0 = 0.f, a1 = 0.f, a2 = 0.f, a3 = 0.f;
  const float* wbase = WQ + (size_t)h * NDH * ND + e0;
#pragma unroll 4
  for (int d = 0; d < NDH; ++d) {
    float uv = u[d];
    const float* wr = wbase + (size_t)d * ND;
    a0 += uv * wr[0]; a1 += uv * wr[1]; a2 += uv * wr[2]; a3 += uv * wr[3];
  }
  ushort4 h4, l4;
  h4.x = rnbf(a0); l4.x = rnbf(a0 - bf2f(h4.x));
  h4.y = rnbf(a1); l4.y = rnbf(a1 - bf2f(h4.y));
  h4.z = rnbf(a2); l4.z = rnbf(a2 - bf2f(h4.z));
  h4.w = rnbf(a3); l4.w = rnbf(a3 - bf2f(h4.w));
  *(ushort4*)&wqhi[(size_t)idx * ND + e0] = h4;
  *(ushort4*)&wqlo[(size_t)idx * ND + e0] = l4;
}

// ---------------------------------------------------------------------------
// gemm_tn: C^T-oriented GEMM, 2-phase pipelined (dbuf LDS, 1 barrier/iter),
// XCD-aware decode (trio of n-blocks sharing an m0 co-located per XCD).
//   out[n][m] = sum_k A[m][k]*B[n][k]; M=2048(s), N=192(rh), K=1024; BM=32.
// A = fp32 reg-staged to bf16 (pair iff PAIR); B = bf16 via global_load_lds.
// grid: 768 blocks (1D).
// ---------------------------------------------------------------------------
template <bool PAIR>
__global__ __launch_bounds__(256) void gemm_tn(
    const float* __restrict__ Af,
    const unsigned short* __restrict__ Bhi, const unsigned short* __restrict__ Blo,
    unsigned short* __restrict__ C0, unsigned short* __restrict__ C1) {
  constexpr int NBUF = PAIR ? 2 : 1;
  __shared__ unsigned short As[2][NBUF][32 * 64];
  __shared__ unsigned short Bs[2][NBUF][64 * 64];
  const int tid = threadIdx.x;
  const int lane = tid & 63;
  const int wid = tid >> 6;
  const int wm = wid >> 1, wn = wid & 1;

  // XCD decode: lin = 0..767; xcd gets contiguous slots; within a slot run,
  // the 3 n-blocks of one (b, m0) are adjacent -> Q/V tile L2-resident.
  int lin = blockIdx.x;
  int xcd = lin & 7, slot = lin >> 3;   // slot 0..95
  int b = slot / 24;
  int rem = slot % 24;
  int m0 = ((rem / 3) * 8 + xcd) * 32;  // 0..2016
  int n0 = (rem % 3) * 64;

  const float* pA = Af + (size_t)b * NS * ND;
  const unsigned short* pBhi = Bhi + (size_t)b * NRH * ND;
  const unsigned short* pBlo = PAIR ? Blo + (size_t)b * NRH * ND : nullptr;

  const int rsub = lane >> 3;
  const int slotg = (lane & 7) ^ rsub;
  const int arow = tid >> 3;  // 0..31
  const int jg = tid & 7;     // slot 0..7

  f32x4 acc[2];
  acc[0] = (f32x4){0.f, 0.f, 0.f, 0.f};
  acc[1] = (f32x4){0.f, 0.f, 0.f, 0.f};

  // ---- prologue: stage tile 0 into buffer 0
  {
    const float* asrc = pA + (size_t)(m0 + arow) * ND + jg * 8;
    float4 au = *(const float4*)(asrc);
    float4 av = *(const float4*)(asrc + 4);
#pragma unroll
    for (int cc = 0; cc < 2; ++cc) {
      int c = wid * 2 + cc;
      int grow = n0 + c * 8 + rsub;
      gload16(&pBhi[(size_t)grow * ND + slotg * 8], &Bs[0][0][c * 512]);
      if (PAIR)
        gload16(&pBlo[(size_t)grow * ND + slotg * 8], &Bs[0][NBUF - 1][c * 512]);
    }
    uint4 h = pk_hi(au, av);
    char* dst = (char*)&As[0][0][0] + arow * 128 + ((jg ^ (arow & 7)) << 4);
    *(uint4*)dst = h;
    if (PAIR) *(uint4*)(dst + 4096) = pk_lo(au, av, h);
  }
  __syncthreads();

  int p = 0;
  for (int k0 = 0; k0 < ND; k0 += 64, p ^= 1) {
    const bool pre = (k0 + 64) < ND;
    float4 aun = {}, avn = {};
    if (pre) {
      // issue next-tile loads: in flight during this tile's MFMA
      const float* asrc = pA + (size_t)(m0 + arow) * ND + k0 + 64 + jg * 8;
      aun = *(const float4*)(asrc);
      avn = *(const float4*)(asrc + 4);
#pragma unroll
      for (int cc = 0; cc < 2; ++cc) {
        int c = wid * 2 + cc;
        int grow = n0 + c * 8 + rsub;
        gload16(&pBhi[(size_t)grow * ND + k0 + 64 + slotg * 8],
                &Bs[p ^ 1][0][c * 512]);
        if (PAIR)
          gload16(&pBlo[(size_t)grow * ND + k0 + 64 + slotg * 8],
                  &Bs[p ^ 1][NBUF - 1][c * 512]);
      }
    }
    // compute on buffer p
#pragma unroll
    for (int kk = 0; kk < 64; kk += 32) {
      int sig = (kk >> 3) + (lane >> 4);
      bf16x8 ah, al, bh[2], bl[2];
      {
        int r = wm * 16 + (lane & 15);
        int off = r * 128 + ((sig ^ (r & 7)) << 4);
        ah = *(const bf16x8*)((const char*)&As[p][0][0] + off);
        if (PAIR) al = *(const bf16x8*)((const char*)&As[p][NBUF - 1][0] + off);
      }
#pragma unroll
      for (int fn = 0; fn < 2; ++fn) {
        int r = wn * 32 + fn * 16 + (lane & 15);
        int off = r * 128 + ((sig ^ (r & 7)) << 4);
        bh[fn] = *(const bf16x8*)((const char*)&Bs[p][0][0] + off);
        if (PAIR)
          bl[fn] = *(const bf16x8*)((const char*)&Bs[p][NBUF - 1][0] + off);
      }
#pragma unroll
      for (int fn = 0; fn < 2; ++fn) {
        acc[fn] = MFMA(ah, bh[fn], acc[fn]);
        if (PAIR) {
          acc[fn] = MFMA(ah, bl[fn], acc[fn]);
          acc[fn] = MFMA(al, bh[fn], acc[fn]);
        }
      }
    }
    if (pre) {
      // convert+write next A (vmcnt wait lands here, after MFMA)
      uint4 h = pk_hi(aun, avn);
      char* dst =
          (char*)&As[p ^ 1][0][0] + arow * 128 + ((jg ^ (arow & 7)) << 4);
      *(uint4*)dst = h;
      if (PAIR) *(uint4*)(dst + 4096) = pk_lo(aun, avn, h);
    }
    __syncthreads();  // next buffers ready; all reads of buf p done
  }

  // ---- transposed epilogue
  const int jr = lane >> 4, cl = lane & 15;
#pragma unroll
  for (int fn = 0; fn < 2; ++fn) {
    f32x4 v = acc[fn];
    int s = m0 + wm * 16 + jr * 4;
    int rh = n0 + wn * 32 + fn * 16 + cl;
    int orow = PAIR ? rh : (rh % NR) * NH + rh / NR;
    size_t o = ((size_t)b * NRH + orow) * NS + s;
    ushort4 h4;
    h4.x = rnbf(v[0]); h4.y = rnbf(v[1]);
    h4.z = rnbf(v[2]); h4.w = rnbf(v[3]);
    *(ushort4*)&C0[o] = h4;
    if (PAIR) {
      ushort4 l4;
      l4.x = rnbf(v[0] - bf2f(h4.x)); l4.y = rnbf(v[1] - bf2f(h4.y));
      l4.z = rnbf(v[2] - bf2f(h4.z)); l4.w = rnbf(v[3] - bf2f(h4.w));
      *(ushort4*)&C1[o] = l4;
    }
  }
}

// ---------------------------------------------------------------------------
// G2: T1 partials. P[z][m][e] = sum_{s in chunk z} s1[m][s]*K[s][e]
// hi/lo pair; in-kernel K transpose+convert; K fp32 regs prefetched across
// the MFMA phase (heavy HBM load hidden). XCD decode co-locates all 48
// blocks of one (b,split) -> K-chunk (2MB) and s1 panel L2-resident.
// grid: 48*NB*sG2 blocks (1D).
// ---------------------------------------------------------------------------
__global__ __launch_bounds__(256) void gemm_g2(
    const unsigned short* __restrict__ Ahi, const unsigned short* __restrict__ Alo,
    const float* __restrict__ Kf, float* __restrict__ P,
    int kchunk, int nz) {
  __shared__ unsigned short As[2][64 * 64];  // hi, lo (single-buffered)
  __shared__ unsigned short Bs[2][64 * 64];  // hi, lo
  __shared__ float tbuf[64 * 68];
  const int tid = threadIdx.x;
  const int lane = tid & 63;
  const int wid = tid >> 6;
  const int wm = wid >> 1, wn = wid & 1;

  int lin = blockIdx.x;
  int bz, m_idx, n_idx;
  if (nz == 16) {
    int xcd = lin & 7, slot = lin >> 3;  // slot 0..95
    bz = xcd + 8 * (slot / 48);
    int rem = slot % 48;
    m_idx = rem / 16; n_idx = rem % 16;
  } else {
    bz = lin / 48;
    int rem = lin % 48;
    m_idx = rem / 16; n_idx = rem % 16;
  }
  const int m0 = m_idx * 64, n0 = n_idx * 64;
  const int b = bz % NB;
  const int kbeg = (bz / NB) * kchunk;
  const unsigned short* pAhi = Ahi + (size_t)b * NRH * NS;
  const unsigned short* pAlo = Alo + (size_t)b * NRH * NS;
  const float* pK = Kf + (size_t)b * NS * ND;

  const int rsub = lane >> 3;
  const int slotg = (lane & 7) ^ rsub;
  const int sr = tid >> 2;          // 0..63 (K stage row)
  const int eg = (tid & 3) * 16;    // e group

  f32x4 acc[2][2];
#pragma unroll
  for (int i = 0; i < 2; ++i)
#pragma unroll
    for (int j = 0; j < 2; ++j) acc[i][j] = (f32x4){0.f, 0.f, 0.f, 0.f};

  // prologue: K regs for step 0
  float4 kr0, kr1, kr2, kr3;
  {
    const float* ksrc = pK + (size_t)(kbeg + sr) * ND + n0 + eg;
    kr0 = *(const float4*)(ksrc + 0);
    kr1 = *(const float4*)(ksrc + 4);
    kr2 = *(const float4*)(ksrc + 8);
    kr3 = *(const float4*)(ksrc + 12);
  }

  for (int k0 = kbeg; k0 < kbeg + kchunk; k0 += 64) {
    // A gload (overlaps tbuf write below)
#pragma unroll
    for (int cc = 0; cc < 2; ++cc) {
      int c = wid * 2 + cc;
      int grow = m0 + c * 8 + rsub;
      gload16(&pAhi[(size_t)grow * NS + k0 + slotg * 8], &As[0][c * 512]);
      gload16(&pAlo[(size_t)grow * NS + k0 + slotg * 8], &As[1][c * 512]);
    }
    // K regs -> tbuf (vmcnt wait here — hidden for steps > 0)
    {
      float* td = &tbuf[sr * 68 + eg];
      *(float4*)(td + 0) = kr0;
      *(float4*)(td + 4) = kr1;
      *(float4*)(td + 8) = kr2;
      *(float4*)(td + 12) = kr3;
    }
    __syncthreads();  // tbuf ready; drains A gloads
    // transpose column read + cvt + swizzled Bs write
    {
      const int e = tid & 63;
      const int sg = (tid >> 6) * 16;
      float v[16];
#pragma unroll
      for (int i = 0; i < 16; ++i) v[i] = tbuf[(sg + i) * 68 + e];
      float4 u0 = {v[0], v[1], v[2], v[3]},   w0 = {v[4], v[5], v[6], v[7]};
      float4 u1 = {v[8], v[9], v[10], v[11]}, w1 = {v[12], v[13], v[14], v[15]};
      uint4 h0 = pk_hi(u0, w0), h1 = pk_hi(u1, w1);
      int j0 = sg >> 3;
      char* dbase = (char*)&Bs[0][0] + e * 128;
      *(uint4*)(dbase + (((j0 + 0) ^ (e & 7)) << 4)) = h0;
      *(uint4*)(dbase + (((j0 + 1) ^ (e & 7)) << 4)) = h1;
      char* dlo = (char*)&Bs[1][0] + e * 128;
      *(uint4*)(dlo + (((j0 + 0) ^ (e & 7)) << 4)) = pk_lo(u0, w0, h0);
      *(uint4*)(dlo + (((j0 + 1) ^ (e & 7)) << 4)) = pk_lo(u1, w1, h1);
    }
    __syncthreads();  // Bs, As ready
    // prefetch next step's K regs: in flight during MFMA
    if (k0 + 64 < kbeg + kchunk) {
      const float* ksrc = pK + (size_t)(k0 + 64 + sr) * ND + n0 + eg;
      kr0 = *(const float4*)(ksrc + 0);
      kr1 = *(const float4*)(ksrc + 4);
      kr2 = *(const float4*)(ksrc + 8);
      kr3 = *(const float4*)(ksrc + 12);
    }
    // MFMA
#pragma unroll
    for (int kk = 0; kk < 64; kk += 32) {
      int sig = (kk >> 3) + (lane >> 4);
      bf16x8 ah[2], al[2], bh[2], bl[2];
#pragma unroll
      for (int fm = 0; fm < 2; ++fm) {
        int r = wm * 32 + fm * 16 + (lane & 15);
        int off = r * 128 + ((sig ^ (r & 7)) << 4);
        ah[fm] = *(const bf16x8*)((const char*)&As[0][0] + off);
        al[fm] = *(const bf16x8*)((const char*)&As[1][0] + off);
      }
#pragma unroll
      for (int fn = 0; fn < 2; ++fn) {
        int r = wn * 32 + fn * 16 + (lane & 15);
        int off = r * 128 + ((sig ^ (r & 7)) << 4);
        bh[fn] = *(const bf16x8*)((const char*)&Bs[0][0] + off);
        bl[fn] = *(const bf16x8*)((const char*)&Bs[1][0] + off);
      }
#pragma unroll
      for (int fm = 0; fm < 2; ++fm)
#pragma unroll
        for (int fn = 0; fn < 2; ++fn) {
          acc[fm][fn] = MFMA(ah[fm], bh[fn], acc[fm][fn]);
          acc[fm][fn] = MFMA(ah[fm], bl[fn], acc[fm][fn]);
          acc[fm][fn] = MFMA(al[fm], bh[fn], acc[fm][fn]);
        }
    }
    __syncthreads();  // protect As/tbuf overwrite next step
  }

  const int jr = lane >> 4, cl = lane & 15;
  float* pc = P + (size_t)bz * NRH * ND;
#pragma unroll
  for (int fm = 0; fm < 2; ++fm)
#pragma unroll
    for (int fn = 0; fn < 2; ++fn) {
      f32x4 v = acc[fm][fn];
      int gcol = n0 + wn * 32 + fn * 16 + cl;
#pragma unroll
      for (int j = 0; j < 4; ++j) {
        int m = m0 + wm * 32 + fm * 16 + jr * 4 + j;
        pc[(size_t)m * ND + gcol] = v[j];
      }
    }
}

// ---------------------------------------------------------------------------
// G4: lin[m][n] = sum_k ctx[m][k]*WL[n][k]; M=1536 N=1024 K=1024.
// 2-phase pipelined; A=ctx bf16 gload dbuf, B=WL fp32 reg-staged dbuf.
// grid: 384 blocks (24 m x 16 n).
// ---------------------------------------------------------------------------
__global__ __launch_bounds__(256) void gemm_g4(
    const unsigned short* __restrict__ A, const float* __restrict__ Bf,
    float* __restrict__ lin) {
  __shared__ unsigned short As[2][64 * 64];
  __shared__ unsigned short Bs[2][64 * 64];
  const int tid = threadIdx.x;
  const int lane = tid & 63;
  const int wid = tid >> 6;
  const int wm = wid >> 1, wn = wid & 1;
  const int m0 = (blockIdx.x >> 4) * 64, n0 = (blockIdx.x & 15) * 64;
  const int rsub = lane >> 3;
  const int slotg = (lane & 7) ^ rsub;
  const int brow = tid >> 2;
  const int jbase = (tid & 3) * 2;

  f32x4 acc[2][2];
#pragma unroll
  for (int i = 0; i < 2; ++i)
#pragma unroll
    for (int j = 0; j < 2; ++j) acc[i][j] = (f32x4){0.f, 0.f, 0.f, 0.f};

  // prologue
#pragma unroll
  for (int cc = 0; cc < 2; ++cc) {
    int c = wid * 2 + cc;
    gload16(&A[(size_t)(m0 + c * 8 + rsub) * ND + slotg * 8], &As[0][c * 512]);
  }
  {
    const float* bsrc = Bf + (size_t)(n0 + brow) * ND + jbase * 8;
    float4 u0 = *(const float4*)(bsrc + 0), v0 = *(const float4*)(bsrc + 4);
    float4 u1 = *(const float4*)(bsrc + 8), v1 = *(const float4*)(bsrc + 12);
    char* dbase = (char*)&Bs[0][0] + brow * 128;
    *(uint4*)(dbase + (((jbase + 0) ^ (brow & 7)) << 4)) = pk_hi(u0, v0);
    *(uint4*)(dbase + (((jbase + 1) ^ (brow & 7)) << 4)) = pk_hi(u1, v1);
  }
  __syncthreads();

  int p = 0;
  for (int k0 = 0; k0 < ND; k0 += 64, p ^= 1) {
    const bool pre = (k0 + 64) < ND;
    float4 pu0 = {}, pv0 = {}, pu1 = {}, pv1 = {};
    if (pre) {
#pragma unroll
      for (int cc = 0; cc < 2; ++cc) {
        int c = wid * 2 + cc;
        gload16(&A[(size_t)(m0 + c * 8 + rsub) * ND + k0 + 64 + slotg * 8],
                &As[p ^ 1][c * 512]);
      }
      const float* bsrc = Bf + (size_t)(n0 + brow) * ND + k0 + 64 + jbase * 8;
      pu0 = *(const float4*)(bsrc + 0); pv0 = *(const float4*)(bsrc + 4);
      pu1 = *(const float4*)(bsrc + 8); pv1 = *(const float4*)(bsrc + 12);
    }
#pragma unroll
    for (int kk = 0; kk < 64; kk += 32) {
      int sig = (kk >> 3) + (lane >> 4);
      bf16x8 ah[2], bh[2];
#pragma unroll
      for (int fm = 0; fm < 2; ++fm) {
        int r = wm * 32 + fm * 16 + (lane & 15);
        int off = r * 128 + ((sig ^ (r & 7)) << 4);
        ah[fm] = *(const bf16x8*)((const char*)&As[p][0] + off);
      }
#pragma unroll
      for (int fn = 0; fn < 2; ++fn) {
        int r = wn * 32 + fn * 16 + (lane & 15);
        int off = r * 128 + ((sig ^ (r & 7)) << 4);
        bh[fn] = *(const bf16x8*)((const char*)&Bs[p][0] + off);
      }
#pragma unroll
      for (int fm = 0; fm < 2; ++fm)
#pragma unroll
        for (int fn = 0; fn < 2; ++fn)
          acc[fm][fn] = MFMA(ah[fm], bh[fn], acc[fm][fn]);
    }
    if (pre) {
      char* dbase = (char*)&Bs[p ^ 1][0] + brow * 128;
      *(uint4*)(dbase + (((jbase + 0) ^ (brow & 7)) << 4)) = pk_hi(pu0, pv0);
      *(uint4*)(dbase + (((jbase + 1) ^ (brow & 7)) << 4)) = pk_hi(pu1, pv1);
    }
    __syncthreads();
  }

  const int jr = lane >> 4, cl = lane & 15;
#pragma unroll
  for (int fm = 0; fm < 2; ++fm)
#pragma unroll
    for (int fn = 0; fn < 2; ++fn) {
      f32x4 v = acc[fm][fn];
      int gcol = n0 + wn * 32 + fn * 16 + cl;
#pragma unroll
      for (int j = 0; j < 4; ++j) {
        int m = m0 + wm * 32 + fm * 16 + jr * 4 + j;
        lin[(size_t)m * ND + gcol] = v[j];
      }
    }
}

// ---------------------------------------------------------------------------
// bias + LayerNorm -> out
// ---------------------------------------------------------------------------
__global__ __launch_bounds__(256) void bias_ln(const float* __restrict__ lin,
                                               const float* __restrict__ bias,
                                               const float* __restrict__ gamma,
                                               const float* __restrict__ beta,
                                               float* __restrict__ out) {
  int row = blockIdx.x;
  int t = threadIdx.x;
  float4 a = ((const float4*)(lin + (size_t)row * ND))[t];
  float4 bv = ((const float4*)bias)[t];
  a.x += bv.x; a.y += bv.y; a.z += bv.z; a.w += bv.w;

  float s = a.x + a.y + a.z + a.w;
  float ss = a.x * a.x + a.y * a.y + a.z * a.z + a.w * a.w;
#pragma unroll
  for (int off = 32; off > 0; off >>= 1) {
    s += __shfl_xor(s, off);
    ss += __shfl_xor(ss, off);
  }
  __shared__ float red[8];
  int wave = t >> 6, lane = t & 63;
  if (lane == 0) { red[wave] = s; red[4 + wave] = ss; }
  __syncthreads();
  s = red[0] + red[1] + red[2] + red[3];
  ss = red[4] + red[5] + red[6] + red[7];
  float mu = s * (1.0f / ND);
  float var = ss * (1.0f / ND) - mu * mu;
  float inv = rsqrtf(var + 1e-6f);
  float4 g = ((const float4*)gamma)[t];
  float4 be = ((const float4*)beta)[t];
  float4 o;
  o.x = (a.x - mu) * inv * g.x + be.x;
  o.y = (a.y - mu) * inv * g.y + be.y;
  o.z = (a.z - mu) * inv * g.z + be.z;
  o.w = (a.w - mu) * inv * g.w + be.w;
  ((float4*)(out + (size_t)row * ND))[t] = o;
}

// ---------------------------------------------------------------------------
// sm_k: one block per (b,h,r). Sums G2's split partials inline.
// ---------------------------------------------------------------------------
__global__ __launch_bounds__(256) void sm_k(const float* __restrict__ P,
                                            int nsplit,
                                            const float* __restrict__ WK,
                                            const float* __restrict__ WV,
                                            unsigned short* __restrict__ A2) {
  int x = blockIdx.x;
  int xcd = x & 7, within = x >> 3;
  int h = xcd + 8 * (within & 1);
  int rb = within >> 1;
  int r = rb >> 2, b = rb & 3;
  int idx = (b * NH + h) * NR + r;
  int rh = h * NR + r;

  const int t = threadIdx.x;
  const int lane = t & 63, wv = t >> 6;
  __shared__ float t1s[ND];
  __shared__ float s2s[NDH];
  __shared__ float attns[NDH];

  {
    const size_t sstride = (size_t)NB * NRH * ND;
    const float* base = P + ((size_t)b * NRH + rh) * ND;
    float4 a = ((const float4*)base)[t];
    for (int s = 1; s < nsplit; ++s) {
      float4 v = ((const float4*)(base + (size_t)s * sstride))[t];
      a.x += v.x; a.y += v.y; a.z += v.z; a.w += v.w;
    }
    ((float4*)t1s)[t] = a;
  }
  __syncthreads();

  for (int j = 0; j < 16; ++j) {
    int d = wv * 16 + j;
    const float* row = WK + (size_t)(h * NDH + d) * ND;
    float acc = 0.f;
#pragma unroll
    for (int i = 0; i < 16; ++i) acc += row[lane + i * 64] * t1s[lane + i * 64];
#pragma unroll
    for (int off = 32; off > 0; off >>= 1) acc += __shfl_xor(acc, off);
    if (lane == 0) s2s[d] = acc;
  }
  __syncthreads();

  if (t < NDH) {
    float s2 = s2s[t];
    float m = s2;
#pragma unroll
    for (int off = 32; off > 0; off >>= 1) m = fmaxf(m, __shfl_xor(m, off));
    float e = __expf(s2 - m);
    float sum = e;
#pragma unroll
    for (int off = 32; off > 0; off >>= 1) sum += __shfl_xor(sum, off);
    attns[t] = e / sum;
  }
  __syncthreads();

  {
    int e0 = t * 4;
    const float* wvp = WV + (size_t)h * NDH * ND + e0;
    float a0 = 0.f, a1 = 0.f, a2 = 0.f, a3 = 0.f;
#pragma unroll 4
    for (int dd = 0; dd < NDH; ++dd) {
      float4 wvv = *(const float4*)&wvp[(size_t)dd * ND];
      float a = attns[dd];
      a0 += a * wvv.x; a1 += a * wvv.y; a2 += a * wvv.z; a3 += a * wvv.w;
    }
    ushort4 o;
    o.x = rnbf(a0); o.y = rnbf(a1); o.z = rnbf(a2); o.w = rnbf(a3);
    *(ushort4*)&A2[(size_t)idx * ND + e0] = o;
  }
}

// ---------------------------------------------------------------------------
extern "C" void kernel_launch(void* const* d_in, const int* in_sizes, int n_in,
                              void* d_out, int out_size, void* d_ws, size_t ws_size,
                              hipStream_t stream) {
  const float* Q = (const float*)d_in[0];
  const float* K = (const float*)d_in[1];
  const float* V = (const float*)d_in[2];
  const float* U = (const float*)d_in[3];
  const float* WQ = (const float*)d_in[4];
  const float* WK = (const float*)d_in[5];
  const float* WV = (const float*)d_in[6];
  const float* WL = (const float*)d_in[7];
  const float* bl = (const float*)d_in[8];
  const float* ga = (const float*)d_in[9];
  const float* be = (const float*)d_in[10];
  float* out = (float*)d_out;
  char* w = (char*)d_ws;

  unsigned short* wqhi = (unsigned short*)w;
  unsigned short* wqlo = (unsigned short*)(w + 1572864);
  unsigned short* A2b = wqhi;  // reuse after G1t
  unsigned short* s1hi = (unsigned short*)(w + 3145728);
  unsigned short* s1lo = (unsigned short*)(w + 6291456);
  unsigned short* ctxb = (unsigned short*)(w + 9437184);
  float* lin = (float*)(w + 12582912);
  float* P = (float*)(w + 18874368);

  size_t avail = ws_size > 18874368 ? ws_size - 18874368 : 0;
  int sG2 = 1;
  while (sG2 * 2 <= 4 && 3145728ull * (size_t)(sG2 * 2) <= avail) sG2 *= 2;

  build_wqeff<<<NB * NH * NR, 256, 0, stream>>>(U, WQ, wqhi, wqlo);

  // G1t: s1^T, pipelined, XCD-decoded. 768 blocks.
  gemm_tn<true><<<768, 256, 0, stream>>>(Q, wqhi, wqlo, s1hi, s1lo);

  // G2: split-K partials, fused K transpose+convert, K-reg prefetch.
  gemm_g2<<<48 * NB * sG2, 256, 0, stream>>>(s1hi, s1lo, K, P, 2048 / sG2,
                                             NB * sG2);

  // s2 -> softmax -> A2 (sums G2 partials inline)
  sm_k<<<NB * NH * NR, 256, 0, stream>>>(P, sG2, WK, WV, A2b);

  // G3t: ctx^T, pipelined, XCD-decoded. 768 blocks.
  gemm_tn<false><<<768, 256, 0, stream>>>(V, A2b, nullptr, ctxb, nullptr);

  // G4: lin = ctx @ WL^T, pipelined. 384 blocks.
  gemm_g4<<<384, 256, 0, stream>>>(ctxb, WL, lin);

  // bias + LayerNorm -> out
  bias_ln<<<NB * 384, 256, 0, stream>>>(lin, bl, ga, be, out);
}